// Round 4
// baseline (1088.142 us; speedup 1.0000x reference)
//
#include <hip/hip_runtime.h>

#define U_NUM 50000
#define I_NUM 20000
#define F_DIM 64
#define N_EDGES 1000000
#define BATCH 131072

// Bucket = 16 consecutive destination rows. Sub-bucket = likely-XCD (blockIdx&7).
#define KU 3125              // U buckets (50000/16)
#define KI 1250              // I buckets (20000/16)
#define CAPU 112             // records per (U bucket, sub); mean 40, >10 sigma margin
#define CAPI 224             // records per (I bucket, sub); mean 100

// ---------------- bucketed append (replaces count+scan+sort) ----------------
// One thread per edge. Record: x = (localrow<<16)|src, y = val bits.
// Append position from an atomic cursor per (bucket, sub). Sub = blockIdx&7
// tracks the XCD round-robin so each region's tail line is single-XCD-writer:
// lines fill all 8 slots in-L2 and write back once, full (no partial-line RMW).
__global__ void bucket_append(const int* __restrict__ rows, const int* __restrict__ cols,
                              const float* __restrict__ ui_vals, const float* __restrict__ iu_vals,
                              int* __restrict__ curU, int* __restrict__ curI,
                              int2* __restrict__ edgesU, int2* __restrict__ edgesI)
{
    int e = blockIdx.x * blockDim.x + threadIdx.x;
    if (e >= N_EDGES) return;
    int sub = blockIdx.x & 7;
    int r = rows[e], c = cols[e];

    int bU = (r >> 4) * 8 + sub;
    int pU = atomicAdd(&curU[bU], 1);
    if (pU < CAPU) {
        int2 rec;
        rec.x = ((r & 15) << 16) | c;          // c < 20000 fits 16 bits
        rec.y = __float_as_int(ui_vals[e]);
        edgesU[bU * CAPU + pU] = rec;
    }
    int bI = (c >> 4) * 8 + sub;
    int pI = atomicAdd(&curI[bI], 1);
    if (pI < CAPI) {
        int2 rec;
        rec.x = ((c & 15) << 16) | r;          // r < 50000 fits 16 bits
        rec.y = __float_as_int(iu_vals[e]);
        edgesI[bI * CAPI + pI] = rec;
    }
}

// ---------------- bucketed gather SpMM with fused GCN epilogue ----------------
// One block per bucket (16 rows). Wave w owns local rows with (lr&3)==w; each
// lane holds 4 row-accumulators in VGPRs (lane = feature). Records staged in
// LDS 256 at a time; the ownership test is wave-uniform (scalar branch).
//   MODE 0: dst = acc;  gcn = base + alpha*acc
//   MODE 1: dst = acc;  gcn += alpha*acc
//   MODE 2:             gcn += alpha*acc      (level-3 result never stored)
template <int MODE>
__global__ void spmm_bucket(const int* __restrict__ cur, const int2* __restrict__ edges,
                            int cap,
                            const float* __restrict__ src_emb,
                            float* __restrict__ dst,
                            const float* __restrict__ base,
                            float* __restrict__ gcn,
                            float alpha)
{
    __shared__ int2 rec[256];
    int bucket = blockIdx.x;
    int lane = threadIdx.x & 63;
    int w    = threadIdx.x >> 6;      // wave 0..3

    float acc0 = 0.f, acc1 = 0.f, acc2 = 0.f, acc3 = 0.f;

    for (int s = 0; s < 8; s++) {
        int sb = bucket * 8 + s;
        int cnt = cur[sb];
        if (cnt > cap) cnt = cap;     // overflow guard (should never trigger)
        int sbase = sb * cap;
        for (int chunk = 0; chunk < cnt; chunk += 256) {
            int m = min(256, cnt - chunk);
            __syncthreads();
            if ((int)threadIdx.x < m)
                rec[threadIdx.x] = edges[sbase + chunk + threadIdx.x];
            __syncthreads();
            for (int t = 0; t < m; t++) {
                int2 e = rec[t];
                int lr = e.x >> 16;               // local row 0..15 (wave-uniform)
                if ((lr & 3) != w) continue;      // scalar branch
                float v = __int_as_float(e.y);
                float x = src_emb[((size_t)(e.x & 0xFFFF) << 6) + lane];
                float vx = v * x;
                int j = lr >> 2;
                acc0 += (j == 0) ? vx : 0.f;
                acc1 += (j == 1) ? vx : 0.f;
                acc2 += (j == 2) ? vx : 0.f;
                acc3 += (j == 3) ? vx : 0.f;
            }
        }
    }

    float accs[4] = {acc0, acc1, acc2, acc3};
    #pragma unroll
    for (int j = 0; j < 4; j++) {
        int row = bucket * 16 + j * 4 + w;        // localrow = j*4+w
        size_t off = (size_t)row * F_DIM + lane;
        float a = accs[j];
        if (MODE < 2) dst[off] = a;
        float g = (MODE == 0) ? base[off] : gcn[off];
        gcn[off] = g + alpha * a;
    }
}

// ---------------- fused contrastive loss (both halves) ----------------
__global__ void contrastive_both(const float* __restrict__ oldU, const float* __restrict__ gcnU,
                                 const int* __restrict__ userU, const int* __restrict__ iiU,
                                 const int* __restrict__ ijU, const float* __restrict__ degU,
                                 const float* __restrict__ oldI, const float* __restrict__ gcnI,
                                 const int* __restrict__ userI, const int* __restrict__ iiI,
                                 const int* __restrict__ ijI, const float* __restrict__ degI,
                                 float* __restrict__ out)
{
    __shared__ float warp_sums[4];
    int half = gridDim.x >> 1;
    bool second = blockIdx.x >= half;
    const float* old_emb = second ? oldI : oldU;
    const float* gcn     = second ? gcnI : gcnU;
    const int* idx_u     = second ? userI : userU;
    const int* idx_i     = second ? iiI : iiU;
    const int* idx_j     = second ? ijI : ijU;
    const float* degree  = second ? degI : degU;
    float inv_num        = second ? (1.f / I_NUM) : (1.f / U_NUM);
    int bid = second ? (blockIdx.x - half) : blockIdx.x;

    int lane = threadIdx.x & 63;
    int wib  = threadIdx.x >> 6;
    int gw = (bid * blockDim.x + threadIdx.x) >> 6;
    int nw = (half * blockDim.x) >> 6;
    float acc = 0.f;
    for (int b = gw; b < BATCH; b += nw) {
        int u = idx_u[b], i = idx_i[b], j = idx_j[b];
        float uv = old_emb[(size_t)u * F_DIM + lane];
        float si = uv * gcn[(size_t)i * F_DIM + lane];
        float sj = uv * gcn[(size_t)j * F_DIM + lane];
        #pragma unroll
        for (int off = 32; off > 0; off >>= 1) {
            si += __shfl_down(si, off, 64);
            sj += __shfl_down(sj, off, 64);
        }
        if (lane == 0) {
            float m = fmaxf(si, sj);
            float lse = m + logf(expf(si - m) + expf(sj - m));
            acc += (si - lse) * degree[b];
        }
    }
    if (lane == 0) warp_sums[wib] = acc;
    __syncthreads();
    if (threadIdx.x == 0) {
        float s = warp_sums[0] + warp_sums[1] + warp_sums[2] + warp_sums[3];
        atomicAdd(out, -s * inv_num);
    }
}

extern "C" void kernel_launch(void* const* d_in, const int* in_sizes, int n_in,
                              void* d_out, int out_size, void* d_ws, size_t ws_size,
                              hipStream_t stream)
{
    const float* embed_user = (const float*)d_in[0];
    const float* embed_item = (const float*)d_in[1];
    const float* old_U      = (const float*)d_in[2];
    const float* old_I      = (const float*)d_in[3];
    const int*   erow       = (const int*)d_in[4];
    const int*   ecol       = (const int*)d_in[5];
    const float* ui_vals    = (const float*)d_in[6];
    const float* iu_vals    = (const float*)d_in[7];
    const int*   user       = (const int*)d_in[8];
    const int*   item_i     = (const int*)d_in[9];
    const int*   item_j     = (const int*)d_in[10];
    const float* degU       = (const float*)d_in[11];
    const int*   user_      = (const int*)d_in[13];
    const int*   item_i_    = (const int*)d_in[14];
    const int*   item_j_    = (const int*)d_in[15];
    const float* degI       = (const float*)d_in[16];

    const size_t UF = (size_t)U_NUM * F_DIM;
    const size_t IF = (size_t)I_NUM * F_DIM;
    const size_t NRECU = (size_t)KU * 8 * CAPU;   // 2.8e6 recs, 22.4 MB
    const size_t NRECI = (size_t)KI * 8 * CAPI;   // 2.24e6 recs, 17.9 MB

    int2*  edgesU = (int2*)d_ws;
    int2*  edgesI = edgesU + NRECU;
    float* uA     = (float*)(edgesI + NRECI);
    float* uB     = uA + UF;
    float* iA     = uB + UF;
    float* iB     = iA + IF;
    float* gcn_u  = iB + IF;
    float* gcn_i  = gcn_u + UF;
    int*   curU   = (int*)(gcn_i + IF);           // KU*8 = 25000 ints
    int*   curI   = curU + KU * 8;                // KI*8 = 10000 ints
    // total ~94.2 MB

    dim3 blk(256);
    const int eblk = (N_EDGES + 255) / 256;       // 3907

    hipMemsetAsync(curU, 0, (KU * 8 + KI * 8) * sizeof(int), stream);
    hipMemsetAsync(d_out, 0, sizeof(float), stream);

    // Build bucket-grouped edge lists (one kernel, no scan, no sort).
    bucket_append<<<eblk, blk, 0, stream>>>(erow, ecol, ui_vals, iu_vals,
                                            curU, curI, edgesU, edgesI);

    // L1: u1 = A@i0, gcn_u = u0 + 0.5*u1 ; i1 = At@u0, gcn_i = i0 + 0.5*i1
    spmm_bucket<0><<<KU, blk, 0, stream>>>(curU, edgesU, CAPU, embed_item,
                                           uA, embed_user, gcn_u, 0.5f);
    spmm_bucket<0><<<KI, blk, 0, stream>>>(curI, edgesI, CAPI, embed_user,
                                           iA, embed_item, gcn_i, 0.5f);
    // L2: u2 = A@i1, gcn_u += (1/3)*u2 ; i2 = At@u1, gcn_i += (1/3)*i2
    spmm_bucket<1><<<KU, blk, 0, stream>>>(curU, edgesU, CAPU, iA,
                                           uB, nullptr, gcn_u, 1.f / 3.f);
    spmm_bucket<1><<<KI, blk, 0, stream>>>(curI, edgesI, CAPI, uA,
                                           iB, nullptr, gcn_i, 1.f / 3.f);
    // L3: gcn_u += 0.25*(A@i2) ; gcn_i += 0.25*(At@u2)
    spmm_bucket<2><<<KU, blk, 0, stream>>>(curU, edgesU, CAPU, iB,
                                           nullptr, nullptr, gcn_u, 0.25f);
    spmm_bucket<2><<<KI, blk, 0, stream>>>(curI, edgesI, CAPI, uB,
                                           nullptr, nullptr, gcn_i, 0.25f);

    contrastive_both<<<4096, blk, 0, stream>>>(old_U, gcn_u, user, item_i, item_j, degU,
                                               old_I, gcn_i, user_, item_i_, item_j_, degI,
                                               (float*)d_out);
}

// Round 5
// 669.154 us; speedup vs baseline: 1.6261x; 1.6261x over previous
//
#include <hip/hip_runtime.h>

#define U_NUM 50000
#define I_NUM 20000
#define F_DIM 64
#define N_EDGES 1000000
#define BATCH 131072

// Destination partitions for the two-pass build.
#define P_U 25            // 50000 >> 11  -> partitions of 2048 rows
#define P_I 20            // 20000 >> 10  -> partitions of 1024 cols
#define CAPP_U 45056      // mean 40960 per full partition, ~+20 sigma
#define CAPP_I 55296      // mean 51200, ~+18 sigma
#define BPU 160           // pass-2 blocks per U partition
#define BPI 200           // pass-2 blocks per I partition

// ---------------- pass 1: partition-grouped append + per-row counts ----------
// Tile = 1024 edges/block. LDS histogram by partition -> one global cursor
// reservation per (partition, tile) -> records land contiguously (full lines),
// killing the 2M-random-partial-line writeback that cost ~170us in r3.
// Record: x = (src<<16)|dst (unsigned), y = val bits.
__global__ void pass1_partition(const int* __restrict__ rows, const int* __restrict__ cols,
                                const float* __restrict__ uiv, const float* __restrict__ iuv,
                                int* __restrict__ cntU, int* __restrict__ cntI,
                                int* __restrict__ pcurU, int* __restrict__ pcurI,
                                int2* __restrict__ pbufU, int2* __restrict__ pbufI)
{
    __shared__ int histU[32], histI[32], resU[32], resI[32];
    if (threadIdx.x < 32) { histU[threadIdx.x] = 0; histI[threadIdx.x] = 0; }
    __syncthreads();

    int base = blockIdx.x * 1024;
    int r[4], c[4], lpU[4], lpI[4];
    float vu[4], vi[4];
    #pragma unroll
    for (int i = 0; i < 4; i++) {
        int e = base + threadIdx.x + i * 256;
        if (e < N_EDGES) {
            r[i] = rows[e]; c[i] = cols[e];
            vu[i] = uiv[e]; vi[i] = iuv[e];
            atomicAdd(&cntU[r[i]], 1);
            atomicAdd(&cntI[c[i]], 1);
            lpU[i] = atomicAdd(&histU[r[i] >> 11], 1);
            lpI[i] = atomicAdd(&histI[c[i] >> 10], 1);
        } else {
            lpU[i] = -1; lpI[i] = -1; r[i] = 0; c[i] = 0; vu[i] = 0.f; vi[i] = 0.f;
        }
    }
    __syncthreads();
    if (threadIdx.x < 32) {
        int h = histU[threadIdx.x];
        resU[threadIdx.x] = h ? atomicAdd(&pcurU[threadIdx.x], h) : 0;
        h = histI[threadIdx.x];
        resI[threadIdx.x] = h ? atomicAdd(&pcurI[threadIdx.x], h) : 0;
    }
    __syncthreads();
    #pragma unroll
    for (int i = 0; i < 4; i++) {
        if (lpU[i] >= 0) {
            int p = r[i] >> 11;
            int idx = resU[p] + lpU[i];
            if (idx < CAPP_U) {
                int2 rec;
                rec.x = (int)(((unsigned)c[i] << 16) | (unsigned)r[i]);
                rec.y = __float_as_int(vu[i]);
                pbufU[(size_t)p * CAPP_U + idx] = rec;
            }
            p = c[i] >> 10;
            idx = resI[p] + lpI[i];
            if (idx < CAPP_I) {
                int2 rec;
                rec.x = (int)(((unsigned)r[i] << 16) | (unsigned)c[i]);
                rec.y = __float_as_int(vi[i]);
                pbufI[(size_t)p * CAPP_I + idx] = rec;
            }
        }
    }
}

// ---------------- exclusive scans (both tables, one launch) ------------------
__global__ void exscan_both(const int* __restrict__ cntU, int* __restrict__ ptrU, int* __restrict__ curU,
                            const int* __restrict__ cntI, int* __restrict__ ptrI, int* __restrict__ curI)
{
    const int* cnt;
    int *ptr, *cur, n;
    if (blockIdx.x == 0) { cnt = cntU; ptr = ptrU; cur = curU; n = U_NUM; }
    else                 { cnt = cntI; ptr = ptrI; cur = curI; n = I_NUM; }

    __shared__ int buf[1024];
    const int chunk = (n + 1023) / 1024;
    int start = threadIdx.x * chunk;
    int local = 0;
    for (int k = 0; k < chunk; k++) {
        int i = start + k;
        if (i < n) local += cnt[i];
    }
    buf[threadIdx.x] = local;
    __syncthreads();
    for (int off = 1; off < 1024; off <<= 1) {
        int t = (threadIdx.x >= (unsigned)off) ? buf[threadIdx.x - off] : 0;
        __syncthreads();
        buf[threadIdx.x] += t;
        __syncthreads();
    }
    int run = buf[threadIdx.x] - local;
    for (int k = 0; k < chunk; k++) {
        int i = start + k;
        if (i < n) {
            ptr[i] = run;
            cur[i] = run;
            run += cnt[i];
        }
    }
}

// ---------------- pass 2: partition -> exact CSR -----------------------------
// Blocks [0, P_U*BPU) handle U partitions; rest handle I. Scatter window per
// partition is ~320KB (U) / ~410KB (I): lines collect all 8 records in L2
// before writeback (vs r3's 16MB-wide random scatter that wrote 2M partial
// lines).
__global__ void pass2_scatter(const int* __restrict__ pcurU, const int2* __restrict__ pbufU,
                              int* __restrict__ curU, int2* __restrict__ edgesU,
                              const int* __restrict__ pcurI, const int2* __restrict__ pbufI,
                              int* __restrict__ curI, int2* __restrict__ edgesI)
{
    const int* pcur; const int2* pbuf; int* cur; int2* edges;
    int p, b, bpp, capp;
    if (blockIdx.x < P_U * BPU) {
        pcur = pcurU; pbuf = pbufU; cur = curU; edges = edgesU;
        p = blockIdx.x / BPU; b = blockIdx.x % BPU; bpp = BPU; capp = CAPP_U;
    } else {
        int q = blockIdx.x - P_U * BPU;
        pcur = pcurI; pbuf = pbufI; cur = curI; edges = edgesI;
        p = q / BPI; b = q % BPI; bpp = BPI; capp = CAPP_I;
    }
    int n = pcur[p];
    if (n > capp) n = capp;
    const int2* src = pbuf + (size_t)p * capp;
    for (int t = b * 256 + threadIdx.x; t < n; t += bpp * 256) {
        int2 rec = src[t];
        unsigned x = (unsigned)rec.x;
        int dst = (int)(x & 0xFFFFu);
        int s   = (int)(x >> 16);
        int pos = atomicAdd(&cur[dst], 1);
        int2 out;
        out.x = s;
        out.y = rec.y;
        edges[pos] = out;
    }
}

// ---------------- fused-level gather SpMM ------------------------------------
// One wave per destination row; quarter-wave (16 lanes) per edge slot; k-loop
// unrolled x4 -> 16 independent 16B gathers in flight per wave. U rows are
// waves [0,U_NUM), I rows are waves [U_NUM, U_NUM+I_NUM) -> both halves of a
// level overlap in one launch (independent work, hides each other's latency).
//   MODE 0: dst = acc;  gcn = base + alpha*acc
//   MODE 1: dst = acc;  gcn += alpha*acc
//   MODE 2:             gcn += alpha*acc   (level-3 result never materialized)
template <int MODE>
__global__ void spmm_level(const int* __restrict__ ptrU, const int* __restrict__ cntU,
                           const int2* __restrict__ edgesU, const float* __restrict__ srcU,
                           float* __restrict__ dstU, const float* __restrict__ baseU,
                           float* __restrict__ gcnU,
                           const int* __restrict__ ptrI, const int* __restrict__ cntI,
                           const int2* __restrict__ edgesI, const float* __restrict__ srcI,
                           float* __restrict__ dstI, const float* __restrict__ baseI,
                           float* __restrict__ gcnI,
                           float alpha)
{
    int wave = (blockIdx.x * blockDim.x + threadIdx.x) >> 6;
    bool isU = wave < U_NUM;
    int row = isU ? wave : wave - U_NUM;
    if (!isU && row >= I_NUM) return;

    const int*  ptr   = isU ? ptrU   : ptrI;
    const int*  cnt   = isU ? cntU   : cntI;
    const int2* edges = isU ? edgesU : edgesI;
    const float* semb = isU ? srcU   : srcI;
    float* dst        = isU ? dstU   : dstI;
    const float* base = isU ? baseU  : baseI;
    float* gcn        = isU ? gcnU   : gcnI;

    int lane = threadIdx.x & 63;
    int sub  = lane >> 4;          // edge slot 0..3
    int q    = lane & 15;          // float4 block 0..15
    int begin = ptr[row];
    int len   = cnt[row];

    float4 a0 = make_float4(0.f, 0.f, 0.f, 0.f);
    float4 a1 = make_float4(0.f, 0.f, 0.f, 0.f);
    float4 a2 = make_float4(0.f, 0.f, 0.f, 0.f);
    float4 a3 = make_float4(0.f, 0.f, 0.f, 0.f);
    int k = sub;
    for (; k + 12 < len; k += 16) {
        int2 e0 = edges[begin + k];
        int2 e1 = edges[begin + k + 4];
        int2 e2 = edges[begin + k + 8];
        int2 e3 = edges[begin + k + 12];
        float4 x0 = ((const float4*)(semb + (size_t)e0.x * F_DIM))[q];
        float4 x1 = ((const float4*)(semb + (size_t)e1.x * F_DIM))[q];
        float4 x2 = ((const float4*)(semb + (size_t)e2.x * F_DIM))[q];
        float4 x3 = ((const float4*)(semb + (size_t)e3.x * F_DIM))[q];
        float v0 = __int_as_float(e0.y), v1 = __int_as_float(e1.y);
        float v2 = __int_as_float(e2.y), v3 = __int_as_float(e3.y);
        a0.x += v0 * x0.x; a0.y += v0 * x0.y; a0.z += v0 * x0.z; a0.w += v0 * x0.w;
        a1.x += v1 * x1.x; a1.y += v1 * x1.y; a1.z += v1 * x1.z; a1.w += v1 * x1.w;
        a2.x += v2 * x2.x; a2.y += v2 * x2.y; a2.z += v2 * x2.z; a2.w += v2 * x2.w;
        a3.x += v3 * x3.x; a3.y += v3 * x3.y; a3.z += v3 * x3.z; a3.w += v3 * x3.w;
    }
    for (; k < len; k += 4) {
        int2 e0 = edges[begin + k];
        float4 x0 = ((const float4*)(semb + (size_t)e0.x * F_DIM))[q];
        float v0 = __int_as_float(e0.y);
        a0.x += v0 * x0.x; a0.y += v0 * x0.y; a0.z += v0 * x0.z; a0.w += v0 * x0.w;
    }
    float4 acc;
    acc.x = (a0.x + a1.x) + (a2.x + a3.x);
    acc.y = (a0.y + a1.y) + (a2.y + a3.y);
    acc.z = (a0.z + a1.z) + (a2.z + a3.z);
    acc.w = (a0.w + a1.w) + (a2.w + a3.w);

    acc.x += __shfl_xor(acc.x, 16, 64);
    acc.y += __shfl_xor(acc.y, 16, 64);
    acc.z += __shfl_xor(acc.z, 16, 64);
    acc.w += __shfl_xor(acc.w, 16, 64);
    acc.x += __shfl_xor(acc.x, 32, 64);
    acc.y += __shfl_xor(acc.y, 32, 64);
    acc.z += __shfl_xor(acc.z, 32, 64);
    acc.w += __shfl_xor(acc.w, 32, 64);

    if (sub == 0) {
        size_t off = (size_t)row * F_DIM;
        if (MODE < 2) ((float4*)(dst + off))[q] = acc;
        float4 g;
        if (MODE == 0) g = ((const float4*)(base + off))[q];
        else           g = ((const float4*)(gcn + off))[q];
        g.x += alpha * acc.x;
        g.y += alpha * acc.y;
        g.z += alpha * acc.z;
        g.w += alpha * acc.w;
        ((float4*)(gcn + off))[q] = g;
    }
}

// ---------------- fused contrastive loss (both halves) -----------------------
__global__ void contrastive_both(const float* __restrict__ oldU, const float* __restrict__ gcnU,
                                 const int* __restrict__ userU, const int* __restrict__ iiU,
                                 const int* __restrict__ ijU, const float* __restrict__ degU,
                                 const float* __restrict__ oldI, const float* __restrict__ gcnI,
                                 const int* __restrict__ userI, const int* __restrict__ iiI,
                                 const int* __restrict__ ijI, const float* __restrict__ degI,
                                 float* __restrict__ out)
{
    __shared__ float warp_sums[4];
    int half = gridDim.x >> 1;
    bool second = blockIdx.x >= half;
    const float* old_emb = second ? oldI : oldU;
    const float* gcn     = second ? gcnI : gcnU;
    const int* idx_u     = second ? userI : userU;
    const int* idx_i     = second ? iiI : iiU;
    const int* idx_j     = second ? ijI : ijU;
    const float* degree  = second ? degI : degU;
    float inv_num        = second ? (1.f / I_NUM) : (1.f / U_NUM);
    int bid = second ? (blockIdx.x - half) : blockIdx.x;

    int lane = threadIdx.x & 63;
    int wib  = threadIdx.x >> 6;
    int gw = (bid * blockDim.x + threadIdx.x) >> 6;
    int nw = (half * blockDim.x) >> 6;
    float acc = 0.f;
    for (int b = gw; b < BATCH; b += nw) {
        int u = idx_u[b], i = idx_i[b], j = idx_j[b];
        float uv = old_emb[(size_t)u * F_DIM + lane];
        float si = uv * gcn[(size_t)i * F_DIM + lane];
        float sj = uv * gcn[(size_t)j * F_DIM + lane];
        #pragma unroll
        for (int off = 32; off > 0; off >>= 1) {
            si += __shfl_down(si, off, 64);
            sj += __shfl_down(sj, off, 64);
        }
        if (lane == 0) {
            float m = fmaxf(si, sj);
            float lse = m + logf(expf(si - m) + expf(sj - m));
            acc += (si - lse) * degree[b];
        }
    }
    if (lane == 0) warp_sums[wib] = acc;
    __syncthreads();
    if (threadIdx.x == 0) {
        float s = warp_sums[0] + warp_sums[1] + warp_sums[2] + warp_sums[3];
        atomicAdd(out, -s * inv_num);
    }
}

extern "C" void kernel_launch(void* const* d_in, const int* in_sizes, int n_in,
                              void* d_out, int out_size, void* d_ws, size_t ws_size,
                              hipStream_t stream)
{
    const float* embed_user = (const float*)d_in[0];
    const float* embed_item = (const float*)d_in[1];
    const float* old_U      = (const float*)d_in[2];
    const float* old_I      = (const float*)d_in[3];
    const int*   erow       = (const int*)d_in[4];
    const int*   ecol       = (const int*)d_in[5];
    const float* ui_vals    = (const float*)d_in[6];
    const float* iu_vals    = (const float*)d_in[7];
    const int*   user       = (const int*)d_in[8];
    const int*   item_i     = (const int*)d_in[9];
    const int*   item_j     = (const int*)d_in[10];
    const float* degU       = (const float*)d_in[11];
    const int*   user_      = (const int*)d_in[13];
    const int*   item_i_    = (const int*)d_in[14];
    const int*   item_j_    = (const int*)d_in[15];
    const float* degI       = (const float*)d_in[16];

    const size_t UF = (size_t)U_NUM * F_DIM;
    const size_t IF = (size_t)I_NUM * F_DIM;

    int2*  pbufU  = (int2*)d_ws;                        // 25*45056 recs = 9.0 MB
    int2*  pbufI  = pbufU + (size_t)P_U * CAPP_U;       // 20*55296 recs = 8.8 MB
    int2*  edgesU = pbufI + (size_t)P_I * CAPP_I;       // 8 MB
    int2*  edgesI = edgesU + N_EDGES;                   // 8 MB
    float* uA     = (float*)(edgesI + N_EDGES);
    float* uB     = uA + UF;
    float* iA     = uB + UF;
    float* iB     = iA + IF;
    float* gcn_u  = iB + IF;
    float* gcn_i  = gcn_u + UF;
    int*   cntU   = (int*)(gcn_i + IF);                 // zeroed region starts here
    int*   cntI   = cntU + U_NUM;
    int*   pcurU  = cntI + I_NUM;
    int*   pcurI  = pcurU + 32;
    int*   ptrU   = pcurI + 32;                         // end of zeroed region
    int*   curU   = ptrU + U_NUM;
    int*   ptrI   = curU + U_NUM;
    int*   curI   = ptrI + I_NUM;
    // total ~88 MB

    dim3 blk(256);
    const int p1_blocks = (N_EDGES + 1023) / 1024;             // 977
    const int p2_blocks = P_U * BPU + P_I * BPI;               // 8000
    const int spmm_blocks = (U_NUM + I_NUM) / 4;               // 17500

    hipMemsetAsync(cntU, 0, (U_NUM + I_NUM + 64) * sizeof(int), stream);
    hipMemsetAsync(d_out, 0, sizeof(float), stream);

    pass1_partition<<<p1_blocks, blk, 0, stream>>>(erow, ecol, ui_vals, iu_vals,
                                                   cntU, cntI, pcurU, pcurI, pbufU, pbufI);
    exscan_both<<<2, 1024, 0, stream>>>(cntU, ptrU, curU, cntI, ptrI, curI);
    pass2_scatter<<<p2_blocks, blk, 0, stream>>>(pcurU, pbufU, curU, edgesU,
                                                 pcurI, pbufI, curI, edgesI);

    // L1: u1 = A@i0, gcn_u = u0 + 0.5*u1 ; i1 = At@u0, gcn_i = i0 + 0.5*i1
    spmm_level<0><<<spmm_blocks, blk, 0, stream>>>(
        ptrU, cntU, edgesU, embed_item, uA, embed_user, gcn_u,
        ptrI, cntI, edgesI, embed_user, iA, embed_item, gcn_i, 0.5f);
    // L2: u2 = A@i1, gcn_u += (1/3)*u2 ; i2 = At@u1, gcn_i += (1/3)*i2
    spmm_level<1><<<spmm_blocks, blk, 0, stream>>>(
        ptrU, cntU, edgesU, iA, uB, nullptr, gcn_u,
        ptrI, cntI, edgesI, uA, iB, nullptr, gcn_i, 1.f / 3.f);
    // L3: gcn_u += 0.25*(A@i2) ; gcn_i += 0.25*(At@u2)
    spmm_level<2><<<spmm_blocks, blk, 0, stream>>>(
        ptrU, cntU, edgesU, iB, nullptr, nullptr, gcn_u,
        ptrI, cntI, edgesI, uB, nullptr, nullptr, gcn_i, 0.25f);

    contrastive_both<<<4096, blk, 0, stream>>>(old_U, gcn_u, user, item_i, item_j, degU,
                                               old_I, gcn_i, user_, item_i_, item_j_, degI,
                                               (float*)d_out);
}

// Round 6
// 550.575 us; speedup vs baseline: 1.9764x; 1.2154x over previous
//
#include <hip/hip_runtime.h>

#define U_NUM 50000
#define I_NUM 20000
#define F_DIM 64
#define N_EDGES 1000000
#define BATCH 131072

// Destination partitions for the two-pass build.
#define P_U 25            // partitions of 2048 rows
#define P_I 20            // partitions of 1024 cols
#define CAPP_U 45056      // mean 40960 per full partition, ~+20 sigma
#define CAPP_I 55296      // mean 51200, ~+18 sigma
#define BPU 160           // pass-2 blocks per U partition
#define BPI 200           // pass-2 blocks per I partition

// ---------------- pass 1: partition-grouped append + per-row counts ----------
// Tile = 1024 edges/block. LDS histogram by partition -> one global cursor
// reservation per (partition, tile) -> records land contiguously (full lines).
// Record: x = (src<<16)|dst (unsigned), y = val bits.
__global__ void pass1_partition(const int* __restrict__ rows, const int* __restrict__ cols,
                                const float* __restrict__ uiv, const float* __restrict__ iuv,
                                int* __restrict__ cntU, int* __restrict__ cntI,
                                int* __restrict__ pcurU, int* __restrict__ pcurI,
                                int2* __restrict__ pbufU, int2* __restrict__ pbufI)
{
    __shared__ int histU[32], histI[32], resU[32], resI[32];
    if (threadIdx.x < 32) { histU[threadIdx.x] = 0; histI[threadIdx.x] = 0; }
    __syncthreads();

    int base = blockIdx.x * 1024;
    int r[4], c[4], lpU[4], lpI[4];
    float vu[4], vi[4];
    #pragma unroll
    for (int i = 0; i < 4; i++) {
        int e = base + threadIdx.x + i * 256;
        if (e < N_EDGES) {
            r[i] = rows[e]; c[i] = cols[e];
            vu[i] = uiv[e]; vi[i] = iuv[e];
            atomicAdd(&cntU[r[i]], 1);
            atomicAdd(&cntI[c[i]], 1);
            lpU[i] = atomicAdd(&histU[r[i] >> 11], 1);
            lpI[i] = atomicAdd(&histI[c[i] >> 10], 1);
        } else {
            lpU[i] = -1; lpI[i] = -1; r[i] = 0; c[i] = 0; vu[i] = 0.f; vi[i] = 0.f;
        }
    }
    __syncthreads();
    if (threadIdx.x < 32) {
        int h = histU[threadIdx.x];
        resU[threadIdx.x] = h ? atomicAdd(&pcurU[threadIdx.x], h) : 0;
        h = histI[threadIdx.x];
        resI[threadIdx.x] = h ? atomicAdd(&pcurI[threadIdx.x], h) : 0;
    }
    __syncthreads();
    #pragma unroll
    for (int i = 0; i < 4; i++) {
        if (lpU[i] >= 0) {
            int p = r[i] >> 11;
            int idx = resU[p] + lpU[i];
            if (idx < CAPP_U) {
                int2 rec;
                rec.x = (int)(((unsigned)c[i] << 16) | (unsigned)r[i]);
                rec.y = __float_as_int(vu[i]);
                pbufU[(size_t)p * CAPP_U + idx] = rec;
            }
            p = c[i] >> 10;
            idx = resI[p] + lpI[i];
            if (idx < CAPP_I) {
                int2 rec;
                rec.x = (int)(((unsigned)r[i] << 16) | (unsigned)c[i]);
                rec.y = __float_as_int(vi[i]);
                pbufI[(size_t)p * CAPP_I + idx] = rec;
            }
        }
    }
}

// ---------------- hierarchical exclusive scan --------------------------------
// One block per partition (45 total). Partition base = sum of pass-1 partition
// totals (pcur) below p (<=24 scalar adds); intra-partition offsets via a
// coalesced 256-entry LDS scan (each thread owns 8 (U) / 4 (I) consecutive
// counts, loaded/stored contiguously). Replaces the 2-block chunked scan that
// was 126us of pure uncoalesced single-CU latency.
__global__ void exscan_part(const int* __restrict__ cntU, int* __restrict__ ptrU,
                            int* __restrict__ curU, const int* __restrict__ pcurU,
                            const int* __restrict__ cntI, int* __restrict__ ptrI,
                            int* __restrict__ curI, const int* __restrict__ pcurI)
{
    const int* cnt; int* ptr; int* cur; const int* pcur;
    int p, psize, n;
    if (blockIdx.x < P_U) {
        cnt = cntU; ptr = ptrU; cur = curU; pcur = pcurU;
        p = blockIdx.x; psize = 2048; n = U_NUM;
    } else {
        cnt = cntI; ptr = ptrI; cur = curI; pcur = pcurI;
        p = blockIdx.x - P_U; psize = 1024; n = I_NUM;
    }
    int base = 0;
    for (int i = 0; i < p; i++) base += pcur[i];

    int ept = psize >> 8;                     // 8 (U) or 4 (I)
    int start = p * psize + threadIdx.x * ept;
    int v[8];
    int local = 0;
    for (int j = 0; j < ept; j++) {
        int idx = start + j;
        v[j] = (idx < n) ? cnt[idx] : 0;
        local += v[j];
    }
    __shared__ int buf[256];
    buf[threadIdx.x] = local;
    __syncthreads();
    for (int off = 1; off < 256; off <<= 1) {
        int t = ((int)threadIdx.x >= off) ? buf[threadIdx.x - off] : 0;
        __syncthreads();
        buf[threadIdx.x] += t;
        __syncthreads();
    }
    int run = base + buf[threadIdx.x] - local;
    for (int j = 0; j < ept; j++) {
        int idx = start + j;
        if (idx < n) {
            ptr[idx] = run;
            cur[idx] = run;
            run += v[j];
        }
    }
}

// ---------------- pass 2: partition -> exact CSR -----------------------------
// Scatter window per partition is ~320KB (U) / ~440KB (I): lines collect all 8
// records in L2 before writeback.
__global__ void pass2_scatter(const int* __restrict__ pcurU, const int2* __restrict__ pbufU,
                              int* __restrict__ curU, int2* __restrict__ edgesU,
                              const int* __restrict__ pcurI, const int2* __restrict__ pbufI,
                              int* __restrict__ curI, int2* __restrict__ edgesI)
{
    const int* pcur; const int2* pbuf; int* cur; int2* edges;
    int p, b, bpp, capp;
    if (blockIdx.x < P_U * BPU) {
        pcur = pcurU; pbuf = pbufU; cur = curU; edges = edgesU;
        p = blockIdx.x / BPU; b = blockIdx.x % BPU; bpp = BPU; capp = CAPP_U;
    } else {
        int q = blockIdx.x - P_U * BPU;
        pcur = pcurI; pbuf = pbufI; cur = curI; edges = edgesI;
        p = q / BPI; b = q % BPI; bpp = BPI; capp = CAPP_I;
    }
    int n = pcur[p];
    if (n > capp) n = capp;
    const int2* src = pbuf + (size_t)p * capp;
    for (int t = b * 256 + threadIdx.x; t < n; t += bpp * 256) {
        int2 rec = src[t];
        unsigned x = (unsigned)rec.x;
        int dst = (int)(x & 0xFFFFu);
        int s   = (int)(x >> 16);
        int pos = atomicAdd(&cur[dst], 1);
        int2 out;
        out.x = s;
        out.y = rec.y;
        edges[pos] = out;
    }
}

// ---------------- fused-level gather SpMM ------------------------------------
// One wave per destination row; quarter-wave per edge slot; k-loop unrolled x4
// -> 16 independent 16B gathers in flight per wave. U rows are waves
// [0,U_NUM), I rows are [U_NUM, U_NUM+I_NUM).
//   MODE 0: dst = acc;  gcn = base + alpha*acc
//   MODE 1: dst = acc;  gcn += alpha*acc
//   MODE 2:             gcn += alpha*acc   (level-3 result never materialized)
template <int MODE>
__global__ void spmm_level(const int* __restrict__ ptrU, const int* __restrict__ cntU,
                           const int2* __restrict__ edgesU, const float* __restrict__ srcU,
                           float* __restrict__ dstU, const float* __restrict__ baseU,
                           float* __restrict__ gcnU,
                           const int* __restrict__ ptrI, const int* __restrict__ cntI,
                           const int2* __restrict__ edgesI, const float* __restrict__ srcI,
                           float* __restrict__ dstI, const float* __restrict__ baseI,
                           float* __restrict__ gcnI,
                           float alpha)
{
    int wave = (blockIdx.x * blockDim.x + threadIdx.x) >> 6;
    bool isU = wave < U_NUM;
    int row = isU ? wave : wave - U_NUM;
    if (!isU && row >= I_NUM) return;

    const int*  ptr   = isU ? ptrU   : ptrI;
    const int*  cnt   = isU ? cntU   : cntI;
    const int2* edges = isU ? edgesU : edgesI;
    const float* semb = isU ? srcU   : srcI;
    float* dst        = isU ? dstU   : dstI;
    const float* base = isU ? baseU  : baseI;
    float* gcn        = isU ? gcnU   : gcnI;

    int lane = threadIdx.x & 63;
    int sub  = lane >> 4;
    int q    = lane & 15;
    int begin = ptr[row];
    int len   = cnt[row];

    float4 a0 = make_float4(0.f, 0.f, 0.f, 0.f);
    float4 a1 = make_float4(0.f, 0.f, 0.f, 0.f);
    float4 a2 = make_float4(0.f, 0.f, 0.f, 0.f);
    float4 a3 = make_float4(0.f, 0.f, 0.f, 0.f);
    int k = sub;
    for (; k + 12 < len; k += 16) {
        int2 e0 = edges[begin + k];
        int2 e1 = edges[begin + k + 4];
        int2 e2 = edges[begin + k + 8];
        int2 e3 = edges[begin + k + 12];
        float4 x0 = ((const float4*)(semb + (size_t)e0.x * F_DIM))[q];
        float4 x1 = ((const float4*)(semb + (size_t)e1.x * F_DIM))[q];
        float4 x2 = ((const float4*)(semb + (size_t)e2.x * F_DIM))[q];
        float4 x3 = ((const float4*)(semb + (size_t)e3.x * F_DIM))[q];
        float v0 = __int_as_float(e0.y), v1 = __int_as_float(e1.y);
        float v2 = __int_as_float(e2.y), v3 = __int_as_float(e3.y);
        a0.x += v0 * x0.x; a0.y += v0 * x0.y; a0.z += v0 * x0.z; a0.w += v0 * x0.w;
        a1.x += v1 * x1.x; a1.y += v1 * x1.y; a1.z += v1 * x1.z; a1.w += v1 * x1.w;
        a2.x += v2 * x2.x; a2.y += v2 * x2.y; a2.z += v2 * x2.z; a2.w += v2 * x2.w;
        a3.x += v3 * x3.x; a3.y += v3 * x3.y; a3.z += v3 * x3.z; a3.w += v3 * x3.w;
    }
    for (; k < len; k += 4) {
        int2 e0 = edges[begin + k];
        float4 x0 = ((const float4*)(semb + (size_t)e0.x * F_DIM))[q];
        float v0 = __int_as_float(e0.y);
        a0.x += v0 * x0.x; a0.y += v0 * x0.y; a0.z += v0 * x0.z; a0.w += v0 * x0.w;
    }
    float4 acc;
    acc.x = (a0.x + a1.x) + (a2.x + a3.x);
    acc.y = (a0.y + a1.y) + (a2.y + a3.y);
    acc.z = (a0.z + a1.z) + (a2.z + a3.z);
    acc.w = (a0.w + a1.w) + (a2.w + a3.w);

    acc.x += __shfl_xor(acc.x, 16, 64);
    acc.y += __shfl_xor(acc.y, 16, 64);
    acc.z += __shfl_xor(acc.z, 16, 64);
    acc.w += __shfl_xor(acc.w, 16, 64);
    acc.x += __shfl_xor(acc.x, 32, 64);
    acc.y += __shfl_xor(acc.y, 32, 64);
    acc.z += __shfl_xor(acc.z, 32, 64);
    acc.w += __shfl_xor(acc.w, 32, 64);

    if (sub == 0) {
        size_t off = (size_t)row * F_DIM;
        if (MODE < 2) ((float4*)(dst + off))[q] = acc;
        float4 g;
        if (MODE == 0) g = ((const float4*)(base + off))[q];
        else           g = ((const float4*)(gcn + off))[q];
        g.x += alpha * acc.x;
        g.y += alpha * acc.y;
        g.z += alpha * acc.z;
        g.w += alpha * acc.w;
        ((float4*)(gcn + off))[q] = g;
    }
}

// ---------------- fused contrastive loss (both halves) -----------------------
__global__ void contrastive_both(const float* __restrict__ oldU, const float* __restrict__ gcnU,
                                 const int* __restrict__ userU, const int* __restrict__ iiU,
                                 const int* __restrict__ ijU, const float* __restrict__ degU,
                                 const float* __restrict__ oldI, const float* __restrict__ gcnI,
                                 const int* __restrict__ userI, const int* __restrict__ iiI,
                                 const int* __restrict__ ijI, const float* __restrict__ degI,
                                 float* __restrict__ out)
{
    __shared__ float warp_sums[4];
    int half = gridDim.x >> 1;
    bool second = blockIdx.x >= half;
    const float* old_emb = second ? oldI : oldU;
    const float* gcn     = second ? gcnI : gcnU;
    const int* idx_u     = second ? userI : userU;
    const int* idx_i     = second ? iiI : iiU;
    const int* idx_j     = second ? ijI : ijU;
    const float* degree  = second ? degI : degU;
    float inv_num        = second ? (1.f / I_NUM) : (1.f / U_NUM);
    int bid = second ? (blockIdx.x - half) : blockIdx.x;

    int lane = threadIdx.x & 63;
    int wib  = threadIdx.x >> 6;
    int gw = (bid * blockDim.x + threadIdx.x) >> 6;
    int nw = (half * blockDim.x) >> 6;
    float acc = 0.f;
    for (int b = gw; b < BATCH; b += nw) {
        int u = idx_u[b], i = idx_i[b], j = idx_j[b];
        float uv = old_emb[(size_t)u * F_DIM + lane];
        float si = uv * gcn[(size_t)i * F_DIM + lane];
        float sj = uv * gcn[(size_t)j * F_DIM + lane];
        #pragma unroll
        for (int off = 32; off > 0; off >>= 1) {
            si += __shfl_down(si, off, 64);
            sj += __shfl_down(sj, off, 64);
        }
        if (lane == 0) {
            float m = fmaxf(si, sj);
            float lse = m + logf(expf(si - m) + expf(sj - m));
            acc += (si - lse) * degree[b];
        }
    }
    if (lane == 0) warp_sums[wib] = acc;
    __syncthreads();
    if (threadIdx.x == 0) {
        float s = warp_sums[0] + warp_sums[1] + warp_sums[2] + warp_sums[3];
        atomicAdd(out, -s * inv_num);
    }
}

extern "C" void kernel_launch(void* const* d_in, const int* in_sizes, int n_in,
                              void* d_out, int out_size, void* d_ws, size_t ws_size,
                              hipStream_t stream)
{
    const float* embed_user = (const float*)d_in[0];
    const float* embed_item = (const float*)d_in[1];
    const float* old_U      = (const float*)d_in[2];
    const float* old_I      = (const float*)d_in[3];
    const int*   erow       = (const int*)d_in[4];
    const int*   ecol       = (const int*)d_in[5];
    const float* ui_vals    = (const float*)d_in[6];
    const float* iu_vals    = (const float*)d_in[7];
    const int*   user       = (const int*)d_in[8];
    const int*   item_i     = (const int*)d_in[9];
    const int*   item_j     = (const int*)d_in[10];
    const float* degU       = (const float*)d_in[11];
    const int*   user_      = (const int*)d_in[13];
    const int*   item_i_    = (const int*)d_in[14];
    const int*   item_j_    = (const int*)d_in[15];
    const float* degI       = (const float*)d_in[16];

    const size_t UF = (size_t)U_NUM * F_DIM;
    const size_t IF = (size_t)I_NUM * F_DIM;

    int2*  pbufU  = (int2*)d_ws;
    int2*  pbufI  = pbufU + (size_t)P_U * CAPP_U;
    int2*  edgesU = pbufI + (size_t)P_I * CAPP_I;
    int2*  edgesI = edgesU + N_EDGES;
    float* uA     = (float*)(edgesI + N_EDGES);
    float* uB     = uA + UF;
    float* iA     = uB + UF;
    float* iB     = iA + IF;
    float* gcn_u  = iB + IF;
    float* gcn_i  = gcn_u + UF;
    int*   cntU   = (int*)(gcn_i + IF);                 // zeroed region starts here
    int*   cntI   = cntU + U_NUM;
    int*   pcurU  = cntI + I_NUM;
    int*   pcurI  = pcurU + 32;
    int*   ptrU   = pcurI + 32;                         // end of zeroed region
    int*   curU   = ptrU + U_NUM;
    int*   ptrI   = curU + U_NUM;
    int*   curI   = ptrI + I_NUM;

    dim3 blk(256);
    const int p1_blocks = (N_EDGES + 1023) / 1024;             // 977
    const int p2_blocks = P_U * BPU + P_I * BPI;               // 8000
    const int spmm_blocks = (U_NUM + I_NUM) / 4;               // 17500

    hipMemsetAsync(cntU, 0, (U_NUM + I_NUM + 64) * sizeof(int), stream);
    hipMemsetAsync(d_out, 0, sizeof(float), stream);

    pass1_partition<<<p1_blocks, blk, 0, stream>>>(erow, ecol, ui_vals, iu_vals,
                                                   cntU, cntI, pcurU, pcurI, pbufU, pbufI);
    exscan_part<<<P_U + P_I, blk, 0, stream>>>(cntU, ptrU, curU, pcurU,
                                               cntI, ptrI, curI, pcurI);
    pass2_scatter<<<p2_blocks, blk, 0, stream>>>(pcurU, pbufU, curU, edgesU,
                                                 pcurI, pbufI, curI, edgesI);

    // L1: u1 = A@i0, gcn_u = u0 + 0.5*u1 ; i1 = At@u0, gcn_i = i0 + 0.5*i1
    spmm_level<0><<<spmm_blocks, blk, 0, stream>>>(
        ptrU, cntU, edgesU, embed_item, uA, embed_user, gcn_u,
        ptrI, cntI, edgesI, embed_user, iA, embed_item, gcn_i, 0.5f);
    // L2: u2 = A@i1, gcn_u += (1/3)*u2 ; i2 = At@u1, gcn_i += (1/3)*i2
    spmm_level<1><<<spmm_blocks, blk, 0, stream>>>(
        ptrU, cntU, edgesU, iA, uB, nullptr, gcn_u,
        ptrI, cntI, edgesI, uA, iB, nullptr, gcn_i, 1.f / 3.f);
    // L3: gcn_u += 0.25*(A@i2) ; gcn_i += 0.25*(At@u2)
    spmm_level<2><<<spmm_blocks, blk, 0, stream>>>(
        ptrU, cntU, edgesU, iB, nullptr, nullptr, gcn_u,
        ptrI, cntI, edgesI, uB, nullptr, nullptr, gcn_i, 0.25f);

    contrastive_both<<<4096, blk, 0, stream>>>(old_U, gcn_u, user, item_i, item_j, degU,
                                               old_I, gcn_i, user_, item_i_, item_j_, degI,
                                               (float*)d_out);
}

// Round 7
// 528.774 us; speedup vs baseline: 2.0579x; 1.0412x over previous
//
#include <hip/hip_runtime.h>

#define U_NUM 50000
#define I_NUM 20000
#define F_DIM 64
#define N_EDGES 1000000
#define BATCH 131072

// Destination partitions for the two-pass build.
#define P_U 25            // partitions of 2048 rows
#define P_I 20            // partitions of 1024 cols
#define CAPP_U 45056      // mean 40960 per full partition, ~+20 sigma
#define CAPP_I 55296      // mean 51200, ~+18 sigma
#define BPU 160           // pass-2 blocks per U partition
#define BPI 200           // pass-2 blocks per I partition

// ---------------- pass 1: partition-grouped append + per-row counts ----------
// Tile = 1024 edges/block. Records are first placed in LDS at
// slot = lbase[p] + lp (i.e. partition-sorted within the tile), then flushed
// to global IN SLOT ORDER: consecutive threads write consecutive addresses
// inside each partition run -> full-line coalesced stores (r6 profile showed
// 78.7MB writeback for 16MB payload when stores scattered straight to HBM).
// Record: x = (src<<16)|dst (both fit 16 bits), y = val bits.
__global__ void pass1_partition(const int* __restrict__ rows, const int* __restrict__ cols,
                                const float* __restrict__ uiv, const float* __restrict__ iuv,
                                int* __restrict__ cntU, int* __restrict__ cntI,
                                int* __restrict__ pcurU, int* __restrict__ pcurI,
                                int2* __restrict__ pbufU, int2* __restrict__ pbufI)
{
    __shared__ int histU[32], histI[32];
    __shared__ int lbaseU[32], lbaseI[32];     // exclusive scan of hist
    __shared__ int deltaU[32], deltaI[32];     // global_addr = delta[p] + slot
    __shared__ int totU, totI;
    __shared__ int2 recU[1024], recI[1024];
    __shared__ unsigned char pidU[1024], pidI[1024];

    if (threadIdx.x < 32) { histU[threadIdx.x] = 0; histI[threadIdx.x] = 0; }
    __syncthreads();

    int base = blockIdx.x * 1024;
    int r[4], c[4], lpU[4], lpI[4];
    float vu[4], vi[4];
    #pragma unroll
    for (int i = 0; i < 4; i++) {
        int e = base + threadIdx.x + i * 256;
        if (e < N_EDGES) {
            r[i] = rows[e]; c[i] = cols[e];
            vu[i] = uiv[e]; vi[i] = iuv[e];
            atomicAdd(&cntU[r[i]], 1);
            atomicAdd(&cntI[c[i]], 1);
            lpU[i] = atomicAdd(&histU[r[i] >> 11], 1);
            lpI[i] = atomicAdd(&histI[c[i] >> 10], 1);
        } else {
            lpU[i] = -1; lpI[i] = -1; r[i] = 0; c[i] = 0; vu[i] = 0.f; vi[i] = 0.f;
        }
    }
    __syncthreads();

    // Wave 0 lanes 0..31: U reservation + scan. Wave 1 lanes 0..31: I.
    int lane = threadIdx.x & 63;
    int w    = threadIdx.x >> 6;
    if (w == 0) {
        int h = (lane < 32) ? histU[lane] : 0;
        int res = (lane < 32 && h) ? atomicAdd(&pcurU[lane], h) : 0;
        int inc = h;
        #pragma unroll
        for (int off = 1; off < 32; off <<= 1) {
            int t = __shfl_up(inc, off, 64);
            if (lane >= off) inc += t;
        }
        if (lane < 32) {
            int lb = inc - h;
            lbaseU[lane] = lb;
            deltaU[lane] = lane * CAPP_U + res - lb;
            if (lane == 31) totU = inc;
        }
    } else if (w == 1) {
        int h = (lane < 32) ? histI[lane] : 0;
        int res = (lane < 32 && h) ? atomicAdd(&pcurI[lane], h) : 0;
        int inc = h;
        #pragma unroll
        for (int off = 1; off < 32; off <<= 1) {
            int t = __shfl_up(inc, off, 64);
            if (lane >= off) inc += t;
        }
        if (lane < 32) {
            int lb = inc - h;
            lbaseI[lane] = lb;
            deltaI[lane] = lane * CAPP_I + res - lb;
            if (lane == 31) totI = inc;
        }
    }
    __syncthreads();

    // Place records partition-sorted in LDS.
    #pragma unroll
    for (int i = 0; i < 4; i++) {
        if (lpU[i] >= 0) {
            int p = r[i] >> 11;
            int slot = lbaseU[p] + lpU[i];
            int2 rec;
            rec.x = (int)(((unsigned)c[i] << 16) | (unsigned)r[i]);
            rec.y = __float_as_int(vu[i]);
            recU[slot] = rec;
            pidU[slot] = (unsigned char)p;

            p = c[i] >> 10;
            slot = lbaseI[p] + lpI[i];
            rec.x = (int)(((unsigned)r[i] << 16) | (unsigned)c[i]);
            rec.y = __float_as_int(vi[i]);
            recI[slot] = rec;
            pidI[slot] = (unsigned char)p;
        }
    }
    __syncthreads();

    // Coalesced flush: consecutive slots -> consecutive global addresses.
    for (int t = threadIdx.x; t < totU; t += 256) {
        int p = pidU[t];
        int a = deltaU[p] + t;
        if (a < (p + 1) * CAPP_U) pbufU[a] = recU[t];
    }
    for (int t = threadIdx.x; t < totI; t += 256) {
        int p = pidI[t];
        int a = deltaI[p] + t;
        if (a < (p + 1) * CAPP_I) pbufI[a] = recI[t];
    }
}

// ---------------- hierarchical exclusive scan --------------------------------
// One block per partition (45 total). Partition base = sum of pass-1 partition
// totals below p; intra-partition offsets via a coalesced 256-entry LDS scan.
__global__ void exscan_part(const int* __restrict__ cntU, int* __restrict__ ptrU,
                            int* __restrict__ curU, const int* __restrict__ pcurU,
                            const int* __restrict__ cntI, int* __restrict__ ptrI,
                            int* __restrict__ curI, const int* __restrict__ pcurI)
{
    const int* cnt; int* ptr; int* cur; const int* pcur;
    int p, psize, n;
    if (blockIdx.x < P_U) {
        cnt = cntU; ptr = ptrU; cur = curU; pcur = pcurU;
        p = blockIdx.x; psize = 2048; n = U_NUM;
    } else {
        cnt = cntI; ptr = ptrI; cur = curI; pcur = pcurI;
        p = blockIdx.x - P_U; psize = 1024; n = I_NUM;
    }
    int base = 0;
    for (int i = 0; i < p; i++) base += pcur[i];

    int ept = psize >> 8;                     // 8 (U) or 4 (I)
    int start = p * psize + threadIdx.x * ept;
    int v[8];
    int local = 0;
    for (int j = 0; j < ept; j++) {
        int idx = start + j;
        v[j] = (idx < n) ? cnt[idx] : 0;
        local += v[j];
    }
    __shared__ int buf[256];
    buf[threadIdx.x] = local;
    __syncthreads();
    for (int off = 1; off < 256; off <<= 1) {
        int t = ((int)threadIdx.x >= off) ? buf[threadIdx.x - off] : 0;
        __syncthreads();
        buf[threadIdx.x] += t;
        __syncthreads();
    }
    int run = base + buf[threadIdx.x] - local;
    for (int j = 0; j < ept; j++) {
        int idx = start + j;
        if (idx < n) {
            ptr[idx] = run;
            cur[idx] = run;
            run += v[j];
        }
    }
}

// ---------------- pass 2: partition -> exact CSR -----------------------------
__global__ void pass2_scatter(const int* __restrict__ pcurU, const int2* __restrict__ pbufU,
                              int* __restrict__ curU, int2* __restrict__ edgesU,
                              const int* __restrict__ pcurI, const int2* __restrict__ pbufI,
                              int* __restrict__ curI, int2* __restrict__ edgesI)
{
    const int* pcur; const int2* pbuf; int* cur; int2* edges;
    int p, b, bpp, capp;
    if (blockIdx.x < P_U * BPU) {
        pcur = pcurU; pbuf = pbufU; cur = curU; edges = edgesU;
        p = blockIdx.x / BPU; b = blockIdx.x % BPU; bpp = BPU; capp = CAPP_U;
    } else {
        int q = blockIdx.x - P_U * BPU;
        pcur = pcurI; pbuf = pbufI; cur = curI; edges = edgesI;
        p = q / BPI; b = q % BPI; bpp = BPI; capp = CAPP_I;
    }
    int n = pcur[p];
    if (n > capp) n = capp;
    const int2* src = pbuf + (size_t)p * capp;
    for (int t = b * 256 + threadIdx.x; t < n; t += bpp * 256) {
        int2 rec = src[t];
        unsigned x = (unsigned)rec.x;
        int dst = (int)(x & 0xFFFFu);
        int s   = (int)(x >> 16);
        int pos = atomicAdd(&cur[dst], 1);
        int2 out;
        out.x = s;
        out.y = rec.y;
        edges[pos] = out;
    }
}

// ---------------- fused-level gather SpMM ------------------------------------
// One wave per destination row; quarter-wave per edge slot; k-loop unrolled x4.
//   MODE 0: dst = acc;  gcn = base + alpha*acc
//   MODE 1: dst = acc;  gcn += alpha*acc
//   MODE 2:             gcn += alpha*acc   (level-3 result never materialized)
template <int MODE>
__global__ void spmm_level(const int* __restrict__ ptrU, const int* __restrict__ cntU,
                           const int2* __restrict__ edgesU, const float* __restrict__ srcU,
                           float* __restrict__ dstU, const float* __restrict__ baseU,
                           float* __restrict__ gcnU,
                           const int* __restrict__ ptrI, const int* __restrict__ cntI,
                           const int2* __restrict__ edgesI, const float* __restrict__ srcI,
                           float* __restrict__ dstI, const float* __restrict__ baseI,
                           float* __restrict__ gcnI,
                           float alpha)
{
    int wave = (blockIdx.x * blockDim.x + threadIdx.x) >> 6;
    bool isU = wave < U_NUM;
    int row = isU ? wave : wave - U_NUM;
    if (!isU && row >= I_NUM) return;

    const int*  ptr   = isU ? ptrU   : ptrI;
    const int*  cnt   = isU ? cntU   : cntI;
    const int2* edges = isU ? edgesU : edgesI;
    const float* semb = isU ? srcU   : srcI;
    float* dst        = isU ? dstU   : dstI;
    const float* base = isU ? baseU  : baseI;
    float* gcn        = isU ? gcnU   : gcnI;

    int lane = threadIdx.x & 63;
    int sub  = lane >> 4;
    int q    = lane & 15;
    int begin = ptr[row];
    int len   = cnt[row];

    float4 a0 = make_float4(0.f, 0.f, 0.f, 0.f);
    float4 a1 = make_float4(0.f, 0.f, 0.f, 0.f);
    float4 a2 = make_float4(0.f, 0.f, 0.f, 0.f);
    float4 a3 = make_float4(0.f, 0.f, 0.f, 0.f);
    int k = sub;
    for (; k + 12 < len; k += 16) {
        int2 e0 = edges[begin + k];
        int2 e1 = edges[begin + k + 4];
        int2 e2 = edges[begin + k + 8];
        int2 e3 = edges[begin + k + 12];
        float4 x0 = ((const float4*)(semb + (size_t)e0.x * F_DIM))[q];
        float4 x1 = ((const float4*)(semb + (size_t)e1.x * F_DIM))[q];
        float4 x2 = ((const float4*)(semb + (size_t)e2.x * F_DIM))[q];
        float4 x3 = ((const float4*)(semb + (size_t)e3.x * F_DIM))[q];
        float v0 = __int_as_float(e0.y), v1 = __int_as_float(e1.y);
        float v2 = __int_as_float(e2.y), v3 = __int_as_float(e3.y);
        a0.x += v0 * x0.x; a0.y += v0 * x0.y; a0.z += v0 * x0.z; a0.w += v0 * x0.w;
        a1.x += v1 * x1.x; a1.y += v1 * x1.y; a1.z += v1 * x1.z; a1.w += v1 * x1.w;
        a2.x += v2 * x2.x; a2.y += v2 * x2.y; a2.z += v2 * x2.z; a2.w += v2 * x2.w;
        a3.x += v3 * x3.x; a3.y += v3 * x3.y; a3.z += v3 * x3.z; a3.w += v3 * x3.w;
    }
    for (; k < len; k += 4) {
        int2 e0 = edges[begin + k];
        float4 x0 = ((const float4*)(semb + (size_t)e0.x * F_DIM))[q];
        float v0 = __int_as_float(e0.y);
        a0.x += v0 * x0.x; a0.y += v0 * x0.y; a0.z += v0 * x0.z; a0.w += v0 * x0.w;
    }
    float4 acc;
    acc.x = (a0.x + a1.x) + (a2.x + a3.x);
    acc.y = (a0.y + a1.y) + (a2.y + a3.y);
    acc.z = (a0.z + a1.z) + (a2.z + a3.z);
    acc.w = (a0.w + a1.w) + (a2.w + a3.w);

    acc.x += __shfl_xor(acc.x, 16, 64);
    acc.y += __shfl_xor(acc.y, 16, 64);
    acc.z += __shfl_xor(acc.z, 16, 64);
    acc.w += __shfl_xor(acc.w, 16, 64);
    acc.x += __shfl_xor(acc.x, 32, 64);
    acc.y += __shfl_xor(acc.y, 32, 64);
    acc.z += __shfl_xor(acc.z, 32, 64);
    acc.w += __shfl_xor(acc.w, 32, 64);

    if (sub == 0) {
        size_t off = (size_t)row * F_DIM;
        if (MODE < 2) ((float4*)(dst + off))[q] = acc;
        float4 g;
        if (MODE == 0) g = ((const float4*)(base + off))[q];
        else           g = ((const float4*)(gcn + off))[q];
        g.x += alpha * acc.x;
        g.y += alpha * acc.y;
        g.z += alpha * acc.z;
        g.w += alpha * acc.w;
        ((float4*)(gcn + off))[q] = g;
    }
}

// ---------------- fused contrastive loss, quarter-wave per sample ------------
// 16 lanes x float4 = one coalesced 256B row load per gather; 4 independent
// samples in flight per wave (vs 1 before); 4-step butterfly reduction.
__global__ void contrastive_both(const float* __restrict__ oldU, const float* __restrict__ gcnU,
                                 const int* __restrict__ userU, const int* __restrict__ iiU,
                                 const int* __restrict__ ijU, const float* __restrict__ degU,
                                 const float* __restrict__ oldI, const float* __restrict__ gcnI,
                                 const int* __restrict__ userI, const int* __restrict__ iiI,
                                 const int* __restrict__ ijI, const float* __restrict__ degI,
                                 float* __restrict__ out)
{
    int lane = threadIdx.x & 63;
    int ql   = lane & 15;
    int gq = (blockIdx.x * blockDim.x + threadIdx.x) >> 4;
    int nq = (gridDim.x * blockDim.x) >> 4;

    float acc = 0.f;
    for (int s = gq; s < 2 * BATCH; s += nq) {
        bool sec = s >= BATCH;
        int b = sec ? s - BATCH : s;
        const float* old_emb = sec ? oldI : oldU;
        const float* gcn     = sec ? gcnI : gcnU;
        const int* iu        = sec ? userI : userU;
        const int* ii        = sec ? iiI : iiU;
        const int* ij        = sec ? ijI : ijU;
        const float* dg      = sec ? degI : degU;
        float inv            = sec ? (1.f / I_NUM) : (1.f / U_NUM);

        int u = iu[b], i = ii[b], j = ij[b];
        float4 uv = ((const float4*)(old_emb + (size_t)u * F_DIM))[ql];
        float4 pi = ((const float4*)(gcn + (size_t)i * F_DIM))[ql];
        float4 pj = ((const float4*)(gcn + (size_t)j * F_DIM))[ql];
        float si = uv.x * pi.x + uv.y * pi.y + uv.z * pi.z + uv.w * pi.w;
        float sj = uv.x * pj.x + uv.y * pj.y + uv.z * pj.z + uv.w * pj.w;
        #pragma unroll
        for (int off = 1; off < 16; off <<= 1) {
            si += __shfl_xor(si, off, 64);
            sj += __shfl_xor(sj, off, 64);
        }
        if (ql == 0) {
            float m = fmaxf(si, sj);
            float lse = m + logf(expf(si - m) + expf(sj - m));
            acc -= (si - lse) * dg[b] * inv;
        }
    }
    // acc is nonzero only on ql==0 lanes; wave sum then block sum.
    #pragma unroll
    for (int off = 32; off > 0; off >>= 1) acc += __shfl_down(acc, off, 64);
    __shared__ float wsum[4];
    if (lane == 0) wsum[threadIdx.x >> 6] = acc;
    __syncthreads();
    if (threadIdx.x == 0)
        atomicAdd(out, wsum[0] + wsum[1] + wsum[2] + wsum[3]);
}

extern "C" void kernel_launch(void* const* d_in, const int* in_sizes, int n_in,
                              void* d_out, int out_size, void* d_ws, size_t ws_size,
                              hipStream_t stream)
{
    const float* embed_user = (const float*)d_in[0];
    const float* embed_item = (const float*)d_in[1];
    const float* old_U      = (const float*)d_in[2];
    const float* old_I      = (const float*)d_in[3];
    const int*   erow       = (const int*)d_in[4];
    const int*   ecol       = (const int*)d_in[5];
    const float* ui_vals    = (const float*)d_in[6];
    const float* iu_vals    = (const float*)d_in[7];
    const int*   user       = (const int*)d_in[8];
    const int*   item_i     = (const int*)d_in[9];
    const int*   item_j     = (const int*)d_in[10];
    const float* degU       = (const float*)d_in[11];
    const int*   user_      = (const int*)d_in[13];
    const int*   item_i_    = (const int*)d_in[14];
    const int*   item_j_    = (const int*)d_in[15];
    const float* degI       = (const float*)d_in[16];

    const size_t UF = (size_t)U_NUM * F_DIM;
    const size_t IF = (size_t)I_NUM * F_DIM;

    int2*  pbufU  = (int2*)d_ws;
    int2*  pbufI  = pbufU + (size_t)P_U * CAPP_U;
    int2*  edgesU = pbufI + (size_t)P_I * CAPP_I;
    int2*  edgesI = edgesU + N_EDGES;
    float* uA     = (float*)(edgesI + N_EDGES);
    float* uB     = uA + UF;
    float* iA     = uB + UF;
    float* iB     = iA + IF;
    float* gcn_u  = iB + IF;
    float* gcn_i  = gcn_u + UF;
    int*   cntU   = (int*)(gcn_i + IF);                 // zeroed region starts here
    int*   cntI   = cntU + U_NUM;
    int*   pcurU  = cntI + I_NUM;
    int*   pcurI  = pcurU + 32;
    int*   ptrU   = pcurI + 32;                         // end of zeroed region
    int*   curU   = ptrU + U_NUM;
    int*   ptrI   = curU + U_NUM;
    int*   curI   = ptrI + I_NUM;

    dim3 blk(256);
    const int p1_blocks = (N_EDGES + 1023) / 1024;             // 977
    const int p2_blocks = P_U * BPU + P_I * BPI;               // 8000
    const int spmm_blocks = (U_NUM + I_NUM) / 4;               // 17500

    hipMemsetAsync(cntU, 0, (U_NUM + I_NUM + 64) * sizeof(int), stream);
    hipMemsetAsync(d_out, 0, sizeof(float), stream);

    pass1_partition<<<p1_blocks, blk, 0, stream>>>(erow, ecol, ui_vals, iu_vals,
                                                   cntU, cntI, pcurU, pcurI, pbufU, pbufI);
    exscan_part<<<P_U + P_I, blk, 0, stream>>>(cntU, ptrU, curU, pcurU,
                                               cntI, ptrI, curI, pcurI);
    pass2_scatter<<<p2_blocks, blk, 0, stream>>>(pcurU, pbufU, curU, edgesU,
                                                 pcurI, pbufI, curI, edgesI);

    // L1: u1 = A@i0, gcn_u = u0 + 0.5*u1 ; i1 = At@u0, gcn_i = i0 + 0.5*i1
    spmm_level<0><<<spmm_blocks, blk, 0, stream>>>(
        ptrU, cntU, edgesU, embed_item, uA, embed_user, gcn_u,
        ptrI, cntI, edgesI, embed_user, iA, embed_item, gcn_i, 0.5f);
    // L2: u2 = A@i1, gcn_u += (1/3)*u2 ; i2 = At@u1, gcn_i += (1/3)*i2
    spmm_level<1><<<spmm_blocks, blk, 0, stream>>>(
        ptrU, cntU, edgesU, iA, uB, nullptr, gcn_u,
        ptrI, cntI, edgesI, uA, iB, nullptr, gcn_i, 1.f / 3.f);
    // L3: gcn_u += 0.25*(A@i2) ; gcn_i += 0.25*(At@u2)
    spmm_level<2><<<spmm_blocks, blk, 0, stream>>>(
        ptrU, cntU, edgesU, iB, nullptr, nullptr, gcn_u,
        ptrI, cntI, edgesI, uB, nullptr, nullptr, gcn_i, 0.25f);

    contrastive_both<<<4096, blk, 0, stream>>>(old_U, gcn_u, user, item_i, item_j, degU,
                                               old_I, gcn_i, user_, item_i_, item_j_, degI,
                                               (float*)d_out);
}

// Round 8
// 415.481 us; speedup vs baseline: 2.6190x; 1.2727x over previous
//
#include <hip/hip_runtime.h>

#define U_NUM 50000
#define I_NUM 20000
#define F_DIM 64
#define N_EDGES 1000000
#define BATCH 131072

// Coarse partitions (pass1) and fine partitions (refine/sort).
#define P_U 25            // coarse: 2048 rows
#define P_I 20            // coarse: 1024 cols
#define CAPP_U 45056      // coarse cap (mean 40960, +20 sigma)
#define CAPP_I 55296      // coarse cap (mean 51200, +18 sigma)
#define FP_U 200          // fine: 256 rows  (25*8)
#define FP_I 160          // fine: 128 cols  (20*8)
#define CAPF_U 5632       // fine cap (mean 5120, +7.2 sigma)
#define CAPF_I 6912       // fine cap (mean 6400, +6.4 sigma)
#define BRU 40            // refine blocks per coarse U partition
#define BRI 50            // refine blocks per coarse I partition

// ---------------- pass 1: coarse partition append (NO per-row atomics) -------
// Record: x = (src<<16)|dst, y = val bits.
__global__ void pass1_partition(const int* __restrict__ rows, const int* __restrict__ cols,
                                const float* __restrict__ uiv, const float* __restrict__ iuv,
                                int* __restrict__ pcurU, int* __restrict__ pcurI,
                                int2* __restrict__ cbufU, int2* __restrict__ cbufI)
{
    __shared__ int histU[32], histI[32];
    __shared__ int lbaseU[32], lbaseI[32];
    __shared__ int deltaU[32], deltaI[32];
    __shared__ int totU, totI;
    __shared__ int2 recU[1024], recI[1024];
    __shared__ unsigned char pidU[1024], pidI[1024];

    if (threadIdx.x < 32) { histU[threadIdx.x] = 0; histI[threadIdx.x] = 0; }
    __syncthreads();

    int base = blockIdx.x * 1024;
    int r[4], c[4], lpU[4], lpI[4];
    float vu[4], vi[4];
    #pragma unroll
    for (int i = 0; i < 4; i++) {
        int e = base + threadIdx.x + i * 256;
        if (e < N_EDGES) {
            r[i] = rows[e]; c[i] = cols[e];
            vu[i] = uiv[e]; vi[i] = iuv[e];
            lpU[i] = atomicAdd(&histU[r[i] >> 11], 1);
            lpI[i] = atomicAdd(&histI[c[i] >> 10], 1);
        } else {
            lpU[i] = -1; lpI[i] = -1; r[i] = 0; c[i] = 0; vu[i] = 0.f; vi[i] = 0.f;
        }
    }
    __syncthreads();

    int lane = threadIdx.x & 63;
    int w    = threadIdx.x >> 6;
    if (w == 0) {
        int h = (lane < 32) ? histU[lane] : 0;
        int res = (lane < 32 && h) ? atomicAdd(&pcurU[lane], h) : 0;
        int inc = h;
        #pragma unroll
        for (int off = 1; off < 32; off <<= 1) {
            int t = __shfl_up(inc, off, 64);
            if (lane >= off) inc += t;
        }
        if (lane < 32) {
            int lb = inc - h;
            lbaseU[lane] = lb;
            deltaU[lane] = lane * CAPP_U + res - lb;
            if (lane == 31) totU = inc;
        }
    } else if (w == 1) {
        int h = (lane < 32) ? histI[lane] : 0;
        int res = (lane < 32 && h) ? atomicAdd(&pcurI[lane], h) : 0;
        int inc = h;
        #pragma unroll
        for (int off = 1; off < 32; off <<= 1) {
            int t = __shfl_up(inc, off, 64);
            if (lane >= off) inc += t;
        }
        if (lane < 32) {
            int lb = inc - h;
            lbaseI[lane] = lb;
            deltaI[lane] = lane * CAPP_I + res - lb;
            if (lane == 31) totI = inc;
        }
    }
    __syncthreads();

    #pragma unroll
    for (int i = 0; i < 4; i++) {
        if (lpU[i] >= 0) {
            int p = r[i] >> 11;
            int slot = lbaseU[p] + lpU[i];
            int2 rec;
            rec.x = (int)(((unsigned)c[i] << 16) | (unsigned)r[i]);
            rec.y = __float_as_int(vu[i]);
            recU[slot] = rec;
            pidU[slot] = (unsigned char)p;

            p = c[i] >> 10;
            slot = lbaseI[p] + lpI[i];
            rec.x = (int)(((unsigned)r[i] << 16) | (unsigned)c[i]);
            rec.y = __float_as_int(vi[i]);
            recI[slot] = rec;
            pidI[slot] = (unsigned char)p;
        }
    }
    __syncthreads();

    for (int t = threadIdx.x; t < totU; t += 256) {
        int p = pidU[t];
        int a = deltaU[p] + t;
        if (a < (p + 1) * CAPP_U) cbufU[a] = recU[t];
    }
    for (int t = threadIdx.x; t < totI; t += 256) {
        int p = pidI[t];
        int a = deltaI[p] + t;
        if (a < (p + 1) * CAPP_I) cbufI[a] = recI[t];
    }
}

// ---------------- refine: coarse -> 8 fine partitions ------------------------
// Tile-staged with 8 bins -> runs of ~128 records (1KB) = full-line coalesced.
__global__ void refine(const int* __restrict__ pcurU, const int2* __restrict__ cbufU,
                       int* __restrict__ fcurU, int2* __restrict__ fbufU,
                       const int* __restrict__ pcurI, const int2* __restrict__ cbufI,
                       int* __restrict__ fcurI, int2* __restrict__ fbufI)
{
    const int* pcur; const int2* cbuf; int* fcur; int2* fbuf;
    int p, b, br, capp, capf, shift;
    if (blockIdx.x < P_U * BRU) {
        pcur = pcurU; cbuf = cbufU; fcur = fcurU; fbuf = fbufU;
        p = blockIdx.x / BRU; b = blockIdx.x % BRU; br = BRU;
        capp = CAPP_U; capf = CAPF_U; shift = 8;
    } else {
        int q = blockIdx.x - P_U * BRU;
        pcur = pcurI; cbuf = cbufI; fcur = fcurI; fbuf = fbufI;
        p = q / BRI; b = q % BRI; br = BRI;
        capp = CAPP_I; capf = CAPF_I; shift = 7;
    }
    int n = min(pcur[p], capp);
    const int2* src = cbuf + (size_t)p * capp;

    __shared__ int hist[8], lbase[8], delta[8];
    __shared__ int tot;
    __shared__ int2 rec[1024];
    __shared__ unsigned char pid[1024];

    for (int base = b * 1024; base < n; base += br * 1024) {
        __syncthreads();
        if (threadIdx.x < 8) hist[threadIdx.x] = 0;
        __syncthreads();
        int2 rr[4]; int ff[4], lp[4];
        #pragma unroll
        for (int i = 0; i < 4; i++) {
            int t = base + i * 256 + threadIdx.x;
            if (t < n) {
                rr[i] = src[t];
                ff[i] = (int)((((unsigned)rr[i].x & 0xFFFFu) >> shift) & 7u);
                lp[i] = atomicAdd(&hist[ff[i]], 1);
            } else lp[i] = -1;
        }
        __syncthreads();
        if ((threadIdx.x >> 6) == 0) {
            int lane = threadIdx.x & 63;
            int h = (lane < 8) ? hist[lane] : 0;
            int res = (lane < 8 && h) ? atomicAdd(&fcur[p * 8 + lane], h) : 0;
            int inc = h;
            #pragma unroll
            for (int off = 1; off < 8; off <<= 1) {
                int t = __shfl_up(inc, off, 64);
                if (lane >= off) inc += t;
            }
            if (lane < 8) {
                int lb = inc - h;
                lbase[lane] = lb;
                delta[lane] = (p * 8 + lane) * capf + res - lb;
                if (lane == 7) tot = inc;
            }
        }
        __syncthreads();
        #pragma unroll
        for (int i = 0; i < 4; i++) {
            if (lp[i] >= 0) {
                int slot = lbase[ff[i]] + lp[i];
                rec[slot] = rr[i];
                pid[slot] = (unsigned char)ff[i];
            }
        }
        __syncthreads();
        for (int t = threadIdx.x; t < tot; t += 256) {
            int f2 = pid[t];
            int a = delta[f2] + t;
            if (a < (p * 8 + f2 + 1) * capf) fbuf[a] = rec[t];
        }
    }
}

// ---------------- sort_csr: fine partition -> exact CSR + ptr/cnt ------------
// One block per fine partition. LDS histogram recovers per-row counts (kills
// the 2M global cnt atomics), LDS cursors place records (kills the 2M global
// cur atomics), and the ~50KB output window has a single CU writer (single
// XCD L2 -> lines fill before writeback).
__global__ void sort_csr(const int* __restrict__ fcurU, const int2* __restrict__ fbufU,
                         int* __restrict__ ptrU, int* __restrict__ cntU, int2* __restrict__ edgesU,
                         const int* __restrict__ fcurI, const int2* __restrict__ fbufI,
                         int* __restrict__ ptrI, int* __restrict__ cntI, int2* __restrict__ edgesI)
{
    __shared__ int hist[256], scan[256], curs[256];
    __shared__ int gbase_s;

    const int* fcur; const int2* fbuf; int* ptr; int* cnt; int2* edges;
    int fp, bins, capf, nrow;
    if (blockIdx.x < FP_U) {
        fcur = fcurU; fbuf = fbufU; ptr = ptrU; cnt = cntU; edges = edgesU;
        fp = blockIdx.x; bins = 256; capf = CAPF_U; nrow = U_NUM;
    } else {
        fcur = fcurI; fbuf = fbufI; ptr = ptrI; cnt = cntI; edges = edgesI;
        fp = blockIdx.x - FP_U; bins = 128; capf = CAPF_I; nrow = I_NUM;
    }

    if (threadIdx.x == 0) gbase_s = 0;
    for (int i = threadIdx.x; i < bins; i += 256) hist[i] = 0;
    __syncthreads();

    // global CSR base = exclusive sum of fine totals below fp (parallel reduce)
    int contrib = ((int)threadIdx.x < fp) ? min(fcur[threadIdx.x], capf) : 0;
    #pragma unroll
    for (int off = 32; off > 0; off >>= 1) contrib += __shfl_down(contrib, off, 64);
    if ((threadIdx.x & 63) == 0 && contrib) atomicAdd(&gbase_s, contrib);

    int n = min(fcur[fp], capf);
    const int2* src = fbuf + (size_t)fp * capf;
    int mask = bins - 1;

    // phase A: histogram of local rows
    for (int t = threadIdx.x; t < n; t += 256) {
        int dst = src[t].x & 0xFFFF;
        atomicAdd(&hist[dst & mask], 1);
    }
    __syncthreads();

    // phase B: inclusive LDS scan -> exclusive offsets
    int v = ((int)threadIdx.x < bins) ? hist[threadIdx.x] : 0;
    scan[threadIdx.x] = v;
    __syncthreads();
    for (int off = 1; off < 256; off <<= 1) {
        int t = ((int)threadIdx.x >= off) ? scan[threadIdx.x - off] : 0;
        __syncthreads();
        scan[threadIdx.x] += t;
        __syncthreads();
    }
    int ex = scan[threadIdx.x] - v;
    curs[threadIdx.x] = ex;
    __syncthreads();
    int gbase = gbase_s;

    if ((int)threadIdx.x < bins) {
        int row = fp * bins + threadIdx.x;
        if (row < nrow) {
            ptr[row] = gbase + ex;
            cnt[row] = v;
        }
    }

    // phase C: place records into exact CSR slots (LDS cursors, no global atomics)
    for (int t = threadIdx.x; t < n; t += 256) {
        int2 r = src[t];
        int dst = r.x & 0xFFFF;
        int pos = atomicAdd(&curs[dst & mask], 1);
        int2 o;
        o.x = (int)((unsigned)r.x >> 16);
        o.y = r.y;
        edges[gbase + pos] = o;
    }
}

// ---------------- fused-level gather SpMM ------------------------------------
template <int MODE>
__global__ void spmm_level(const int* __restrict__ ptrU, const int* __restrict__ cntU,
                           const int2* __restrict__ edgesU, const float* __restrict__ srcU,
                           float* __restrict__ dstU, const float* __restrict__ baseU,
                           float* __restrict__ gcnU,
                           const int* __restrict__ ptrI, const int* __restrict__ cntI,
                           const int2* __restrict__ edgesI, const float* __restrict__ srcI,
                           float* __restrict__ dstI, const float* __restrict__ baseI,
                           float* __restrict__ gcnI,
                           float alpha)
{
    int wave = (blockIdx.x * blockDim.x + threadIdx.x) >> 6;
    bool isU = wave < U_NUM;
    int row = isU ? wave : wave - U_NUM;
    if (!isU && row >= I_NUM) return;

    const int*  ptr   = isU ? ptrU   : ptrI;
    const int*  cnt   = isU ? cntU   : cntI;
    const int2* edges = isU ? edgesU : edgesI;
    const float* semb = isU ? srcU   : srcI;
    float* dst        = isU ? dstU   : dstI;
    const float* base = isU ? baseU  : baseI;
    float* gcn        = isU ? gcnU   : gcnI;

    int lane = threadIdx.x & 63;
    int sub  = lane >> 4;
    int q    = lane & 15;
    int begin = ptr[row];
    int len   = cnt[row];

    float4 a0 = make_float4(0.f, 0.f, 0.f, 0.f);
    float4 a1 = make_float4(0.f, 0.f, 0.f, 0.f);
    float4 a2 = make_float4(0.f, 0.f, 0.f, 0.f);
    float4 a3 = make_float4(0.f, 0.f, 0.f, 0.f);
    int k = sub;
    for (; k + 12 < len; k += 16) {
        int2 e0 = edges[begin + k];
        int2 e1 = edges[begin + k + 4];
        int2 e2 = edges[begin + k + 8];
        int2 e3 = edges[begin + k + 12];
        float4 x0 = ((const float4*)(semb + (size_t)e0.x * F_DIM))[q];
        float4 x1 = ((const float4*)(semb + (size_t)e1.x * F_DIM))[q];
        float4 x2 = ((const float4*)(semb + (size_t)e2.x * F_DIM))[q];
        float4 x3 = ((const float4*)(semb + (size_t)e3.x * F_DIM))[q];
        float v0 = __int_as_float(e0.y), v1 = __int_as_float(e1.y);
        float v2 = __int_as_float(e2.y), v3 = __int_as_float(e3.y);
        a0.x += v0 * x0.x; a0.y += v0 * x0.y; a0.z += v0 * x0.z; a0.w += v0 * x0.w;
        a1.x += v1 * x1.x; a1.y += v1 * x1.y; a1.z += v1 * x1.z; a1.w += v1 * x1.w;
        a2.x += v2 * x2.x; a2.y += v2 * x2.y; a2.z += v2 * x2.z; a2.w += v2 * x2.w;
        a3.x += v3 * x3.x; a3.y += v3 * x3.y; a3.z += v3 * x3.z; a3.w += v3 * x3.w;
    }
    for (; k < len; k += 4) {
        int2 e0 = edges[begin + k];
        float4 x0 = ((const float4*)(semb + (size_t)e0.x * F_DIM))[q];
        float v0 = __int_as_float(e0.y);
        a0.x += v0 * x0.x; a0.y += v0 * x0.y; a0.z += v0 * x0.z; a0.w += v0 * x0.w;
    }
    float4 acc;
    acc.x = (a0.x + a1.x) + (a2.x + a3.x);
    acc.y = (a0.y + a1.y) + (a2.y + a3.y);
    acc.z = (a0.z + a1.z) + (a2.z + a3.z);
    acc.w = (a0.w + a1.w) + (a2.w + a3.w);

    acc.x += __shfl_xor(acc.x, 16, 64);
    acc.y += __shfl_xor(acc.y, 16, 64);
    acc.z += __shfl_xor(acc.z, 16, 64);
    acc.w += __shfl_xor(acc.w, 16, 64);
    acc.x += __shfl_xor(acc.x, 32, 64);
    acc.y += __shfl_xor(acc.y, 32, 64);
    acc.z += __shfl_xor(acc.z, 32, 64);
    acc.w += __shfl_xor(acc.w, 32, 64);

    if (sub == 0) {
        size_t off = (size_t)row * F_DIM;
        if (MODE < 2) ((float4*)(dst + off))[q] = acc;
        float4 g;
        if (MODE == 0) g = ((const float4*)(base + off))[q];
        else           g = ((const float4*)(gcn + off))[q];
        g.x += alpha * acc.x;
        g.y += alpha * acc.y;
        g.z += alpha * acc.z;
        g.w += alpha * acc.w;
        ((float4*)(gcn + off))[q] = g;
    }
}

// ---------------- fused contrastive loss, quarter-wave per sample ------------
__global__ void contrastive_both(const float* __restrict__ oldU, const float* __restrict__ gcnU,
                                 const int* __restrict__ userU, const int* __restrict__ iiU,
                                 const int* __restrict__ ijU, const float* __restrict__ degU,
                                 const float* __restrict__ oldI, const float* __restrict__ gcnI,
                                 const int* __restrict__ userI, const int* __restrict__ iiI,
                                 const int* __restrict__ ijI, const float* __restrict__ degI,
                                 float* __restrict__ out)
{
    int lane = threadIdx.x & 63;
    int ql   = lane & 15;
    int gq = (blockIdx.x * blockDim.x + threadIdx.x) >> 4;
    int nq = (gridDim.x * blockDim.x) >> 4;

    float acc = 0.f;
    for (int s = gq; s < 2 * BATCH; s += nq) {
        bool sec = s >= BATCH;
        int b = sec ? s - BATCH : s;
        const float* old_emb = sec ? oldI : oldU;
        const float* gcn     = sec ? gcnI : gcnU;
        const int* iu        = sec ? userI : userU;
        const int* ii        = sec ? iiI : iiU;
        const int* ij        = sec ? ijI : ijU;
        const float* dg      = sec ? degI : degU;
        float inv            = sec ? (1.f / I_NUM) : (1.f / U_NUM);

        int u = iu[b], i = ii[b], j = ij[b];
        float4 uv = ((const float4*)(old_emb + (size_t)u * F_DIM))[ql];
        float4 pi = ((const float4*)(gcn + (size_t)i * F_DIM))[ql];
        float4 pj = ((const float4*)(gcn + (size_t)j * F_DIM))[ql];
        float si = uv.x * pi.x + uv.y * pi.y + uv.z * pi.z + uv.w * pi.w;
        float sj = uv.x * pj.x + uv.y * pj.y + uv.z * pj.z + uv.w * pj.w;
        #pragma unroll
        for (int off = 1; off < 16; off <<= 1) {
            si += __shfl_xor(si, off, 64);
            sj += __shfl_xor(sj, off, 64);
        }
        if (ql == 0) {
            float m = fmaxf(si, sj);
            float lse = m + logf(expf(si - m) + expf(sj - m));
            acc -= (si - lse) * dg[b] * inv;
        }
    }
    #pragma unroll
    for (int off = 32; off > 0; off >>= 1) acc += __shfl_down(acc, off, 64);
    __shared__ float wsum[4];
    if (lane == 0) wsum[threadIdx.x >> 6] = acc;
    __syncthreads();
    if (threadIdx.x == 0)
        atomicAdd(out, wsum[0] + wsum[1] + wsum[2] + wsum[3]);
}

extern "C" void kernel_launch(void* const* d_in, const int* in_sizes, int n_in,
                              void* d_out, int out_size, void* d_ws, size_t ws_size,
                              hipStream_t stream)
{
    const float* embed_user = (const float*)d_in[0];
    const float* embed_item = (const float*)d_in[1];
    const float* old_U      = (const float*)d_in[2];
    const float* old_I      = (const float*)d_in[3];
    const int*   erow       = (const int*)d_in[4];
    const int*   ecol       = (const int*)d_in[5];
    const float* ui_vals    = (const float*)d_in[6];
    const float* iu_vals    = (const float*)d_in[7];
    const int*   user       = (const int*)d_in[8];
    const int*   item_i     = (const int*)d_in[9];
    const int*   item_j     = (const int*)d_in[10];
    const float* degU       = (const float*)d_in[11];
    const int*   user_      = (const int*)d_in[13];
    const int*   item_i_    = (const int*)d_in[14];
    const int*   item_j_    = (const int*)d_in[15];
    const float* degI       = (const float*)d_in[16];

    const size_t UF = (size_t)U_NUM * F_DIM;
    const size_t IF = (size_t)I_NUM * F_DIM;
    const size_t CREC = (size_t)P_U * CAPP_U + (size_t)P_I * CAPP_I;  // 2,232,320

    // Region 0: coarse buffers, later overlaid by the exact CSR (coarse is dead
    // after refine; CSR total 2M recs <= 2.23M coarse recs).
    int2*  cbufU  = (int2*)d_ws;
    int2*  cbufI  = cbufU + (size_t)P_U * CAPP_U;
    int2*  edgesU = (int2*)d_ws;                 // overlay
    int2*  edgesI = edgesU + N_EDGES;
    // Region 1: fine buffers.
    int2*  fbufU  = cbufU + CREC;
    int2*  fbufI  = fbufU + (size_t)FP_U * CAPF_U;
    // Floats.
    float* uA     = (float*)(fbufI + (size_t)FP_I * CAPF_I);
    float* uB     = uA + UF;
    float* iA     = uB + UF;
    float* iB     = iA + IF;
    float* gcn_u  = iB + IF;
    float* gcn_i  = gcn_u + UF;
    // Aux (zeroed region: pcur + fcur = 576 ints).
    int*   pcurU  = (int*)(gcn_i + IF);
    int*   pcurI  = pcurU + 32;
    int*   fcurU  = pcurI + 32;          // 256 slots (200 used)
    int*   fcurI  = fcurU + 256;         // 256 slots (160 used)
    int*   ptrU   = fcurI + 256;
    int*   cntUa  = ptrU + U_NUM;
    int*   ptrI   = cntUa + U_NUM;
    int*   cntIa  = ptrI + I_NUM;
    // total ~88.2 MB

    dim3 blk(256);
    const int p1_blocks  = (N_EDGES + 1023) / 1024;        // 977
    const int rf_blocks  = P_U * BRU + P_I * BRI;          // 2000
    const int st_blocks  = FP_U + FP_I;                    // 360
    const int spmm_blocks = (U_NUM + I_NUM) / 4;           // 17500

    hipMemsetAsync(pcurU, 0, 576 * sizeof(int), stream);
    hipMemsetAsync(d_out, 0, sizeof(float), stream);

    pass1_partition<<<p1_blocks, blk, 0, stream>>>(erow, ecol, ui_vals, iu_vals,
                                                   pcurU, pcurI, cbufU, cbufI);
    refine<<<rf_blocks, blk, 0, stream>>>(pcurU, cbufU, fcurU, fbufU,
                                          pcurI, cbufI, fcurI, fbufI);
    sort_csr<<<st_blocks, blk, 0, stream>>>(fcurU, fbufU, ptrU, cntUa, edgesU,
                                            fcurI, fbufI, ptrI, cntIa, edgesI);

    // L1: u1 = A@i0, gcn_u = u0 + 0.5*u1 ; i1 = At@u0, gcn_i = i0 + 0.5*i1
    spmm_level<0><<<spmm_blocks, blk, 0, stream>>>(
        ptrU, cntUa, edgesU, embed_item, uA, embed_user, gcn_u,
        ptrI, cntIa, edgesI, embed_user, iA, embed_item, gcn_i, 0.5f);
    // L2: u2 = A@i1, gcn_u += (1/3)*u2 ; i2 = At@u1, gcn_i += (1/3)*i2
    spmm_level<1><<<spmm_blocks, blk, 0, stream>>>(
        ptrU, cntUa, edgesU, iA, uB, nullptr, gcn_u,
        ptrI, cntIa, edgesI, uA, iB, nullptr, gcn_i, 1.f / 3.f);
    // L3: gcn_u += 0.25*(A@i2) ; gcn_i += 0.25*(At@u2)
    spmm_level<2><<<spmm_blocks, blk, 0, stream>>>(
        ptrU, cntUa, edgesU, iB, nullptr, nullptr, gcn_u,
        ptrI, cntIa, edgesI, uB, nullptr, nullptr, gcn_i, 0.25f);

    contrastive_both<<<4096, blk, 0, stream>>>(old_U, gcn_u, user, item_i, item_j, degU,
                                               old_I, gcn_i, user_, item_i_, item_j_, degI,
                                               (float*)d_out);
}

// Round 9
// 375.059 us; speedup vs baseline: 2.9013x; 1.1078x over previous
//
#include <hip/hip_runtime.h>

#define U_NUM 50000
#define I_NUM 20000
#define F_DIM 64
#define N_EDGES 1000000
#define BATCH 131072

// Coarse partitions (pass1) and fine partitions (refine/sort).
#define P_U 25
#define P_I 20
#define CAPP_U 45056
#define CAPP_I 55296
#define FP_U 200
#define FP_I 160
#define CAPF_U 5632
#define CAPF_I 6912
#define BRU 40
#define BRI 50

// ---------------- bf16 helpers ----------------
__device__ __forceinline__ float b2f(unsigned short h) {
    return __uint_as_float((unsigned)h << 16);
}
__device__ __forceinline__ unsigned short f2b(float f) {
    unsigned b = __float_as_uint(f);
    b += 0x7FFFu + ((b >> 16) & 1u);         // round-to-nearest-even
    return (unsigned short)(b >> 16);
}

// ---------------- pass 1: coarse partition append (no per-row atomics) -------
__global__ void pass1_partition(const int* __restrict__ rows, const int* __restrict__ cols,
                                const float* __restrict__ uiv, const float* __restrict__ iuv,
                                int* __restrict__ pcurU, int* __restrict__ pcurI,
                                int2* __restrict__ cbufU, int2* __restrict__ cbufI)
{
    __shared__ int histU[32], histI[32];
    __shared__ int lbaseU[32], lbaseI[32];
    __shared__ int deltaU[32], deltaI[32];
    __shared__ int totU, totI;
    __shared__ int2 recU[1024], recI[1024];
    __shared__ unsigned char pidU[1024], pidI[1024];

    if (threadIdx.x < 32) { histU[threadIdx.x] = 0; histI[threadIdx.x] = 0; }
    __syncthreads();

    int base = blockIdx.x * 1024;
    int r[4], c[4], lpU[4], lpI[4];
    float vu[4], vi[4];
    #pragma unroll
    for (int i = 0; i < 4; i++) {
        int e = base + threadIdx.x + i * 256;
        if (e < N_EDGES) {
            r[i] = rows[e]; c[i] = cols[e];
            vu[i] = uiv[e]; vi[i] = iuv[e];
            lpU[i] = atomicAdd(&histU[r[i] >> 11], 1);
            lpI[i] = atomicAdd(&histI[c[i] >> 10], 1);
        } else {
            lpU[i] = -1; lpI[i] = -1; r[i] = 0; c[i] = 0; vu[i] = 0.f; vi[i] = 0.f;
        }
    }
    __syncthreads();

    int lane = threadIdx.x & 63;
    int w    = threadIdx.x >> 6;
    if (w == 0) {
        int h = (lane < 32) ? histU[lane] : 0;
        int res = (lane < 32 && h) ? atomicAdd(&pcurU[lane], h) : 0;
        int inc = h;
        #pragma unroll
        for (int off = 1; off < 32; off <<= 1) {
            int t = __shfl_up(inc, off, 64);
            if (lane >= off) inc += t;
        }
        if (lane < 32) {
            int lb = inc - h;
            lbaseU[lane] = lb;
            deltaU[lane] = lane * CAPP_U + res - lb;
            if (lane == 31) totU = inc;
        }
    } else if (w == 1) {
        int h = (lane < 32) ? histI[lane] : 0;
        int res = (lane < 32 && h) ? atomicAdd(&pcurI[lane], h) : 0;
        int inc = h;
        #pragma unroll
        for (int off = 1; off < 32; off <<= 1) {
            int t = __shfl_up(inc, off, 64);
            if (lane >= off) inc += t;
        }
        if (lane < 32) {
            int lb = inc - h;
            lbaseI[lane] = lb;
            deltaI[lane] = lane * CAPP_I + res - lb;
            if (lane == 31) totI = inc;
        }
    }
    __syncthreads();

    #pragma unroll
    for (int i = 0; i < 4; i++) {
        if (lpU[i] >= 0) {
            int p = r[i] >> 11;
            int slot = lbaseU[p] + lpU[i];
            int2 rec;
            rec.x = (int)(((unsigned)c[i] << 16) | (unsigned)r[i]);
            rec.y = __float_as_int(vu[i]);
            recU[slot] = rec;
            pidU[slot] = (unsigned char)p;

            p = c[i] >> 10;
            slot = lbaseI[p] + lpI[i];
            rec.x = (int)(((unsigned)r[i] << 16) | (unsigned)c[i]);
            rec.y = __float_as_int(vi[i]);
            recI[slot] = rec;
            pidI[slot] = (unsigned char)p;
        }
    }
    __syncthreads();

    for (int t = threadIdx.x; t < totU; t += 256) {
        int p = pidU[t];
        int a = deltaU[p] + t;
        if (a < (p + 1) * CAPP_U) cbufU[a] = recU[t];
    }
    for (int t = threadIdx.x; t < totI; t += 256) {
        int p = pidI[t];
        int a = deltaI[p] + t;
        if (a < (p + 1) * CAPP_I) cbufI[a] = recI[t];
    }
}

// ---------------- refine: coarse -> 8 fine partitions ------------------------
__global__ void refine(const int* __restrict__ pcurU, const int2* __restrict__ cbufU,
                       int* __restrict__ fcurU, int2* __restrict__ fbufU,
                       const int* __restrict__ pcurI, const int2* __restrict__ cbufI,
                       int* __restrict__ fcurI, int2* __restrict__ fbufI)
{
    const int* pcur; const int2* cbuf; int* fcur; int2* fbuf;
    int p, b, br, capp, capf, shift;
    if (blockIdx.x < P_U * BRU) {
        pcur = pcurU; cbuf = cbufU; fcur = fcurU; fbuf = fbufU;
        p = blockIdx.x / BRU; b = blockIdx.x % BRU; br = BRU;
        capp = CAPP_U; capf = CAPF_U; shift = 8;
    } else {
        int q = blockIdx.x - P_U * BRU;
        pcur = pcurI; cbuf = cbufI; fcur = fcurI; fbuf = fbufI;
        p = q / BRI; b = q % BRI; br = BRI;
        capp = CAPP_I; capf = CAPF_I; shift = 7;
    }
    int n = min(pcur[p], capp);
    const int2* src = cbuf + (size_t)p * capp;

    __shared__ int hist[8], lbase[8], delta[8];
    __shared__ int tot;
    __shared__ int2 rec[1024];
    __shared__ unsigned char pid[1024];

    for (int base = b * 1024; base < n; base += br * 1024) {
        __syncthreads();
        if (threadIdx.x < 8) hist[threadIdx.x] = 0;
        __syncthreads();
        int2 rr[4]; int ff[4], lp[4];
        #pragma unroll
        for (int i = 0; i < 4; i++) {
            int t = base + i * 256 + threadIdx.x;
            if (t < n) {
                rr[i] = src[t];
                ff[i] = (int)((((unsigned)rr[i].x & 0xFFFFu) >> shift) & 7u);
                lp[i] = atomicAdd(&hist[ff[i]], 1);
            } else lp[i] = -1;
        }
        __syncthreads();
        if ((threadIdx.x >> 6) == 0) {
            int lane = threadIdx.x & 63;
            int h = (lane < 8) ? hist[lane] : 0;
            int res = (lane < 8 && h) ? atomicAdd(&fcur[p * 8 + lane], h) : 0;
            int inc = h;
            #pragma unroll
            for (int off = 1; off < 8; off <<= 1) {
                int t = __shfl_up(inc, off, 64);
                if (lane >= off) inc += t;
            }
            if (lane < 8) {
                int lb = inc - h;
                lbase[lane] = lb;
                delta[lane] = (p * 8 + lane) * capf + res - lb;
                if (lane == 7) tot = inc;
            }
        }
        __syncthreads();
        #pragma unroll
        for (int i = 0; i < 4; i++) {
            if (lp[i] >= 0) {
                int slot = lbase[ff[i]] + lp[i];
                rec[slot] = rr[i];
                pid[slot] = (unsigned char)ff[i];
            }
        }
        __syncthreads();
        for (int t = threadIdx.x; t < tot; t += 256) {
            int f2 = pid[t];
            int a = delta[f2] + t;
            if (a < (p * 8 + f2 + 1) * capf) fbuf[a] = rec[t];
        }
    }
}

// ---------------- sort_csr: fine partition -> exact CSR + ptr/cnt ------------
__global__ void sort_csr(const int* __restrict__ fcurU, const int2* __restrict__ fbufU,
                         int* __restrict__ ptrU, int* __restrict__ cntU, int2* __restrict__ edgesU,
                         const int* __restrict__ fcurI, const int2* __restrict__ fbufI,
                         int* __restrict__ ptrI, int* __restrict__ cntI, int2* __restrict__ edgesI)
{
    __shared__ int hist[256], scan[256], curs[256];
    __shared__ int gbase_s;

    const int* fcur; const int2* fbuf; int* ptr; int* cnt; int2* edges;
    int fp, bins, capf, nrow;
    if (blockIdx.x < FP_U) {
        fcur = fcurU; fbuf = fbufU; ptr = ptrU; cnt = cntU; edges = edgesU;
        fp = blockIdx.x; bins = 256; capf = CAPF_U; nrow = U_NUM;
    } else {
        fcur = fcurI; fbuf = fbufI; ptr = ptrI; cnt = cntI; edges = edgesI;
        fp = blockIdx.x - FP_U; bins = 128; capf = CAPF_I; nrow = I_NUM;
    }

    if (threadIdx.x == 0) gbase_s = 0;
    for (int i = threadIdx.x; i < bins; i += 256) hist[i] = 0;
    __syncthreads();

    int contrib = ((int)threadIdx.x < fp) ? min(fcur[threadIdx.x], capf) : 0;
    #pragma unroll
    for (int off = 32; off > 0; off >>= 1) contrib += __shfl_down(contrib, off, 64);
    if ((threadIdx.x & 63) == 0 && contrib) atomicAdd(&gbase_s, contrib);

    int n = min(fcur[fp], capf);
    const int2* src = fbuf + (size_t)fp * capf;
    int mask = bins - 1;

    for (int t = threadIdx.x; t < n; t += 256) {
        int dst = src[t].x & 0xFFFF;
        atomicAdd(&hist[dst & mask], 1);
    }
    __syncthreads();

    int v = ((int)threadIdx.x < bins) ? hist[threadIdx.x] : 0;
    scan[threadIdx.x] = v;
    __syncthreads();
    for (int off = 1; off < 256; off <<= 1) {
        int t = ((int)threadIdx.x >= off) ? scan[threadIdx.x - off] : 0;
        __syncthreads();
        scan[threadIdx.x] += t;
        __syncthreads();
    }
    int ex = scan[threadIdx.x] - v;
    curs[threadIdx.x] = ex;
    __syncthreads();
    int gbase = gbase_s;

    if ((int)threadIdx.x < bins) {
        int row = fp * bins + threadIdx.x;
        if (row < nrow) {
            ptr[row] = gbase + ex;
            cnt[row] = v;
        }
    }

    for (int t = threadIdx.x; t < n; t += 256) {
        int2 r = src[t];
        int dst = r.x & 0xFFFF;
        int pos = atomicAdd(&curs[dst & mask], 1);
        int2 o;
        o.x = (int)((unsigned)r.x >> 16);
        o.y = r.y;
        edges[gbase + pos] = o;
    }
}

// ---------------- fp32 -> bf16 table conversion ------------------------------
#define N4_EU 800000
#define N4_EI 320000
#define N4_OU 800000
#define N4_OI 320000
__global__ void cvt_all(const float* __restrict__ eU, const float* __restrict__ eI,
                        const float* __restrict__ oU, const float* __restrict__ oI,
                        unsigned short* __restrict__ beU, unsigned short* __restrict__ beI,
                        unsigned short* __restrict__ boU, unsigned short* __restrict__ boI)
{
    int idx = blockIdx.x * 256 + threadIdx.x;
    const float* s; unsigned short* d; int off;
    if (idx < N4_EU)                        { s = eU; d = beU; off = idx; }
    else if (idx < N4_EU + N4_EI)           { s = eI; d = beI; off = idx - N4_EU; }
    else if (idx < N4_EU + N4_EI + N4_OU)   { s = oU; d = boU; off = idx - N4_EU - N4_EI; }
    else                                    { s = oI; d = boI; off = idx - N4_EU - N4_EI - N4_OU; }
    float4 v = ((const float4*)s)[off];
    ushort4 r;
    r.x = f2b(v.x); r.y = f2b(v.y); r.z = f2b(v.z); r.w = f2b(v.w);
    ((ushort4*)d)[off] = r;
}

// ---------------- fused-level gather SpMM (bf16 rows, fp32 accumulate) -------
//   MODE 0: dst = bf16(acc);  gcn = base + alpha*acc          (fp32 gcn)
//   MODE 1: dst = bf16(acc);  gcn += alpha*acc                (fp32 gcn)
//   MODE 2: gbf = bf16(gcn + alpha*acc)                       (final, bf16 out)
template <int MODE>
__global__ void spmm_level(const int* __restrict__ ptrU, const int* __restrict__ cntU,
                           const int2* __restrict__ edgesU, const unsigned short* __restrict__ srcU,
                           unsigned short* __restrict__ dstU, const float* __restrict__ baseU,
                           float* __restrict__ gcnU, unsigned short* __restrict__ gbfU,
                           const int* __restrict__ ptrI, const int* __restrict__ cntI,
                           const int2* __restrict__ edgesI, const unsigned short* __restrict__ srcI,
                           unsigned short* __restrict__ dstI, const float* __restrict__ baseI,
                           float* __restrict__ gcnI, unsigned short* __restrict__ gbfI,
                           float alpha)
{
    int wave = (blockIdx.x * blockDim.x + threadIdx.x) >> 6;
    bool isU = wave < U_NUM;
    int row = isU ? wave : wave - U_NUM;
    if (!isU && row >= I_NUM) return;

    const int*  ptr   = isU ? ptrU   : ptrI;
    const int*  cnt   = isU ? cntU   : cntI;
    const int2* edges = isU ? edgesU : edgesI;
    const unsigned short* semb = isU ? srcU : srcI;
    unsigned short* dst = isU ? dstU : dstI;
    const float* base   = isU ? baseU : baseI;
    float* gcn          = isU ? gcnU  : gcnI;
    unsigned short* gbf = isU ? gbfU  : gbfI;

    int lane = threadIdx.x & 63;
    int sub  = lane >> 4;
    int q    = lane & 15;
    int begin = ptr[row];
    int len   = cnt[row];

    float4 a0 = make_float4(0.f, 0.f, 0.f, 0.f);
    float4 a1 = make_float4(0.f, 0.f, 0.f, 0.f);
    float4 a2 = make_float4(0.f, 0.f, 0.f, 0.f);
    float4 a3 = make_float4(0.f, 0.f, 0.f, 0.f);
    int k = sub;
    for (; k + 12 < len; k += 16) {
        int2 e0 = edges[begin + k];
        int2 e1 = edges[begin + k + 4];
        int2 e2 = edges[begin + k + 8];
        int2 e3 = edges[begin + k + 12];
        ushort4 x0 = ((const ushort4*)(semb + ((size_t)e0.x << 6)))[q];
        ushort4 x1 = ((const ushort4*)(semb + ((size_t)e1.x << 6)))[q];
        ushort4 x2 = ((const ushort4*)(semb + ((size_t)e2.x << 6)))[q];
        ushort4 x3 = ((const ushort4*)(semb + ((size_t)e3.x << 6)))[q];
        float v0 = __int_as_float(e0.y), v1 = __int_as_float(e1.y);
        float v2 = __int_as_float(e2.y), v3 = __int_as_float(e3.y);
        a0.x += v0 * b2f(x0.x); a0.y += v0 * b2f(x0.y); a0.z += v0 * b2f(x0.z); a0.w += v0 * b2f(x0.w);
        a1.x += v1 * b2f(x1.x); a1.y += v1 * b2f(x1.y); a1.z += v1 * b2f(x1.z); a1.w += v1 * b2f(x1.w);
        a2.x += v2 * b2f(x2.x); a2.y += v2 * b2f(x2.y); a2.z += v2 * b2f(x2.z); a2.w += v2 * b2f(x2.w);
        a3.x += v3 * b2f(x3.x); a3.y += v3 * b2f(x3.y); a3.z += v3 * b2f(x3.z); a3.w += v3 * b2f(x3.w);
    }
    for (; k < len; k += 4) {
        int2 e0 = edges[begin + k];
        ushort4 x0 = ((const ushort4*)(semb + ((size_t)e0.x << 6)))[q];
        float v0 = __int_as_float(e0.y);
        a0.x += v0 * b2f(x0.x); a0.y += v0 * b2f(x0.y); a0.z += v0 * b2f(x0.z); a0.w += v0 * b2f(x0.w);
    }
    float4 acc;
    acc.x = (a0.x + a1.x) + (a2.x + a3.x);
    acc.y = (a0.y + a1.y) + (a2.y + a3.y);
    acc.z = (a0.z + a1.z) + (a2.z + a3.z);
    acc.w = (a0.w + a1.w) + (a2.w + a3.w);

    acc.x += __shfl_xor(acc.x, 16, 64);
    acc.y += __shfl_xor(acc.y, 16, 64);
    acc.z += __shfl_xor(acc.z, 16, 64);
    acc.w += __shfl_xor(acc.w, 16, 64);
    acc.x += __shfl_xor(acc.x, 32, 64);
    acc.y += __shfl_xor(acc.y, 32, 64);
    acc.z += __shfl_xor(acc.z, 32, 64);
    acc.w += __shfl_xor(acc.w, 32, 64);

    if (sub == 0) {
        size_t off = (size_t)row * F_DIM;
        if (MODE < 2) {
            ushort4 o;
            o.x = f2b(acc.x); o.y = f2b(acc.y); o.z = f2b(acc.z); o.w = f2b(acc.w);
            ((ushort4*)(dst + off))[q] = o;
        }
        float4 g;
        if (MODE == 0) g = ((const float4*)(base + off))[q];
        else           g = ((const float4*)(gcn + off))[q];
        g.x += alpha * acc.x;
        g.y += alpha * acc.y;
        g.z += alpha * acc.z;
        g.w += alpha * acc.w;
        if (MODE < 2) {
            ((float4*)(gcn + off))[q] = g;
        } else {
            ushort4 o;
            o.x = f2b(g.x); o.y = f2b(g.y); o.z = f2b(g.z); o.w = f2b(g.w);
            ((ushort4*)(gbf + off))[q] = o;
        }
    }
}

// ---------------- contrastive loss: bf16 rows, 4 samples per quarter-wave ----
__device__ __forceinline__ float dot4b(const ushort4& a, const ushort4& b) {
    return b2f(a.x) * b2f(b.x) + b2f(a.y) * b2f(b.y)
         + b2f(a.z) * b2f(b.z) + b2f(a.w) * b2f(b.w);
}
__device__ __forceinline__ ushort4 ldrow(const unsigned short* t, int row, int ql) {
    return ((const ushort4*)(t + ((size_t)row << 6)))[ql];
}

__global__ void contrastive_both(const unsigned short* __restrict__ oldU, const unsigned short* __restrict__ gcnU,
                                 const int* __restrict__ userU, const int* __restrict__ iiU,
                                 const int* __restrict__ ijU, const float* __restrict__ degU,
                                 const unsigned short* __restrict__ oldI, const unsigned short* __restrict__ gcnI,
                                 const int* __restrict__ userI, const int* __restrict__ iiI,
                                 const int* __restrict__ ijI, const float* __restrict__ degI,
                                 float* __restrict__ out)
{
    int lane = threadIdx.x & 63;
    int ql   = lane & 15;
    int gq = (blockIdx.x * blockDim.x + threadIdx.x) >> 4;   // 0..65535 (grid=4096)
    int b0 = gq, b1 = gq + 65536;                            // both halves of each BATCH

    int ua0 = userU[b0], ia0 = iiU[b0], ja0 = ijU[b0];
    int ua1 = userU[b1], ia1 = iiU[b1], ja1 = ijU[b1];
    int ub0 = userI[b0], ib0 = iiI[b0], jb0 = ijI[b0];
    int ub1 = userI[b1], ib1 = iiI[b1], jb1 = ijI[b1];

    ushort4 A0u = ldrow(oldU, ua0, ql), A0i = ldrow(gcnU, ia0, ql), A0j = ldrow(gcnU, ja0, ql);
    ushort4 A1u = ldrow(oldU, ua1, ql), A1i = ldrow(gcnU, ia1, ql), A1j = ldrow(gcnU, ja1, ql);
    ushort4 B0u = ldrow(oldI, ub0, ql), B0i = ldrow(gcnI, ib0, ql), B0j = ldrow(gcnI, jb0, ql);
    ushort4 B1u = ldrow(oldI, ub1, ql), B1i = ldrow(gcnI, ib1, ql), B1j = ldrow(gcnI, jb1, ql);

    float si0 = dot4b(A0u, A0i), sj0 = dot4b(A0u, A0j);
    float si1 = dot4b(A1u, A1i), sj1 = dot4b(A1u, A1j);
    float si2 = dot4b(B0u, B0i), sj2 = dot4b(B0u, B0j);
    float si3 = dot4b(B1u, B1i), sj3 = dot4b(B1u, B1j);

    #pragma unroll
    for (int off = 1; off < 16; off <<= 1) {
        si0 += __shfl_xor(si0, off, 64); sj0 += __shfl_xor(sj0, off, 64);
        si1 += __shfl_xor(si1, off, 64); sj1 += __shfl_xor(sj1, off, 64);
        si2 += __shfl_xor(si2, off, 64); sj2 += __shfl_xor(sj2, off, 64);
        si3 += __shfl_xor(si3, off, 64); sj3 += __shfl_xor(sj3, off, 64);
    }

    float acc = 0.f;
    if (ql == 0) {
        const float invU = 1.f / U_NUM, invI = 1.f / I_NUM;
        float m, lse;
        m = fmaxf(si0, sj0); lse = m + logf(expf(si0 - m) + expf(sj0 - m));
        acc -= (si0 - lse) * degU[b0] * invU;
        m = fmaxf(si1, sj1); lse = m + logf(expf(si1 - m) + expf(sj1 - m));
        acc -= (si1 - lse) * degU[b1] * invU;
        m = fmaxf(si2, sj2); lse = m + logf(expf(si2 - m) + expf(sj2 - m));
        acc -= (si2 - lse) * degI[b0] * invI;
        m = fmaxf(si3, sj3); lse = m + logf(expf(si3 - m) + expf(sj3 - m));
        acc -= (si3 - lse) * degI[b1] * invI;
    }
    #pragma unroll
    for (int off = 32; off > 0; off >>= 1) acc += __shfl_down(acc, off, 64);
    __shared__ float wsum[4];
    if (lane == 0) wsum[threadIdx.x >> 6] = acc;
    __syncthreads();
    if (threadIdx.x == 0)
        atomicAdd(out, wsum[0] + wsum[1] + wsum[2] + wsum[3]);
}

extern "C" void kernel_launch(void* const* d_in, const int* in_sizes, int n_in,
                              void* d_out, int out_size, void* d_ws, size_t ws_size,
                              hipStream_t stream)
{
    const float* embed_user = (const float*)d_in[0];
    const float* embed_item = (const float*)d_in[1];
    const float* old_U      = (const float*)d_in[2];
    const float* old_I      = (const float*)d_in[3];
    const int*   erow       = (const int*)d_in[4];
    const int*   ecol       = (const int*)d_in[5];
    const float* ui_vals    = (const float*)d_in[6];
    const float* iu_vals    = (const float*)d_in[7];
    const int*   user       = (const int*)d_in[8];
    const int*   item_i     = (const int*)d_in[9];
    const int*   item_j     = (const int*)d_in[10];
    const float* degU       = (const float*)d_in[11];
    const int*   user_      = (const int*)d_in[13];
    const int*   item_i_    = (const int*)d_in[14];
    const int*   item_j_    = (const int*)d_in[15];
    const float* degI       = (const float*)d_in[16];

    const size_t UF = (size_t)U_NUM * F_DIM;    // 3.2M
    const size_t IF = (size_t)I_NUM * F_DIM;    // 1.28M
    const size_t CREC = (size_t)P_U * CAPP_U + (size_t)P_I * CAPP_I;   // 2,232,320
    const size_t FREC = (size_t)FP_U * CAPF_U + (size_t)FP_I * CAPF_I; // 2,232,320

    // Region 0: coarse buffers, overlaid by the exact CSR after refine.
    int2*  cbufU  = (int2*)d_ws;
    int2*  cbufI  = cbufU + (size_t)P_U * CAPP_U;
    int2*  edgesU = (int2*)d_ws;                 // overlay (2M <= 2.23M recs)
    int2*  edgesI = edgesU + N_EDGES;
    // Region 1: fine buffers, overlaid by bf16 embed/old tables after sort_csr.
    int2*  fbufU  = cbufU + CREC;
    int2*  fbufI  = fbufU + (size_t)FP_U * CAPF_U;
    unsigned short* beU = (unsigned short*)fbufU;          // 3.2M us
    unsigned short* beI = beU + UF;                        // 1.28M
    unsigned short* boU = beI + IF;                        // 3.2M  (15.36MB <= 17.86MB) ok
    // fp32 gcn accumulators.
    float* gcn_u = (float*)(((char*)d_ws) + CREC * 8 + FREC * 8);
    float* gcn_i = gcn_u + UF;
    // fresh bf16 buffers.
    unsigned short* uAb  = (unsigned short*)(gcn_i + IF);  // u1 bf16
    unsigned short* uBb  = uAb + UF;                       // u2
    unsigned short* iAb  = uBb + UF;                       // i1
    unsigned short* iBb  = iAb + IF;                       // i2
    unsigned short* gbfU = iBb + IF;                       // final gcn_u bf16
    unsigned short* gbfI = gbfU + UF;
    unsigned short* boI  = gbfI + IF;                      // old_I bf16 (didn't fit overlay)
    // aux ints (zeroed region: pcur + fcur = 576 ints).
    int* pcurU = (int*)(boI + IF);
    int* pcurI = pcurU + 32;
    int* fcurU = pcurI + 32;
    int* fcurI = fcurU + 256;
    int* ptrU  = fcurI + 256;
    int* cntUa = ptrU + U_NUM;
    int* ptrI  = cntUa + U_NUM;
    int* cntIa = ptrI + I_NUM;
    // total ~84 MB

    dim3 blk(256);
    const int p1_blocks  = (N_EDGES + 1023) / 1024;        // 977
    const int rf_blocks  = P_U * BRU + P_I * BRI;          // 2000
    const int st_blocks  = FP_U + FP_I;                    // 360
    const int cv_blocks  = (N4_EU + N4_EI + N4_OU + N4_OI + 255) / 256;  // 8750
    const int spmm_blocks = (U_NUM + I_NUM) / 4;           // 17500

    hipMemsetAsync(pcurU, 0, 576 * sizeof(int), stream);
    hipMemsetAsync(d_out, 0, sizeof(float), stream);

    pass1_partition<<<p1_blocks, blk, 0, stream>>>(erow, ecol, ui_vals, iu_vals,
                                                   pcurU, pcurI, cbufU, cbufI);
    refine<<<rf_blocks, blk, 0, stream>>>(pcurU, cbufU, fcurU, fbufU,
                                          pcurI, cbufI, fcurI, fbufI);
    sort_csr<<<st_blocks, blk, 0, stream>>>(fcurU, fbufU, ptrU, cntUa, edgesU,
                                            fcurI, fbufI, ptrI, cntIa, edgesI);
    // Convert fp32 tables to bf16 (overlays the now-dead fine buffers).
    cvt_all<<<cv_blocks, blk, 0, stream>>>(embed_user, embed_item, old_U, old_I,
                                           beU, beI, boU, boI);

    // L1: u1 = A@i0, gcn_u = u0 + 0.5*u1 ; i1 = At@u0, gcn_i = i0 + 0.5*i1
    spmm_level<0><<<spmm_blocks, blk, 0, stream>>>(
        ptrU, cntUa, edgesU, beI, uAb, embed_user, gcn_u, gbfU,
        ptrI, cntIa, edgesI, beU, iAb, embed_item, gcn_i, gbfI, 0.5f);
    // L2: u2 = A@i1, gcn_u += (1/3)*u2 ; i2 = At@u1, gcn_i += (1/3)*i2
    spmm_level<1><<<spmm_blocks, blk, 0, stream>>>(
        ptrU, cntUa, edgesU, iAb, uBb, nullptr, gcn_u, gbfU,
        ptrI, cntIa, edgesI, uAb, iBb, nullptr, gcn_i, gbfI, 1.f / 3.f);
    // L3: gbf = bf16(gcn + 0.25*level3)
    spmm_level<2><<<spmm_blocks, blk, 0, stream>>>(
        ptrU, cntUa, edgesU, iBb, nullptr, nullptr, gcn_u, gbfU,
        ptrI, cntIa, edgesI, uBb, nullptr, nullptr, gcn_i, gbfI, 0.25f);

    contrastive_both<<<4096, blk, 0, stream>>>(boU, gbfU, user, item_i, item_j, degU,
                                               boI, gbfI, user_, item_i_, item_j_, degI,
                                               (float*)d_out);
}

// Round 10
// 350.217 us; speedup vs baseline: 3.1071x; 1.0709x over previous
//
#include <hip/hip_runtime.h>

#define U_NUM 50000
#define I_NUM 20000
#define F_DIM 64
#define N_EDGES 1000000
#define BATCH 131072

#define P_U 25
#define P_I 20
#define CAPP_U 45056
#define CAPP_I 55296
#define FP_U 200
#define FP_I 160
#define CAPF_U 5632
#define CAPF_I 6912
#define BRU 40
#define BRI 50
#define P1B 977            // (N_EDGES+1023)/1024

// fp8 e4m3 (OCP) helpers; HW converts on gfx950, software fallback otherwise.
#if defined(__has_builtin)
#if __has_builtin(__builtin_amdgcn_cvt_pk_f32_fp8) && __has_builtin(__builtin_amdgcn_cvt_pk_fp8_f32)
#define HW_FP8 1
#endif
#endif

typedef float v2f __attribute__((ext_vector_type(2)));

__device__ __forceinline__ void dec4(unsigned u, float* f) {
#ifdef HW_FP8
    v2f lo = __builtin_amdgcn_cvt_pk_f32_fp8((int)u, false);
    v2f hi = __builtin_amdgcn_cvt_pk_f32_fp8((int)u, true);
    f[0] = lo.x; f[1] = lo.y; f[2] = hi.x; f[3] = hi.y;
#else
    #pragma unroll
    for (int i = 0; i < 4; i++) {
        unsigned v = (u >> (8 * i)) & 0xFFu;
        unsigned s = v >> 7, e = (v >> 3) & 15u, m = v & 7u;
        float mag = (e == 0) ? (float)m * 0.001953125f
                             : __uint_as_float(((e + 120u) << 23) | (m << 20));
        f[i] = s ? -mag : mag;
    }
#endif
}

#ifndef HW_FP8
__device__ __forceinline__ unsigned char enc1(float x) {
    unsigned s = (__float_as_uint(x) >> 31) << 7;
    float a = fabsf(x);
    if (a >= 448.f) return (unsigned char)(s | 0x7E);
    if (a < 0.015625f) {
        int m = __float2int_rn(a * 512.f);
        if (m >= 8) return (unsigned char)(s | 0x08);
        return (unsigned char)(s | m);
    }
    unsigned au = __float_as_uint(a);
    au += 0x7FFFFu + ((au >> 20) & 1u);
    int e = (int)(au >> 23) - 127;
    if (e > 8) return (unsigned char)(s | 0x7E);
    return (unsigned char)(s | ((unsigned)(e + 7) << 3) | ((au >> 20) & 7u));
}
#endif

__device__ __forceinline__ unsigned enc4(float a, float b, float c, float d) {
#ifdef HW_FP8
    int v = __builtin_amdgcn_cvt_pk_fp8_f32(a, b, 0, false);
    v = __builtin_amdgcn_cvt_pk_fp8_f32(c, d, v, true);
    return (unsigned)v;
#else
    return (unsigned)enc1(a) | ((unsigned)enc1(b) << 8)
         | ((unsigned)enc1(c) << 16) | ((unsigned)enc1(d) << 24);
#endif
}

// ---------------- pass 1 (+ merged fp32->fp8 table cvt) ----------------------
#define N_EU 800000
#define N_EI 320000
#define N_OU 800000
#define N_OI 320000
__global__ void pass1_cvt(const int* __restrict__ rows, const int* __restrict__ cols,
                          const float* __restrict__ uiv, const float* __restrict__ iuv,
                          int* __restrict__ pcurU, int* __restrict__ pcurI,
                          int2* __restrict__ cbufU, int2* __restrict__ cbufI,
                          const float* __restrict__ eU, const float* __restrict__ eI,
                          const float* __restrict__ oU, const float* __restrict__ oI,
                          unsigned* __restrict__ e8U, unsigned* __restrict__ e8I,
                          unsigned* __restrict__ o8U, unsigned* __restrict__ o8I)
{
    if (blockIdx.x >= P1B) {
        // table conversion blocks (independent of pass1 work)
        int idx = (blockIdx.x - P1B) * 256 + threadIdx.x;
        const float* s; unsigned* d; int off; float sc;
        if (idx < N_EU)                        { s = eU; d = e8U; off = idx; sc = 128.f; }
        else if (idx < N_EU + N_EI)            { s = eI; d = e8I; off = idx - N_EU; sc = 128.f; }
        else if (idx < N_EU + N_EI + N_OU)     { s = oU; d = o8U; off = idx - N_EU - N_EI; sc = 1.f; }
        else if (idx < N_EU + N_EI + N_OU + N_OI) { s = oI; d = o8I; off = idx - N_EU - N_EI - N_OU; sc = 1.f; }
        else return;
        float4 v = ((const float4*)s)[off];
        d[off] = enc4(v.x * sc, v.y * sc, v.z * sc, v.w * sc);
        return;
    }

    __shared__ int histU[32], histI[32];
    __shared__ int lbaseU[32], lbaseI[32];
    __shared__ int deltaU[32], deltaI[32];
    __shared__ int totU, totI;
    __shared__ int2 recU[1024], recI[1024];
    __shared__ unsigned char pidU[1024], pidI[1024];

    if (threadIdx.x < 32) { histU[threadIdx.x] = 0; histI[threadIdx.x] = 0; }
    __syncthreads();

    int base = blockIdx.x * 1024;
    int r[4], c[4], lpU[4], lpI[4];
    float vu[4], vi[4];
    #pragma unroll
    for (int i = 0; i < 4; i++) {
        int e = base + threadIdx.x + i * 256;
        if (e < N_EDGES) {
            r[i] = rows[e]; c[i] = cols[e];
            vu[i] = uiv[e]; vi[i] = iuv[e];
            lpU[i] = atomicAdd(&histU[r[i] >> 11], 1);
            lpI[i] = atomicAdd(&histI[c[i] >> 10], 1);
        } else {
            lpU[i] = -1; lpI[i] = -1; r[i] = 0; c[i] = 0; vu[i] = 0.f; vi[i] = 0.f;
        }
    }
    __syncthreads();

    int lane = threadIdx.x & 63;
    int w    = threadIdx.x >> 6;
    if (w == 0) {
        int h = (lane < 32) ? histU[lane] : 0;
        int res = (lane < 32 && h) ? atomicAdd(&pcurU[lane], h) : 0;
        int inc = h;
        #pragma unroll
        for (int off = 1; off < 32; off <<= 1) {
            int t = __shfl_up(inc, off, 64);
            if (lane >= off) inc += t;
        }
        if (lane < 32) {
            int lb = inc - h;
            lbaseU[lane] = lb;
            deltaU[lane] = lane * CAPP_U + res - lb;
            if (lane == 31) totU = inc;
        }
    } else if (w == 1) {
        int h = (lane < 32) ? histI[lane] : 0;
        int res = (lane < 32 && h) ? atomicAdd(&pcurI[lane], h) : 0;
        int inc = h;
        #pragma unroll
        for (int off = 1; off < 32; off <<= 1) {
            int t = __shfl_up(inc, off, 64);
            if (lane >= off) inc += t;
        }
        if (lane < 32) {
            int lb = inc - h;
            lbaseI[lane] = lb;
            deltaI[lane] = lane * CAPP_I + res - lb;
            if (lane == 31) totI = inc;
        }
    }
    __syncthreads();

    #pragma unroll
    for (int i = 0; i < 4; i++) {
        if (lpU[i] >= 0) {
            int p = r[i] >> 11;
            int slot = lbaseU[p] + lpU[i];
            int2 rec;
            rec.x = (int)(((unsigned)c[i] << 16) | (unsigned)r[i]);
            rec.y = __float_as_int(vu[i]);
            recU[slot] = rec;
            pidU[slot] = (unsigned char)p;

            p = c[i] >> 10;
            slot = lbaseI[p] + lpI[i];
            rec.x = (int)(((unsigned)r[i] << 16) | (unsigned)c[i]);
            rec.y = __float_as_int(vi[i]);
            recI[slot] = rec;
            pidI[slot] = (unsigned char)p;
        }
    }
    __syncthreads();

    for (int t = threadIdx.x; t < totU; t += 256) {
        int p = pidU[t];
        int a = deltaU[p] + t;
        if (a < (p + 1) * CAPP_U) cbufU[a] = recU[t];
    }
    for (int t = threadIdx.x; t < totI; t += 256) {
        int p = pidI[t];
        int a = deltaI[p] + t;
        if (a < (p + 1) * CAPP_I) cbufI[a] = recI[t];
    }
}

// ---------------- refine: coarse -> 8 fine partitions ------------------------
__global__ void refine(const int* __restrict__ pcurU, const int2* __restrict__ cbufU,
                       int* __restrict__ fcurU, int2* __restrict__ fbufU,
                       const int* __restrict__ pcurI, const int2* __restrict__ cbufI,
                       int* __restrict__ fcurI, int2* __restrict__ fbufI)
{
    const int* pcur; const int2* cbuf; int* fcur; int2* fbuf;
    int p, b, br, capp, capf, shift;
    if (blockIdx.x < P_U * BRU) {
        pcur = pcurU; cbuf = cbufU; fcur = fcurU; fbuf = fbufU;
        p = blockIdx.x / BRU; b = blockIdx.x % BRU; br = BRU;
        capp = CAPP_U; capf = CAPF_U; shift = 8;
    } else {
        int q = blockIdx.x - P_U * BRU;
        pcur = pcurI; cbuf = cbufI; fcur = fcurI; fbuf = fbufI;
        p = q / BRI; b = q % BRI; br = BRI;
        capp = CAPP_I; capf = CAPF_I; shift = 7;
    }
    int n = min(pcur[p], capp);
    const int2* src = cbuf + (size_t)p * capp;

    __shared__ int hist[8], lbase[8], delta[8];
    __shared__ int tot;
    __shared__ int2 rec[1024];
    __shared__ unsigned char pid[1024];

    for (int base = b * 1024; base < n; base += br * 1024) {
        __syncthreads();
        if (threadIdx.x < 8) hist[threadIdx.x] = 0;
        __syncthreads();
        int2 rr[4]; int ff[4], lp[4];
        #pragma unroll
        for (int i = 0; i < 4; i++) {
            int t = base + i * 256 + threadIdx.x;
            if (t < n) {
                rr[i] = src[t];
                ff[i] = (int)((((unsigned)rr[i].x & 0xFFFFu) >> shift) & 7u);
                lp[i] = atomicAdd(&hist[ff[i]], 1);
            } else lp[i] = -1;
        }
        __syncthreads();
        if ((threadIdx.x >> 6) == 0) {
            int lane = threadIdx.x & 63;
            int h = (lane < 8) ? hist[lane] : 0;
            int res = (lane < 8 && h) ? atomicAdd(&fcur[p * 8 + lane], h) : 0;
            int inc = h;
            #pragma unroll
            for (int off = 1; off < 8; off <<= 1) {
                int t = __shfl_up(inc, off, 64);
                if (lane >= off) inc += t;
            }
            if (lane < 8) {
                int lb = inc - h;
                lbase[lane] = lb;
                delta[lane] = (p * 8 + lane) * capf + res - lb;
                if (lane == 7) tot = inc;
            }
        }
        __syncthreads();
        #pragma unroll
        for (int i = 0; i < 4; i++) {
            if (lp[i] >= 0) {
                int slot = lbase[ff[i]] + lp[i];
                rec[slot] = rr[i];
                pid[slot] = (unsigned char)ff[i];
            }
        }
        __syncthreads();
        for (int t = threadIdx.x; t < tot; t += 256) {
            int f2 = pid[t];
            int a = delta[f2] + t;
            if (a < (p * 8 + f2 + 1) * capf) fbuf[a] = rec[t];
        }
    }
}

// ---------------- sort_csr: fine partition -> exact CSR + ptr/cnt ------------
__global__ void sort_csr(const int* __restrict__ fcurU, const int2* __restrict__ fbufU,
                         int* __restrict__ ptrU, int* __restrict__ cntU, int2* __restrict__ edgesU,
                         const int* __restrict__ fcurI, const int2* __restrict__ fbufI,
                         int* __restrict__ ptrI, int* __restrict__ cntI, int2* __restrict__ edgesI)
{
    __shared__ int hist[256], scan[256], curs[256];
    __shared__ int gbase_s;

    const int* fcur; const int2* fbuf; int* ptr; int* cnt; int2* edges;
    int fp, bins, capf, nrow;
    if (blockIdx.x < FP_U) {
        fcur = fcurU; fbuf = fbufU; ptr = ptrU; cnt = cntU; edges = edgesU;
        fp = blockIdx.x; bins = 256; capf = CAPF_U; nrow = U_NUM;
    } else {
        fcur = fcurI; fbuf = fbufI; ptr = ptrI; cnt = cntI; edges = edgesI;
        fp = blockIdx.x - FP_U; bins = 128; capf = CAPF_I; nrow = I_NUM;
    }

    if (threadIdx.x == 0) gbase_s = 0;
    for (int i = threadIdx.x; i < bins; i += 256) hist[i] = 0;
    __syncthreads();

    int contrib = ((int)threadIdx.x < fp) ? min(fcur[threadIdx.x], capf) : 0;
    #pragma unroll
    for (int off = 32; off > 0; off >>= 1) contrib += __shfl_down(contrib, off, 64);
    if ((threadIdx.x & 63) == 0 && contrib) atomicAdd(&gbase_s, contrib);

    int n = min(fcur[fp], capf);
    const int2* src = fbuf + (size_t)fp * capf;
    int mask = bins - 1;

    for (int t = threadIdx.x; t < n; t += 256) {
        int dst = src[t].x & 0xFFFF;
        atomicAdd(&hist[dst & mask], 1);
    }
    __syncthreads();

    int v = ((int)threadIdx.x < bins) ? hist[threadIdx.x] : 0;
    scan[threadIdx.x] = v;
    __syncthreads();
    for (int off = 1; off < 256; off <<= 1) {
        int t = ((int)threadIdx.x >= off) ? scan[threadIdx.x - off] : 0;
        __syncthreads();
        scan[threadIdx.x] += t;
        __syncthreads();
    }
    int ex = scan[threadIdx.x] - v;
    curs[threadIdx.x] = ex;
    __syncthreads();
    int gbase = gbase_s;

    if ((int)threadIdx.x < bins) {
        int row = fp * bins + threadIdx.x;
        if (row < nrow) {
            ptr[row] = gbase + ex;
            cnt[row] = v;
        }
    }

    for (int t = threadIdx.x; t < n; t += 256) {
        int2 r = src[t];
        int dst = r.x & 0xFFFF;
        int pos = atomicAdd(&curs[dst & mask], 1);
        int2 o;
        o.x = (int)((unsigned)r.x >> 16);
        o.y = r.y;
        edges[gbase + pos] = o;
    }
}

// ---------------- fused-level gather SpMM (fp8 rows, fp32 accumulate) --------
// Source rows stored as fp8 e4m3 scaled x128: 64B/row = ONE cache line per
// gather (bf16 was 2 — the r9 profile showed line count, not bytes, is the
// wall). acc of scaled inputs IS the next level's scaled input (scale cancels).
//   MODE 0: dst8 = enc(acc);  gcn = base + (alpha/128)*acc
//   MODE 1: dst8 = enc(acc);  gcn += (alpha/128)*acc
//   MODE 2: g8 = enc(16 * (gcn + (alpha/128)*acc))       (final, for the loss)
template <int MODE>
__global__ void spmm_level(const int* __restrict__ ptrU, const int* __restrict__ cntU,
                           const int2* __restrict__ edgesU, const unsigned* __restrict__ srcU,
                           unsigned* __restrict__ dstU, const float* __restrict__ baseU,
                           float* __restrict__ gcnU, unsigned* __restrict__ g8U,
                           const int* __restrict__ ptrI, const int* __restrict__ cntI,
                           const int2* __restrict__ edgesI, const unsigned* __restrict__ srcI,
                           unsigned* __restrict__ dstI, const float* __restrict__ baseI,
                           float* __restrict__ gcnI, unsigned* __restrict__ g8I,
                           float alphaS)
{
    int wave = (blockIdx.x * blockDim.x + threadIdx.x) >> 6;
    bool isU = wave < U_NUM;
    int row = isU ? wave : wave - U_NUM;
    if (!isU && row >= I_NUM) return;

    const int*  ptr   = isU ? ptrU   : ptrI;
    const int*  cnt   = isU ? cntU   : cntI;
    const int2* edges = isU ? edgesU : edgesI;
    const unsigned* semb = isU ? srcU : srcI;
    unsigned* dst = isU ? dstU : dstI;
    const float* base = isU ? baseU : baseI;
    float* gcn        = isU ? gcnU  : gcnI;
    unsigned* g8      = isU ? g8U   : g8I;

    int lane = threadIdx.x & 63;
    int sub  = lane >> 4;
    int q    = lane & 15;
    int begin = ptr[row];
    int len   = cnt[row];

    float4 a0 = make_float4(0.f, 0.f, 0.f, 0.f);
    float4 a1 = make_float4(0.f, 0.f, 0.f, 0.f);
    float4 a2 = make_float4(0.f, 0.f, 0.f, 0.f);
    float4 a3 = make_float4(0.f, 0.f, 0.f, 0.f);
    int k = sub;
    for (; k + 12 < len; k += 16) {
        int2 e0 = edges[begin + k];
        int2 e1 = edges[begin + k + 4];
        int2 e2 = edges[begin + k + 8];
        int2 e3 = edges[begin + k + 12];
        unsigned x0 = semb[((size_t)e0.x << 4) + q];
        unsigned x1 = semb[((size_t)e1.x << 4) + q];
        unsigned x2 = semb[((size_t)e2.x << 4) + q];
        unsigned x3 = semb[((size_t)e3.x << 4) + q];
        float v0 = __int_as_float(e0.y), v1 = __int_as_float(e1.y);
        float v2 = __int_as_float(e2.y), v3 = __int_as_float(e3.y);
        float f0[4], f1[4], f2[4], f3[4];
        dec4(x0, f0); dec4(x1, f1); dec4(x2, f2); dec4(x3, f3);
        a0.x += v0 * f0[0]; a0.y += v0 * f0[1]; a0.z += v0 * f0[2]; a0.w += v0 * f0[3];
        a1.x += v1 * f1[0]; a1.y += v1 * f1[1]; a1.z += v1 * f1[2]; a1.w += v1 * f1[3];
        a2.x += v2 * f2[0]; a2.y += v2 * f2[1]; a2.z += v2 * f2[2]; a2.w += v2 * f2[3];
        a3.x += v3 * f3[0]; a3.y += v3 * f3[1]; a3.z += v3 * f3[2]; a3.w += v3 * f3[3];
    }
    for (; k < len; k += 4) {
        int2 e0 = edges[begin + k];
        unsigned x0 = semb[((size_t)e0.x << 4) + q];
        float v0 = __int_as_float(e0.y);
        float f0[4];
        dec4(x0, f0);
        a0.x += v0 * f0[0]; a0.y += v0 * f0[1]; a0.z += v0 * f0[2]; a0.w += v0 * f0[3];
    }
    float4 acc;
    acc.x = (a0.x + a1.x) + (a2.x + a3.x);
    acc.y = (a0.y + a1.y) + (a2.y + a3.y);
    acc.z = (a0.z + a1.z) + (a2.z + a3.z);
    acc.w = (a0.w + a1.w) + (a2.w + a3.w);

    acc.x += __shfl_xor(acc.x, 16, 64);
    acc.y += __shfl_xor(acc.y, 16, 64);
    acc.z += __shfl_xor(acc.z, 16, 64);
    acc.w += __shfl_xor(acc.w, 16, 64);
    acc.x += __shfl_xor(acc.x, 32, 64);
    acc.y += __shfl_xor(acc.y, 32, 64);
    acc.z += __shfl_xor(acc.z, 32, 64);
    acc.w += __shfl_xor(acc.w, 32, 64);

    if (sub == 0) {
        size_t off = (size_t)row * F_DIM;
        if (MODE < 2)
            dst[((size_t)row << 4) + q] = enc4(acc.x, acc.y, acc.z, acc.w);
        float4 g;
        if (MODE == 0) g = ((const float4*)(base + off))[q];
        else           g = ((const float4*)(gcn + off))[q];
        g.x += alphaS * acc.x;
        g.y += alphaS * acc.y;
        g.z += alphaS * acc.z;
        g.w += alphaS * acc.w;
        if (MODE < 2) {
            ((float4*)(gcn + off))[q] = g;
        } else {
            g8[((size_t)row << 4) + q] = enc4(g.x * 16.f, g.y * 16.f, g.z * 16.f, g.w * 16.f);
        }
    }
}

// ---------------- contrastive loss: fp8 rows (64B = 1 line per gather) -------
// old stored x1, gcn stored x16 -> si_true = si_raw / 16.
__device__ __forceinline__ void dots8(unsigned u, unsigned a, unsigned b,
                                      float& si, float& sj)
{
    float fu[4], fa[4], fb[4];
    dec4(u, fu); dec4(a, fa); dec4(b, fb);
    si = fu[0] * fa[0] + fu[1] * fa[1] + fu[2] * fa[2] + fu[3] * fa[3];
    sj = fu[0] * fb[0] + fu[1] * fb[1] + fu[2] * fb[2] + fu[3] * fb[3];
}

__global__ void contrastive_both(const unsigned* __restrict__ oldU, const unsigned* __restrict__ gcnU,
                                 const int* __restrict__ userU, const int* __restrict__ iiU,
                                 const int* __restrict__ ijU, const float* __restrict__ degU,
                                 const unsigned* __restrict__ oldI, const unsigned* __restrict__ gcnI,
                                 const int* __restrict__ userI, const int* __restrict__ iiI,
                                 const int* __restrict__ ijI, const float* __restrict__ degI,
                                 float* __restrict__ out)
{
    int lane = threadIdx.x & 63;
    int ql   = lane & 15;
    int gq = (blockIdx.x * blockDim.x + threadIdx.x) >> 4;   // 0..65535
    int b0 = gq, b1 = gq + 65536;

    int ua0 = userU[b0], ia0 = iiU[b0], ja0 = ijU[b0];
    int ua1 = userU[b1], ia1 = iiU[b1], ja1 = ijU[b1];
    int ub0 = userI[b0], ib0 = iiI[b0], jb0 = ijI[b0];
    int ub1 = userI[b1], ib1 = iiI[b1], jb1 = ijI[b1];

    unsigned A0u = oldU[((size_t)ua0 << 4) + ql], A0i = gcnU[((size_t)ia0 << 4) + ql], A0j = gcnU[((size_t)ja0 << 4) + ql];
    unsigned A1u = oldU[((size_t)ua1 << 4) + ql], A1i = gcnU[((size_t)ia1 << 4) + ql], A1j = gcnU[((size_t)ja1 << 4) + ql];
    unsigned B0u = oldI[((size_t)ub0 << 4) + ql], B0i = gcnI[((size_t)ib0 << 4) + ql], B0j = gcnI[((size_t)jb0 << 4) + ql];
    unsigned B1u = oldI[((size_t)ub1 << 4) + ql], B1i = gcnI[((size_t)ib1 << 4) + ql], B1j = gcnI[((size_t)jb1 << 4) + ql];

    float si0, sj0, si1, sj1, si2, sj2, si3, sj3;
    dots8(A0u, A0i, A0j, si0, sj0);
    dots8(A1u, A1i, A1j, si1, sj1);
    dots8(B0u, B0i, B0j, si2, sj2);
    dots8(B1u, B1i, B1j, si3, sj3);

    #pragma unroll
    for (int off = 1; off < 16; off <<= 1) {
        si0 += __shfl_xor(si0, off, 64); sj0 += __shfl_xor(sj0, off, 64);
        si1 += __shfl_xor(si1, off, 64); sj1 += __shfl_xor(sj1, off, 64);
        si2 += __shfl_xor(si2, off, 64); sj2 += __shfl_xor(sj2, off, 64);
        si3 += __shfl_xor(si3, off, 64); sj3 += __shfl_xor(sj3, off, 64);
    }

    float acc = 0.f;
    if (ql == 0) {
        const float S = 0.0625f;                 // undo the x16 gcn scale
        const float invU = 1.f / U_NUM, invI = 1.f / I_NUM;
        float m, lse;
        si0 *= S; sj0 *= S; si1 *= S; sj1 *= S;
        si2 *= S; sj2 *= S; si3 *= S; sj3 *= S;
        m = fmaxf(si0, sj0); lse = m + logf(expf(si0 - m) + expf(sj0 - m));
        acc -= (si0 - lse) * degU[b0] * invU;
        m = fmaxf(si1, sj1); lse = m + logf(expf(si1 - m) + expf(sj1 - m));
        acc -= (si1 - lse) * degU[b1] * invU;
        m = fmaxf(si2, sj2); lse = m + logf(expf(si2 - m) + expf(sj2 - m));
        acc -= (si2 - lse) * degI[b0] * invI;
        m = fmaxf(si3, sj3); lse = m + logf(expf(si3 - m) + expf(sj3 - m));
        acc -= (si3 - lse) * degI[b1] * invI;
    }
    #pragma unroll
    for (int off = 32; off > 0; off >>= 1) acc += __shfl_down(acc, off, 64);
    __shared__ float wsum[4];
    if (lane == 0) wsum[threadIdx.x >> 6] = acc;
    __syncthreads();
    if (threadIdx.x == 0)
        atomicAdd(out, wsum[0] + wsum[1] + wsum[2] + wsum[3]);
}

extern "C" void kernel_launch(void* const* d_in, const int* in_sizes, int n_in,
                              void* d_out, int out_size, void* d_ws, size_t ws_size,
                              hipStream_t stream)
{
    const float* embed_user = (const float*)d_in[0];
    const float* embed_item = (const float*)d_in[1];
    const float* old_U      = (const float*)d_in[2];
    const float* old_I      = (const float*)d_in[3];
    const int*   erow       = (const int*)d_in[4];
    const int*   ecol       = (const int*)d_in[5];
    const float* ui_vals    = (const float*)d_in[6];
    const float* iu_vals    = (const float*)d_in[7];
    const int*   user       = (const int*)d_in[8];
    const int*   item_i     = (const int*)d_in[9];
    const int*   item_j     = (const int*)d_in[10];
    const float* degU       = (const float*)d_in[11];
    const int*   user_      = (const int*)d_in[13];
    const int*   item_i_    = (const int*)d_in[14];
    const int*   item_j_    = (const int*)d_in[15];
    const float* degI       = (const float*)d_in[16];

    const size_t UF = (size_t)U_NUM * F_DIM;    // 3.2M elements
    const size_t IF = (size_t)I_NUM * F_DIM;    // 1.28M
    const size_t CREC = (size_t)P_U * CAPP_U + (size_t)P_I * CAPP_I;   // 2,232,320

    // Region 0: coarse buffers, overlaid by exact CSR after refine.
    int2*  cbufU  = (int2*)d_ws;
    int2*  cbufI  = cbufU + (size_t)P_U * CAPP_U;
    int2*  edgesU = (int2*)d_ws;
    int2*  edgesI = edgesU + N_EDGES;
    // Region 1: fine buffers.
    int2*  fbufU  = (int2*)d_ws + CREC;
    int2*  fbufI  = fbufU + (size_t)FP_U * CAPF_U;
    // Fresh region.
    char* cur = (char*)d_ws + 2 * CREC * sizeof(int2);
    float* gcn_u = (float*)cur;  cur += UF * sizeof(float);
    float* gcn_i = (float*)cur;  cur += IF * sizeof(float);
    unsigned* e8U = (unsigned*)cur; cur += UF;   // fp8: 1 B/elt
    unsigned* e8I = (unsigned*)cur; cur += IF;
    unsigned* o8U = (unsigned*)cur; cur += UF;
    unsigned* o8I = (unsigned*)cur; cur += IF;
    unsigned* u1_8 = (unsigned*)cur; cur += UF;
    unsigned* u2_8 = (unsigned*)cur; cur += UF;
    unsigned* i1_8 = (unsigned*)cur; cur += IF;
    unsigned* i2_8 = (unsigned*)cur; cur += IF;
    unsigned* g8U  = (unsigned*)cur; cur += UF;
    unsigned* g8I  = (unsigned*)cur; cur += IF;
    int* pcurU = (int*)cur;
    int* pcurI = pcurU + 32;
    int* fcurU = pcurI + 32;
    int* fcurI = fcurU + 256;
    int* ptrU  = fcurI + 256;
    int* cntUa = ptrU + U_NUM;
    int* ptrI  = cntUa + U_NUM;
    int* cntIa = ptrI + I_NUM;
    // total ~77 MB

    dim3 blk(256);
    const int cv_blocks  = (N_EU + N_EI + N_OU + N_OI + 255) / 256;      // 8750
    const int p1_blocks  = P1B + cv_blocks;                              // merged
    const int rf_blocks  = P_U * BRU + P_I * BRI;                        // 2000
    const int st_blocks  = FP_U + FP_I;                                  // 360
    const int spmm_blocks = (U_NUM + I_NUM) / 4;                         // 17500

    hipMemsetAsync(pcurU, 0, 576 * sizeof(int), stream);
    hipMemsetAsync(d_out, 0, sizeof(float), stream);

    pass1_cvt<<<p1_blocks, blk, 0, stream>>>(erow, ecol, ui_vals, iu_vals,
                                             pcurU, pcurI, cbufU, cbufI,
                                             embed_user, embed_item, old_U, old_I,
                                             e8U, e8I, o8U, o8I);
    refine<<<rf_blocks, blk, 0, stream>>>(pcurU, cbufU, fcurU, fbufU,
                                          pcurI, cbufI, fcurI, fbufI);
    sort_csr<<<st_blocks, blk, 0, stream>>>(fcurU, fbufU, ptrU, cntUa, edgesU,
                                            fcurI, fbufI, ptrI, cntIa, edgesI);

    // L1: acc=128*u1 -> u1_8 ; gcn_u = u0 + (0.5/128)*acc
    spmm_level<0><<<spmm_blocks, blk, 0, stream>>>(
        ptrU, cntUa, edgesU, e8I, u1_8, embed_user, gcn_u, g8U,
        ptrI, cntIa, edgesI, e8U, i1_8, embed_item, gcn_i, g8I, 0.5f / 128.f);
    // L2: acc=128*u2 -> u2_8 ; gcn += (1/3/128)*acc
    spmm_level<1><<<spmm_blocks, blk, 0, stream>>>(
        ptrU, cntUa, edgesU, i1_8, u2_8, nullptr, gcn_u, g8U,
        ptrI, cntIa, edgesI, u1_8, i2_8, nullptr, gcn_i, g8I, 1.f / 3.f / 128.f);
    // L3: g8 = enc(16*(gcn + (0.25/128)*acc))
    spmm_level<2><<<spmm_blocks, blk, 0, stream>>>(
        ptrU, cntUa, edgesU, i2_8, nullptr, nullptr, gcn_u, g8U,
        ptrI, cntIa, edgesI, u2_8, nullptr, nullptr, gcn_i, g8I, 0.25f / 128.f);

    contrastive_both<<<4096, blk, 0, stream>>>(o8U, g8U, user, item_i, item_j, degU,
                                               o8I, g8I, user_, item_i_, item_j_, degI,
                                               (float*)d_out);
}

// Round 11
// 328.475 us; speedup vs baseline: 3.3127x; 1.0662x over previous
//
#include <hip/hip_runtime.h>

#define U_NUM 50000
#define I_NUM 20000
#define F_DIM 64
#define N_EDGES 1000000
#define BATCH 131072

#define P_U 25
#define P_I 20
#define CAPP_U 45056
#define CAPP_I 55296
#define FP_U 200
#define FP_I 160
#define CAPF_U 5632
#define CAPF_I 6912
#define BRU 40
#define BRI 50
#define P1B 977            // (N_EDGES+1023)/1024

// fp8 e4m3 (OCP) helpers; HW converts on gfx950, software fallback otherwise.
#if defined(__has_builtin)
#if __has_builtin(__builtin_amdgcn_cvt_pk_f32_fp8) && __has_builtin(__builtin_amdgcn_cvt_pk_fp8_f32)
#define HW_FP8 1
#endif
#endif

typedef float v2f __attribute__((ext_vector_type(2)));

__device__ __forceinline__ void dec4(unsigned u, float* f) {
#ifdef HW_FP8
    v2f lo = __builtin_amdgcn_cvt_pk_f32_fp8((int)u, false);
    v2f hi = __builtin_amdgcn_cvt_pk_f32_fp8((int)u, true);
    f[0] = lo.x; f[1] = lo.y; f[2] = hi.x; f[3] = hi.y;
#else
    #pragma unroll
    for (int i = 0; i < 4; i++) {
        unsigned v = (u >> (8 * i)) & 0xFFu;
        unsigned s = v >> 7, e = (v >> 3) & 15u, m = v & 7u;
        float mag = (e == 0) ? (float)m * 0.001953125f
                             : __uint_as_float(((e + 120u) << 23) | (m << 20));
        f[i] = s ? -mag : mag;
    }
#endif
}

#ifndef HW_FP8
__device__ __forceinline__ unsigned char enc1(float x) {
    unsigned s = (__float_as_uint(x) >> 31) << 7;
    float a = fabsf(x);
    if (a >= 448.f) return (unsigned char)(s | 0x7E);
    if (a < 0.015625f) {
        int m = __float2int_rn(a * 512.f);
        if (m >= 8) return (unsigned char)(s | 0x08);
        return (unsigned char)(s | m);
    }
    unsigned au = __float_as_uint(a);
    au += 0x7FFFFu + ((au >> 20) & 1u);
    int e = (int)(au >> 23) - 127;
    if (e > 8) return (unsigned char)(s | 0x7E);
    return (unsigned char)(s | ((unsigned)(e + 7) << 3) | ((au >> 20) & 7u));
}
#endif

__device__ __forceinline__ unsigned enc4(float a, float b, float c, float d) {
#ifdef HW_FP8
    int v = __builtin_amdgcn_cvt_pk_fp8_f32(a, b, 0, false);
    v = __builtin_amdgcn_cvt_pk_fp8_f32(c, d, v, true);
    return (unsigned)v;
#else
    return (unsigned)enc1(a) | ((unsigned)enc1(b) << 8)
         | ((unsigned)enc1(c) << 16) | ((unsigned)enc1(d) << 24);
#endif
}

// ---------------- pass 1 (+ merged fp32->fp8 table cvt) ----------------------
#define N_EU 800000
#define N_EI 320000
#define N_OU 800000
#define N_OI 320000
__global__ void pass1_cvt(const int* __restrict__ rows, const int* __restrict__ cols,
                          const float* __restrict__ uiv, const float* __restrict__ iuv,
                          int* __restrict__ pcurU, int* __restrict__ pcurI,
                          int2* __restrict__ cbufU, int2* __restrict__ cbufI,
                          const float* __restrict__ eU, const float* __restrict__ eI,
                          const float* __restrict__ oU, const float* __restrict__ oI,
                          unsigned* __restrict__ e8U, unsigned* __restrict__ e8I,
                          unsigned* __restrict__ o8U, unsigned* __restrict__ o8I)
{
    if (blockIdx.x >= P1B) {
        int idx = (blockIdx.x - P1B) * 256 + threadIdx.x;
        const float* s; unsigned* d; int off; float sc;
        if (idx < N_EU)                        { s = eU; d = e8U; off = idx; sc = 128.f; }
        else if (idx < N_EU + N_EI)            { s = eI; d = e8I; off = idx - N_EU; sc = 128.f; }
        else if (idx < N_EU + N_EI + N_OU)     { s = oU; d = o8U; off = idx - N_EU - N_EI; sc = 1.f; }
        else if (idx < N_EU + N_EI + N_OU + N_OI) { s = oI; d = o8I; off = idx - N_EU - N_EI - N_OU; sc = 1.f; }
        else return;
        float4 v = ((const float4*)s)[off];
        d[off] = enc4(v.x * sc, v.y * sc, v.z * sc, v.w * sc);
        return;
    }

    __shared__ int histU[32], histI[32];
    __shared__ int lbaseU[32], lbaseI[32];
    __shared__ int deltaU[32], deltaI[32];
    __shared__ int totU, totI;
    __shared__ int2 recU[1024], recI[1024];
    __shared__ unsigned char pidU[1024], pidI[1024];

    if (threadIdx.x < 32) { histU[threadIdx.x] = 0; histI[threadIdx.x] = 0; }
    __syncthreads();

    int base = blockIdx.x * 1024;
    int r[4], c[4], lpU[4], lpI[4];
    float vu[4], vi[4];
    #pragma unroll
    for (int i = 0; i < 4; i++) {
        int e = base + threadIdx.x + i * 256;
        if (e < N_EDGES) {
            r[i] = rows[e]; c[i] = cols[e];
            vu[i] = uiv[e]; vi[i] = iuv[e];
            lpU[i] = atomicAdd(&histU[r[i] >> 11], 1);
            lpI[i] = atomicAdd(&histI[c[i] >> 10], 1);
        } else {
            lpU[i] = -1; lpI[i] = -1; r[i] = 0; c[i] = 0; vu[i] = 0.f; vi[i] = 0.f;
        }
    }
    __syncthreads();

    int lane = threadIdx.x & 63;
    int w    = threadIdx.x >> 6;
    if (w == 0) {
        int h = (lane < 32) ? histU[lane] : 0;
        int res = (lane < 32 && h) ? atomicAdd(&pcurU[lane], h) : 0;
        int inc = h;
        #pragma unroll
        for (int off = 1; off < 32; off <<= 1) {
            int t = __shfl_up(inc, off, 64);
            if (lane >= off) inc += t;
        }
        if (lane < 32) {
            int lb = inc - h;
            lbaseU[lane] = lb;
            deltaU[lane] = lane * CAPP_U + res - lb;
            if (lane == 31) totU = inc;
        }
    } else if (w == 1) {
        int h = (lane < 32) ? histI[lane] : 0;
        int res = (lane < 32 && h) ? atomicAdd(&pcurI[lane], h) : 0;
        int inc = h;
        #pragma unroll
        for (int off = 1; off < 32; off <<= 1) {
            int t = __shfl_up(inc, off, 64);
            if (lane >= off) inc += t;
        }
        if (lane < 32) {
            int lb = inc - h;
            lbaseI[lane] = lb;
            deltaI[lane] = lane * CAPP_I + res - lb;
            if (lane == 31) totI = inc;
        }
    }
    __syncthreads();

    #pragma unroll
    for (int i = 0; i < 4; i++) {
        if (lpU[i] >= 0) {
            int p = r[i] >> 11;
            int slot = lbaseU[p] + lpU[i];
            int2 rec;
            rec.x = (int)(((unsigned)c[i] << 16) | (unsigned)r[i]);
            rec.y = __float_as_int(vu[i]);
            recU[slot] = rec;
            pidU[slot] = (unsigned char)p;

            p = c[i] >> 10;
            slot = lbaseI[p] + lpI[i];
            rec.x = (int)(((unsigned)r[i] << 16) | (unsigned)c[i]);
            rec.y = __float_as_int(vi[i]);
            recI[slot] = rec;
            pidI[slot] = (unsigned char)p;
        }
    }
    __syncthreads();

    for (int t = threadIdx.x; t < totU; t += 256) {
        int p = pidU[t];
        int a = deltaU[p] + t;
        if (a < (p + 1) * CAPP_U) cbufU[a] = recU[t];
    }
    for (int t = threadIdx.x; t < totI; t += 256) {
        int p = pidI[t];
        int a = deltaI[p] + t;
        if (a < (p + 1) * CAPP_I) cbufI[a] = recI[t];
    }
}

// ---------------- refine: coarse -> 8 fine partitions ------------------------
__global__ void refine(const int* __restrict__ pcurU, const int2* __restrict__ cbufU,
                       int* __restrict__ fcurU, int2* __restrict__ fbufU,
                       const int* __restrict__ pcurI, const int2* __restrict__ cbufI,
                       int* __restrict__ fcurI, int2* __restrict__ fbufI)
{
    const int* pcur; const int2* cbuf; int* fcur; int2* fbuf;
    int p, b, br, capp, capf, shift;
    if (blockIdx.x < P_U * BRU) {
        pcur = pcurU; cbuf = cbufU; fcur = fcurU; fbuf = fbufU;
        p = blockIdx.x / BRU; b = blockIdx.x % BRU; br = BRU;
        capp = CAPP_U; capf = CAPF_U; shift = 8;
    } else {
        int q = blockIdx.x - P_U * BRU;
        pcur = pcurI; cbuf = cbufI; fcur = fcurI; fbuf = fbufI;
        p = q / BRI; b = q % BRI; br = BRI;
        capp = CAPP_I; capf = CAPF_I; shift = 7;
    }
    int n = min(pcur[p], capp);
    const int2* src = cbuf + (size_t)p * capp;

    __shared__ int hist[8], lbase[8], delta[8];
    __shared__ int tot;
    __shared__ int2 rec[1024];
    __shared__ unsigned char pid[1024];

    for (int base = b * 1024; base < n; base += br * 1024) {
        __syncthreads();
        if (threadIdx.x < 8) hist[threadIdx.x] = 0;
        __syncthreads();
        int2 rr[4]; int ff[4], lp[4];
        #pragma unroll
        for (int i = 0; i < 4; i++) {
            int t = base + i * 256 + threadIdx.x;
            if (t < n) {
                rr[i] = src[t];
                ff[i] = (int)((((unsigned)rr[i].x & 0xFFFFu) >> shift) & 7u);
                lp[i] = atomicAdd(&hist[ff[i]], 1);
            } else lp[i] = -1;
        }
        __syncthreads();
        if ((threadIdx.x >> 6) == 0) {
            int lane = threadIdx.x & 63;
            int h = (lane < 8) ? hist[lane] : 0;
            int res = (lane < 8 && h) ? atomicAdd(&fcur[p * 8 + lane], h) : 0;
            int inc = h;
            #pragma unroll
            for (int off = 1; off < 8; off <<= 1) {
                int t = __shfl_up(inc, off, 64);
                if (lane >= off) inc += t;
            }
            if (lane < 8) {
                int lb = inc - h;
                lbase[lane] = lb;
                delta[lane] = (p * 8 + lane) * capf + res - lb;
                if (lane == 7) tot = inc;
            }
        }
        __syncthreads();
        #pragma unroll
        for (int i = 0; i < 4; i++) {
            if (lp[i] >= 0) {
                int slot = lbase[ff[i]] + lp[i];
                rec[slot] = rr[i];
                pid[slot] = (unsigned char)ff[i];
            }
        }
        __syncthreads();
        for (int t = threadIdx.x; t < tot; t += 256) {
            int f2 = pid[t];
            int a = delta[f2] + t;
            if (a < (p * 8 + f2 + 1) * capf) fbuf[a] = rec[t];
        }
    }
}

// ---------------- sort_csr: fine partition -> exact CSR + ptr/cnt ------------
__global__ void sort_csr(const int* __restrict__ fcurU, const int2* __restrict__ fbufU,
                         int* __restrict__ ptrU, int* __restrict__ cntU, int2* __restrict__ edgesU,
                         const int* __restrict__ fcurI, const int2* __restrict__ fbufI,
                         int* __restrict__ ptrI, int* __restrict__ cntI, int2* __restrict__ edgesI)
{
    __shared__ int hist[256], scan[256], curs[256];
    __shared__ int gbase_s;

    const int* fcur; const int2* fbuf; int* ptr; int* cnt; int2* edges;
    int fp, bins, capf, nrow;
    if (blockIdx.x < FP_U) {
        fcur = fcurU; fbuf = fbufU; ptr = ptrU; cnt = cntU; edges = edgesU;
        fp = blockIdx.x; bins = 256; capf = CAPF_U; nrow = U_NUM;
    } else {
        fcur = fcurI; fbuf = fbufI; ptr = ptrI; cnt = cntI; edges = edgesI;
        fp = blockIdx.x - FP_U; bins = 128; capf = CAPF_I; nrow = I_NUM;
    }

    if (threadIdx.x == 0) gbase_s = 0;
    for (int i = threadIdx.x; i < bins; i += 256) hist[i] = 0;
    __syncthreads();

    int contrib = ((int)threadIdx.x < fp) ? min(fcur[threadIdx.x], capf) : 0;
    #pragma unroll
    for (int off = 32; off > 0; off >>= 1) contrib += __shfl_down(contrib, off, 64);
    if ((threadIdx.x & 63) == 0 && contrib) atomicAdd(&gbase_s, contrib);

    int n = min(fcur[fp], capf);
    const int2* src = fbuf + (size_t)fp * capf;
    int mask = bins - 1;

    for (int t = threadIdx.x; t < n; t += 256) {
        int dst = src[t].x & 0xFFFF;
        atomicAdd(&hist[dst & mask], 1);
    }
    __syncthreads();

    int v = ((int)threadIdx.x < bins) ? hist[threadIdx.x] : 0;
    scan[threadIdx.x] = v;
    __syncthreads();
    for (int off = 1; off < 256; off <<= 1) {
        int t = ((int)threadIdx.x >= off) ? scan[threadIdx.x - off] : 0;
        __syncthreads();
        scan[threadIdx.x] += t;
        __syncthreads();
    }
    int ex = scan[threadIdx.x] - v;
    curs[threadIdx.x] = ex;
    __syncthreads();
    int gbase = gbase_s;

    if ((int)threadIdx.x < bins) {
        int row = fp * bins + threadIdx.x;
        if (row < nrow) {
            ptr[row] = gbase + ex;
            cnt[row] = v;
        }
    }

    for (int t = threadIdx.x; t < n; t += 256) {
        int2 r = src[t];
        int dst = r.x & 0xFFFF;
        int pos = atomicAdd(&curs[dst & mask], 1);
        int2 o;
        o.x = (int)((unsigned)r.x >> 16);
        o.y = r.y;
        edges[gbase + pos] = o;
    }
}

// ---------------- fused-level gather SpMM (fp8 rows, fp32 accumulate) --------
template <int MODE>
__global__ void spmm_level(const int* __restrict__ ptrU, const int* __restrict__ cntU,
                           const int2* __restrict__ edgesU, const unsigned* __restrict__ srcU,
                           unsigned* __restrict__ dstU, const float* __restrict__ baseU,
                           float* __restrict__ gcnU, unsigned* __restrict__ g8U,
                           const int* __restrict__ ptrI, const int* __restrict__ cntI,
                           const int2* __restrict__ edgesI, const unsigned* __restrict__ srcI,
                           unsigned* __restrict__ dstI, const float* __restrict__ baseI,
                           float* __restrict__ gcnI, unsigned* __restrict__ g8I,
                           float alphaS)
{
    int wave = (blockIdx.x * blockDim.x + threadIdx.x) >> 6;
    bool isU = wave < U_NUM;
    int row = isU ? wave : wave - U_NUM;
    if (!isU && row >= I_NUM) return;

    const int*  ptr   = isU ? ptrU   : ptrI;
    const int*  cnt   = isU ? cntU   : cntI;
    const int2* edges = isU ? edgesU : edgesI;
    const unsigned* semb = isU ? srcU : srcI;
    unsigned* dst = isU ? dstU : dstI;
    const float* base = isU ? baseU : baseI;
    float* gcn        = isU ? gcnU  : gcnI;
    unsigned* g8      = isU ? g8U   : g8I;

    int lane = threadIdx.x & 63;
    int sub  = lane >> 4;
    int q    = lane & 15;
    int begin = ptr[row];
    int len   = cnt[row];

    float4 a0 = make_float4(0.f, 0.f, 0.f, 0.f);
    float4 a1 = make_float4(0.f, 0.f, 0.f, 0.f);
    float4 a2 = make_float4(0.f, 0.f, 0.f, 0.f);
    float4 a3 = make_float4(0.f, 0.f, 0.f, 0.f);
    int k = sub;
    for (; k + 12 < len; k += 16) {
        int2 e0 = edges[begin + k];
        int2 e1 = edges[begin + k + 4];
        int2 e2 = edges[begin + k + 8];
        int2 e3 = edges[begin + k + 12];
        unsigned x0 = semb[((size_t)e0.x << 4) + q];
        unsigned x1 = semb[((size_t)e1.x << 4) + q];
        unsigned x2 = semb[((size_t)e2.x << 4) + q];
        unsigned x3 = semb[((size_t)e3.x << 4) + q];
        float v0 = __int_as_float(e0.y), v1 = __int_as_float(e1.y);
        float v2 = __int_as_float(e2.y), v3 = __int_as_float(e3.y);
        float f0[4], f1[4], f2[4], f3[4];
        dec4(x0, f0); dec4(x1, f1); dec4(x2, f2); dec4(x3, f3);
        a0.x += v0 * f0[0]; a0.y += v0 * f0[1]; a0.z += v0 * f0[2]; a0.w += v0 * f0[3];
        a1.x += v1 * f1[0]; a1.y += v1 * f1[1]; a1.z += v1 * f1[2]; a1.w += v1 * f1[3];
        a2.x += v2 * f2[0]; a2.y += v2 * f2[1]; a2.z += v2 * f2[2]; a2.w += v2 * f2[3];
        a3.x += v3 * f3[0]; a3.y += v3 * f3[1]; a3.z += v3 * f3[2]; a3.w += v3 * f3[3];
    }
    for (; k < len; k += 4) {
        int2 e0 = edges[begin + k];
        unsigned x0 = semb[((size_t)e0.x << 4) + q];
        float v0 = __int_as_float(e0.y);
        float f0[4];
        dec4(x0, f0);
        a0.x += v0 * f0[0]; a0.y += v0 * f0[1]; a0.z += v0 * f0[2]; a0.w += v0 * f0[3];
    }
    float4 acc;
    acc.x = (a0.x + a1.x) + (a2.x + a3.x);
    acc.y = (a0.y + a1.y) + (a2.y + a3.y);
    acc.z = (a0.z + a1.z) + (a2.z + a3.z);
    acc.w = (a0.w + a1.w) + (a2.w + a3.w);

    acc.x += __shfl_xor(acc.x, 16, 64);
    acc.y += __shfl_xor(acc.y, 16, 64);
    acc.z += __shfl_xor(acc.z, 16, 64);
    acc.w += __shfl_xor(acc.w, 16, 64);
    acc.x += __shfl_xor(acc.x, 32, 64);
    acc.y += __shfl_xor(acc.y, 32, 64);
    acc.z += __shfl_xor(acc.z, 32, 64);
    acc.w += __shfl_xor(acc.w, 32, 64);

    if (sub == 0) {
        size_t off = (size_t)row * F_DIM;
        if (MODE < 2)
            dst[((size_t)row << 4) + q] = enc4(acc.x, acc.y, acc.z, acc.w);
        float4 g;
        if (MODE == 0) g = ((const float4*)(base + off))[q];
        else           g = ((const float4*)(gcn + off))[q];
        g.x += alphaS * acc.x;
        g.y += alphaS * acc.y;
        g.z += alphaS * acc.z;
        g.w += alphaS * acc.w;
        if (MODE < 2) {
            ((float4*)(gcn + off))[q] = g;
        } else {
            g8[((size_t)row << 4) + q] = enc4(g.x * 16.f, g.y * 16.f, g.z * 16.f, g.w * 16.f);
        }
    }
}

// ---------------- contrastive loss v3: MLP-restructured ----------------------
// Grid 2048 (one full-residency round). Quarter-wave handles 8 samples
// (4 U + 4 I). Indices: TWO coalesced-lane loads (lane ql picks array by
// ql>>2) + in-register shfl broadcast, replacing 24 serialized same-address
// loads. All 24 row gathers issued back-to-back. log/exp epilogue spread
// across lanes 0..7 (one transcendental pass for all 8 samples).
__device__ __forceinline__ float dotq(const float* a, const float* b) {
    return a[0] * b[0] + a[1] * b[1] + a[2] * b[2] + a[3] * b[3];
}

__global__ void __launch_bounds__(256, 2)
contrastive_both(const unsigned* __restrict__ oldU, const unsigned* __restrict__ gcnU,
                 const int* __restrict__ userU, const int* __restrict__ iiU,
                 const int* __restrict__ ijU, const float* __restrict__ degU,
                 const unsigned* __restrict__ oldI, const unsigned* __restrict__ gcnI,
                 const int* __restrict__ userI, const int* __restrict__ iiI,
                 const int* __restrict__ ijI, const float* __restrict__ degI,
                 float* __restrict__ out)
{
    int lane = threadIdx.x & 63;
    int sub  = lane >> 4;          // quarter-wave 0..3
    int ql   = lane & 15;
    int qg = (blockIdx.x * blockDim.x + threadIdx.x) >> 4;   // 0..32767
    int s0 = qg << 2;                                        // 4 samples/side

    // --- 2 index loads (lane ql: array = ql>>2, sample = s0 + (ql&3)) ---
    int sel = ql >> 2, so = s0 + (ql & 3);
    const int* pu = (sel == 0) ? (userU + so) : (sel == 1) ? (iiU + so)
                  : (sel == 2) ? (ijU + so)   : ((const int*)degU + so);
    const int* pi = (sel == 0) ? (userI + so) : (sel == 1) ? (iiI + so)
                  : (sel == 2) ? (ijI + so)   : ((const int*)degI + so);
    int idxU = *pu;
    int idxI = *pi;

    // --- broadcast row indices, issue all 24 gathers back-to-back ---
    int qb = sub << 4;
    unsigned Au[4], Ai[4], Aj[4], Bu[4], Bi[4], Bj[4];
    #pragma unroll
    for (int t = 0; t < 4; t++) {
        int uU = __shfl(idxU, qb + t, 64);
        int iU = __shfl(idxU, qb + 4 + t, 64);
        int jU = __shfl(idxU, qb + 8 + t, 64);
        int uI = __shfl(idxI, qb + t, 64);
        int iI = __shfl(idxI, qb + 4 + t, 64);
        int jI = __shfl(idxI, qb + 8 + t, 64);
        Au[t] = oldU[((size_t)uU << 4) + ql];
        Ai[t] = gcnU[((size_t)iU << 4) + ql];
        Aj[t] = gcnU[((size_t)jU << 4) + ql];
        Bu[t] = oldI[((size_t)uI << 4) + ql];
        Bi[t] = gcnI[((size_t)iI << 4) + ql];
        Bj[t] = gcnI[((size_t)jI << 4) + ql];
    }

    // --- dots ---
    float siU[4], sjU[4], siI[4], sjI[4];
    #pragma unroll
    for (int t = 0; t < 4; t++) {
        float fu[4], fi[4], fj[4];
        dec4(Au[t], fu); dec4(Ai[t], fi); dec4(Aj[t], fj);
        siU[t] = dotq(fu, fi); sjU[t] = dotq(fu, fj);
        dec4(Bu[t], fu); dec4(Bi[t], fi); dec4(Bj[t], fj);
        siI[t] = dotq(fu, fi); sjI[t] = dotq(fu, fj);
    }

    // --- 16-lane butterfly for all 16 values ---
    #pragma unroll
    for (int off = 1; off < 16; off <<= 1) {
        #pragma unroll
        for (int t = 0; t < 4; t++) {
            siU[t] += __shfl_xor(siU[t], off, 64);
            sjU[t] += __shfl_xor(sjU[t], off, 64);
            siI[t] += __shfl_xor(siI[t], off, 64);
            sjI[t] += __shfl_xor(sjI[t], off, 64);
        }
    }

    // --- per-lane epilogue: lane ql<4 -> U sample ql; ql in 4..7 -> I sample ---
    int t3 = ql & 3;
    bool isI = (ql & 4) != 0;
    float si = isI ? siI[t3] : siU[t3];
    float sj = isI ? sjI[t3] : sjU[t3];
    float dg = __int_as_float(__shfl(isI ? idxI : idxU, qb + 12 + t3, 64));
    float inv = isI ? (1.f / I_NUM) : (1.f / U_NUM);

    const float S = 0.0625f;                 // undo the x16 gcn scale
    si *= S; sj *= S;
    float m = fmaxf(si, sj);
    float lse = m + logf(expf(si - m) + expf(sj - m));
    float acc = (ql < 8) ? -(si - lse) * dg * inv : 0.f;

    // --- wave + block reduce ---
    #pragma unroll
    for (int off = 32; off > 0; off >>= 1) acc += __shfl_down(acc, off, 64);
    __shared__ float wsum[4];
    if (lane == 0) wsum[threadIdx.x >> 6] = acc;
    __syncthreads();
    if (threadIdx.x == 0)
        atomicAdd(out, wsum[0] + wsum[1] + wsum[2] + wsum[3]);
}

extern "C" void kernel_launch(void* const* d_in, const int* in_sizes, int n_in,
                              void* d_out, int out_size, void* d_ws, size_t ws_size,
                              hipStream_t stream)
{
    const float* embed_user = (const float*)d_in[0];
    const float* embed_item = (const float*)d_in[1];
    const float* old_U      = (const float*)d_in[2];
    const float* old_I      = (const float*)d_in[3];
    const int*   erow       = (const int*)d_in[4];
    const int*   ecol       = (const int*)d_in[5];
    const float* ui_vals    = (const float*)d_in[6];
    const float* iu_vals    = (const float*)d_in[7];
    const int*   user       = (const int*)d_in[8];
    const int*   item_i     = (const int*)d_in[9];
    const int*   item_j     = (const int*)d_in[10];
    const float* degU       = (const float*)d_in[11];
    const int*   user_      = (const int*)d_in[13];
    const int*   item_i_    = (const int*)d_in[14];
    const int*   item_j_    = (const int*)d_in[15];
    const float* degI       = (const float*)d_in[16];

    const size_t UF = (size_t)U_NUM * F_DIM;
    const size_t IF = (size_t)I_NUM * F_DIM;
    const size_t CREC = (size_t)P_U * CAPP_U + (size_t)P_I * CAPP_I;

    int2*  cbufU  = (int2*)d_ws;
    int2*  cbufI  = cbufU + (size_t)P_U * CAPP_U;
    int2*  edgesU = (int2*)d_ws;
    int2*  edgesI = edgesU + N_EDGES;
    int2*  fbufU  = (int2*)d_ws + CREC;
    int2*  fbufI  = fbufU + (size_t)FP_U * CAPF_U;
    char* cur = (char*)d_ws + 2 * CREC * sizeof(int2);
    float* gcn_u = (float*)cur;  cur += UF * sizeof(float);
    float* gcn_i = (float*)cur;  cur += IF * sizeof(float);
    unsigned* e8U = (unsigned*)cur; cur += UF;
    unsigned* e8I = (unsigned*)cur; cur += IF;
    unsigned* o8U = (unsigned*)cur; cur += UF;
    unsigned* o8I = (unsigned*)cur; cur += IF;
    unsigned* u1_8 = (unsigned*)cur; cur += UF;
    unsigned* u2_8 = (unsigned*)cur; cur += UF;
    unsigned* i1_8 = (unsigned*)cur; cur += IF;
    unsigned* i2_8 = (unsigned*)cur; cur += IF;
    unsigned* g8U  = (unsigned*)cur; cur += UF;
    unsigned* g8I  = (unsigned*)cur; cur += IF;
    int* pcurU = (int*)cur;
    int* pcurI = pcurU + 32;
    int* fcurU = pcurI + 32;
    int* fcurI = fcurU + 256;
    int* ptrU  = fcurI + 256;
    int* cntUa = ptrU + U_NUM;
    int* ptrI  = cntUa + U_NUM;
    int* cntIa = ptrI + I_NUM;

    dim3 blk(256);
    const int cv_blocks  = (N_EU + N_EI + N_OU + N_OI + 255) / 256;
    const int p1_blocks  = P1B + cv_blocks;
    const int rf_blocks  = P_U * BRU + P_I * BRI;
    const int st_blocks  = FP_U + FP_I;
    const int spmm_blocks = (U_NUM + I_NUM) / 4;

    hipMemsetAsync(pcurU, 0, 576 * sizeof(int), stream);
    hipMemsetAsync(d_out, 0, sizeof(float), stream);

    pass1_cvt<<<p1_blocks, blk, 0, stream>>>(erow, ecol, ui_vals, iu_vals,
                                             pcurU, pcurI, cbufU, cbufI,
                                             embed_user, embed_item, old_U, old_I,
                                             e8U, e8I, o8U, o8I);
    refine<<<rf_blocks, blk, 0, stream>>>(pcurU, cbufU, fcurU, fbufU,
                                          pcurI, cbufI, fcurI, fbufI);
    sort_csr<<<st_blocks, blk, 0, stream>>>(fcurU, fbufU, ptrU, cntUa, edgesU,
                                            fcurI, fbufI, ptrI, cntIa, edgesI);

    spmm_level<0><<<spmm_blocks, blk, 0, stream>>>(
        ptrU, cntUa, edgesU, e8I, u1_8, embed_user, gcn_u, g8U,
        ptrI, cntIa, edgesI, e8U, i1_8, embed_item, gcn_i, g8I, 0.5f / 128.f);
    spmm_level<1><<<spmm_blocks, blk, 0, stream>>>(
        ptrU, cntUa, edgesU, i1_8, u2_8, nullptr, gcn_u, g8U,
        ptrI, cntIa, edgesI, u1_8, i2_8, nullptr, gcn_i, g8I, 1.f / 3.f / 128.f);
    spmm_level<2><<<spmm_blocks, blk, 0, stream>>>(
        ptrU, cntUa, edgesU, i2_8, nullptr, nullptr, gcn_u, g8U,
        ptrI, cntIa, edgesI, u2_8, nullptr, nullptr, gcn_i, g8I, 0.25f / 128.f);

    contrastive_both<<<2048, blk, 0, stream>>>(o8U, g8U, user, item_i, item_j, degU,
                                               o8I, g8I, user_, item_i_, item_j_, degI,
                                               (float*)d_out);
}

// Round 12
// 318.736 us; speedup vs baseline: 3.4139x; 1.0306x over previous
//
#include <hip/hip_runtime.h>

#define U_NUM 50000
#define I_NUM 20000
#define F_DIM 64
#define N_EDGES 1000000
#define BATCH 131072

#define P_U 25
#define P_I 20
#define CAPP_U 45056
#define CAPP_I 55296
#define FP_U 200
#define FP_I 160
#define CAPF_U 5632
#define CAPF_I 6912
#define BRU 40
#define BRI 50
#define P1B 977            // (N_EDGES+1023)/1024

// fp8 e4m3 (OCP) helpers; HW converts on gfx950, software fallback otherwise.
#if defined(__has_builtin)
#if __has_builtin(__builtin_amdgcn_cvt_pk_f32_fp8) && __has_builtin(__builtin_amdgcn_cvt_pk_fp8_f32)
#define HW_FP8 1
#endif
#endif

typedef float v2f __attribute__((ext_vector_type(2)));

__device__ __forceinline__ void dec4(unsigned u, float* f) {
#ifdef HW_FP8
    v2f lo = __builtin_amdgcn_cvt_pk_f32_fp8((int)u, false);
    v2f hi = __builtin_amdgcn_cvt_pk_f32_fp8((int)u, true);
    f[0] = lo.x; f[1] = lo.y; f[2] = hi.x; f[3] = hi.y;
#else
    #pragma unroll
    for (int i = 0; i < 4; i++) {
        unsigned v = (u >> (8 * i)) & 0xFFu;
        unsigned s = v >> 7, e = (v >> 3) & 15u, m = v & 7u;
        float mag = (e == 0) ? (float)m * 0.001953125f
                             : __uint_as_float(((e + 120u) << 23) | (m << 20));
        f[i] = s ? -mag : mag;
    }
#endif
}

#ifndef HW_FP8
__device__ __forceinline__ unsigned char enc1(float x) {
    unsigned s = (__float_as_uint(x) >> 31) << 7;
    float a = fabsf(x);
    if (a >= 448.f) return (unsigned char)(s | 0x7E);
    if (a < 0.015625f) {
        int m = __float2int_rn(a * 512.f);
        if (m >= 8) return (unsigned char)(s | 0x08);
        return (unsigned char)(s | m);
    }
    unsigned au = __float_as_uint(a);
    au += 0x7FFFFu + ((au >> 20) & 1u);
    int e = (int)(au >> 23) - 127;
    if (e > 8) return (unsigned char)(s | 0x7E);
    return (unsigned char)(s | ((unsigned)(e + 7) << 3) | ((au >> 20) & 7u));
}
#endif

__device__ __forceinline__ unsigned enc4(float a, float b, float c, float d) {
#ifdef HW_FP8
    int v = __builtin_amdgcn_cvt_pk_fp8_f32(a, b, 0, false);
    v = __builtin_amdgcn_cvt_pk_fp8_f32(c, d, v, true);
    return (unsigned)v;
#else
    return (unsigned)enc1(a) | ((unsigned)enc1(b) << 8)
         | ((unsigned)enc1(c) << 16) | ((unsigned)enc1(d) << 24);
#endif
}

// ---------------- pass 1 (+ merged fp32->fp8 table cvt) ----------------------
#define N_EU 800000
#define N_EI 320000
#define N_OU 800000
#define N_OI 320000
__global__ void pass1_cvt(const int* __restrict__ rows, const int* __restrict__ cols,
                          const float* __restrict__ uiv, const float* __restrict__ iuv,
                          int* __restrict__ pcurU, int* __restrict__ pcurI,
                          int2* __restrict__ cbufU, int2* __restrict__ cbufI,
                          const float* __restrict__ eU, const float* __restrict__ eI,
                          const float* __restrict__ oU, const float* __restrict__ oI,
                          unsigned* __restrict__ e8U, unsigned* __restrict__ e8I,
                          unsigned* __restrict__ o8U, unsigned* __restrict__ o8I)
{
    if (blockIdx.x >= P1B) {
        int idx = (blockIdx.x - P1B) * 256 + threadIdx.x;
        const float* s; unsigned* d; int off; float sc;
        if (idx < N_EU)                        { s = eU; d = e8U; off = idx; sc = 128.f; }
        else if (idx < N_EU + N_EI)            { s = eI; d = e8I; off = idx - N_EU; sc = 128.f; }
        else if (idx < N_EU + N_EI + N_OU)     { s = oU; d = o8U; off = idx - N_EU - N_EI; sc = 1.f; }
        else if (idx < N_EU + N_EI + N_OU + N_OI) { s = oI; d = o8I; off = idx - N_EU - N_EI - N_OU; sc = 1.f; }
        else return;
        float4 v = ((const float4*)s)[off];
        d[off] = enc4(v.x * sc, v.y * sc, v.z * sc, v.w * sc);
        return;
    }

    __shared__ int histU[32], histI[32];
    __shared__ int lbaseU[32], lbaseI[32];
    __shared__ int deltaU[32], deltaI[32];
    __shared__ int totU, totI;
    __shared__ int2 recU[1024], recI[1024];
    __shared__ unsigned char pidU[1024], pidI[1024];

    if (threadIdx.x < 32) { histU[threadIdx.x] = 0; histI[threadIdx.x] = 0; }
    __syncthreads();

    int base = blockIdx.x * 1024;
    int r[4], c[4], lpU[4], lpI[4];
    float vu[4], vi[4];
    #pragma unroll
    for (int i = 0; i < 4; i++) {
        int e = base + threadIdx.x + i * 256;
        if (e < N_EDGES) {
            r[i] = rows[e]; c[i] = cols[e];
            vu[i] = uiv[e]; vi[i] = iuv[e];
            lpU[i] = atomicAdd(&histU[r[i] >> 11], 1);
            lpI[i] = atomicAdd(&histI[c[i] >> 10], 1);
        } else {
            lpU[i] = -1; lpI[i] = -1; r[i] = 0; c[i] = 0; vu[i] = 0.f; vi[i] = 0.f;
        }
    }
    __syncthreads();

    int lane = threadIdx.x & 63;
    int w    = threadIdx.x >> 6;
    if (w == 0) {
        int h = (lane < 32) ? histU[lane] : 0;
        int res = (lane < 32 && h) ? atomicAdd(&pcurU[lane], h) : 0;
        int inc = h;
        #pragma unroll
        for (int off = 1; off < 32; off <<= 1) {
            int t = __shfl_up(inc, off, 64);
            if (lane >= off) inc += t;
        }
        if (lane < 32) {
            int lb = inc - h;
            lbaseU[lane] = lb;
            deltaU[lane] = lane * CAPP_U + res - lb;
            if (lane == 31) totU = inc;
        }
    } else if (w == 1) {
        int h = (lane < 32) ? histI[lane] : 0;
        int res = (lane < 32 && h) ? atomicAdd(&pcurI[lane], h) : 0;
        int inc = h;
        #pragma unroll
        for (int off = 1; off < 32; off <<= 1) {
            int t = __shfl_up(inc, off, 64);
            if (lane >= off) inc += t;
        }
        if (lane < 32) {
            int lb = inc - h;
            lbaseI[lane] = lb;
            deltaI[lane] = lane * CAPP_I + res - lb;
            if (lane == 31) totI = inc;
        }
    }
    __syncthreads();

    #pragma unroll
    for (int i = 0; i < 4; i++) {
        if (lpU[i] >= 0) {
            int p = r[i] >> 11;
            int slot = lbaseU[p] + lpU[i];
            int2 rec;
            rec.x = (int)(((unsigned)c[i] << 16) | (unsigned)r[i]);
            rec.y = __float_as_int(vu[i]);
            recU[slot] = rec;
            pidU[slot] = (unsigned char)p;

            p = c[i] >> 10;
            slot = lbaseI[p] + lpI[i];
            rec.x = (int)(((unsigned)r[i] << 16) | (unsigned)c[i]);
            rec.y = __float_as_int(vi[i]);
            recI[slot] = rec;
            pidI[slot] = (unsigned char)p;
        }
    }
    __syncthreads();

    for (int t = threadIdx.x; t < totU; t += 256) {
        int p = pidU[t];
        int a = deltaU[p] + t;
        if (a < (p + 1) * CAPP_U) cbufU[a] = recU[t];
    }
    for (int t = threadIdx.x; t < totI; t += 256) {
        int p = pidI[t];
        int a = deltaI[p] + t;
        if (a < (p + 1) * CAPP_I) cbufI[a] = recI[t];
    }
}

// ---------------- refine: coarse -> 8 fine partitions ------------------------
__global__ void refine(const int* __restrict__ pcurU, const int2* __restrict__ cbufU,
                       int* __restrict__ fcurU, int2* __restrict__ fbufU,
                       const int* __restrict__ pcurI, const int2* __restrict__ cbufI,
                       int* __restrict__ fcurI, int2* __restrict__ fbufI)
{
    const int* pcur; const int2* cbuf; int* fcur; int2* fbuf;
    int p, b, br, capp, capf, shift;
    if (blockIdx.x < P_U * BRU) {
        pcur = pcurU; cbuf = cbufU; fcur = fcurU; fbuf = fbufU;
        p = blockIdx.x / BRU; b = blockIdx.x % BRU; br = BRU;
        capp = CAPP_U; capf = CAPF_U; shift = 8;
    } else {
        int q = blockIdx.x - P_U * BRU;
        pcur = pcurI; cbuf = cbufI; fcur = fcurI; fbuf = fbufI;
        p = q / BRI; b = q % BRI; br = BRI;
        capp = CAPP_I; capf = CAPF_I; shift = 7;
    }
    int n = min(pcur[p], capp);
    const int2* src = cbuf + (size_t)p * capp;

    __shared__ int hist[8], lbase[8], delta[8];
    __shared__ int tot;
    __shared__ int2 rec[1024];
    __shared__ unsigned char pid[1024];

    for (int base = b * 1024; base < n; base += br * 1024) {
        __syncthreads();
        if (threadIdx.x < 8) hist[threadIdx.x] = 0;
        __syncthreads();
        int2 rr[4]; int ff[4], lp[4];
        #pragma unroll
        for (int i = 0; i < 4; i++) {
            int t = base + i * 256 + threadIdx.x;
            if (t < n) {
                rr[i] = src[t];
                ff[i] = (int)((((unsigned)rr[i].x & 0xFFFFu) >> shift) & 7u);
                lp[i] = atomicAdd(&hist[ff[i]], 1);
            } else lp[i] = -1;
        }
        __syncthreads();
        if ((threadIdx.x >> 6) == 0) {
            int lane = threadIdx.x & 63;
            int h = (lane < 8) ? hist[lane] : 0;
            int res = (lane < 8 && h) ? atomicAdd(&fcur[p * 8 + lane], h) : 0;
            int inc = h;
            #pragma unroll
            for (int off = 1; off < 8; off <<= 1) {
                int t = __shfl_up(inc, off, 64);
                if (lane >= off) inc += t;
            }
            if (lane < 8) {
                int lb = inc - h;
                lbase[lane] = lb;
                delta[lane] = (p * 8 + lane) * capf + res - lb;
                if (lane == 7) tot = inc;
            }
        }
        __syncthreads();
        #pragma unroll
        for (int i = 0; i < 4; i++) {
            if (lp[i] >= 0) {
                int slot = lbase[ff[i]] + lp[i];
                rec[slot] = rr[i];
                pid[slot] = (unsigned char)ff[i];
            }
        }
        __syncthreads();
        for (int t = threadIdx.x; t < tot; t += 256) {
            int f2 = pid[t];
            int a = delta[f2] + t;
            if (a < (p * 8 + f2 + 1) * capf) fbuf[a] = rec[t];
        }
    }
}

// ---------------- sort_csr: fine partition -> exact CSR + ptr/cnt ------------
__global__ void sort_csr(const int* __restrict__ fcurU, const int2* __restrict__ fbufU,
                         int* __restrict__ ptrU, int* __restrict__ cntU, int2* __restrict__ edgesU,
                         const int* __restrict__ fcurI, const int2* __restrict__ fbufI,
                         int* __restrict__ ptrI, int* __restrict__ cntI, int2* __restrict__ edgesI)
{
    __shared__ int hist[256], scan[256], curs[256];
    __shared__ int gbase_s;

    const int* fcur; const int2* fbuf; int* ptr; int* cnt; int2* edges;
    int fp, bins, capf, nrow;
    if (blockIdx.x < FP_U) {
        fcur = fcurU; fbuf = fbufU; ptr = ptrU; cnt = cntU; edges = edgesU;
        fp = blockIdx.x; bins = 256; capf = CAPF_U; nrow = U_NUM;
    } else {
        fcur = fcurI; fbuf = fbufI; ptr = ptrI; cnt = cntI; edges = edgesI;
        fp = blockIdx.x - FP_U; bins = 128; capf = CAPF_I; nrow = I_NUM;
    }

    if (threadIdx.x == 0) gbase_s = 0;
    for (int i = threadIdx.x; i < bins; i += 256) hist[i] = 0;
    __syncthreads();

    int contrib = ((int)threadIdx.x < fp) ? min(fcur[threadIdx.x], capf) : 0;
    #pragma unroll
    for (int off = 32; off > 0; off >>= 1) contrib += __shfl_down(contrib, off, 64);
    if ((threadIdx.x & 63) == 0 && contrib) atomicAdd(&gbase_s, contrib);

    int n = min(fcur[fp], capf);
    const int2* src = fbuf + (size_t)fp * capf;
    int mask = bins - 1;

    for (int t = threadIdx.x; t < n; t += 256) {
        int dst = src[t].x & 0xFFFF;
        atomicAdd(&hist[dst & mask], 1);
    }
    __syncthreads();

    int v = ((int)threadIdx.x < bins) ? hist[threadIdx.x] : 0;
    scan[threadIdx.x] = v;
    __syncthreads();
    for (int off = 1; off < 256; off <<= 1) {
        int t = ((int)threadIdx.x >= off) ? scan[threadIdx.x - off] : 0;
        __syncthreads();
        scan[threadIdx.x] += t;
        __syncthreads();
    }
    int ex = scan[threadIdx.x] - v;
    curs[threadIdx.x] = ex;
    __syncthreads();
    int gbase = gbase_s;

    if ((int)threadIdx.x < bins) {
        int row = fp * bins + threadIdx.x;
        if (row < nrow) {
            ptr[row] = gbase + ex;
            cnt[row] = v;
        }
    }

    for (int t = threadIdx.x; t < n; t += 256) {
        int2 r = src[t];
        int dst = r.x & 0xFFFF;
        int pos = atomicAdd(&curs[dst & mask], 1);
        int2 o;
        o.x = (int)((unsigned)r.x >> 16);
        o.y = r.y;
        edges[gbase + pos] = o;
    }
}

// ---------------- fused-level gather SpMM (fp8 in, fp8 out, NO fp32 gcn) -----
// All stored levels carry the x128 scale; the scale cancels level-to-level.
//   MODE 0/1: dst8 = enc(acc)                                 (4.5 MB write only)
//   MODE 2:   g8 = enc(0.125*(l0 + 0.5*l1 + (1/3)*l2 + 0.25*acc))
//             (l0=e8 table, l1/l2 = stored level fp8 rows; = 16*gcn for the loss)
// r11 profile: fp32 gcn stream was 36 MB/level of the 63 MB HBM traffic.
template <int MODE>
__global__ void spmm_level(const int* __restrict__ ptrU, const int* __restrict__ cntU,
                           const int2* __restrict__ edgesU, const unsigned* __restrict__ srcU,
                           unsigned* __restrict__ dstU,
                           const unsigned* __restrict__ l0U, const unsigned* __restrict__ l1U,
                           const unsigned* __restrict__ l2U, unsigned* __restrict__ g8U,
                           const int* __restrict__ ptrI, const int* __restrict__ cntI,
                           const int2* __restrict__ edgesI, const unsigned* __restrict__ srcI,
                           unsigned* __restrict__ dstI,
                           const unsigned* __restrict__ l0I, const unsigned* __restrict__ l1I,
                           const unsigned* __restrict__ l2I, unsigned* __restrict__ g8I)
{
    int wave = (blockIdx.x * blockDim.x + threadIdx.x) >> 6;
    bool isU = wave < U_NUM;
    int row = isU ? wave : wave - U_NUM;
    if (!isU && row >= I_NUM) return;

    const int*  ptr   = isU ? ptrU   : ptrI;
    const int*  cnt   = isU ? cntU   : cntI;
    const int2* edges = isU ? edgesU : edgesI;
    const unsigned* semb = isU ? srcU : srcI;

    int lane = threadIdx.x & 63;
    int sub  = lane >> 4;
    int q    = lane & 15;
    int begin = ptr[row];
    int len   = cnt[row];

    float4 a0 = make_float4(0.f, 0.f, 0.f, 0.f);
    float4 a1 = make_float4(0.f, 0.f, 0.f, 0.f);
    float4 a2 = make_float4(0.f, 0.f, 0.f, 0.f);
    float4 a3 = make_float4(0.f, 0.f, 0.f, 0.f);
    int k = sub;
    for (; k + 12 < len; k += 16) {
        int2 e0 = edges[begin + k];
        int2 e1 = edges[begin + k + 4];
        int2 e2 = edges[begin + k + 8];
        int2 e3 = edges[begin + k + 12];
        unsigned x0 = semb[((size_t)e0.x << 4) + q];
        unsigned x1 = semb[((size_t)e1.x << 4) + q];
        unsigned x2 = semb[((size_t)e2.x << 4) + q];
        unsigned x3 = semb[((size_t)e3.x << 4) + q];
        float v0 = __int_as_float(e0.y), v1 = __int_as_float(e1.y);
        float v2 = __int_as_float(e2.y), v3 = __int_as_float(e3.y);
        float f0[4], f1[4], f2[4], f3[4];
        dec4(x0, f0); dec4(x1, f1); dec4(x2, f2); dec4(x3, f3);
        a0.x += v0 * f0[0]; a0.y += v0 * f0[1]; a0.z += v0 * f0[2]; a0.w += v0 * f0[3];
        a1.x += v1 * f1[0]; a1.y += v1 * f1[1]; a1.z += v1 * f1[2]; a1.w += v1 * f1[3];
        a2.x += v2 * f2[0]; a2.y += v2 * f2[1]; a2.z += v2 * f2[2]; a2.w += v2 * f2[3];
        a3.x += v3 * f3[0]; a3.y += v3 * f3[1]; a3.z += v3 * f3[2]; a3.w += v3 * f3[3];
    }
    for (; k < len; k += 4) {
        int2 e0 = edges[begin + k];
        unsigned x0 = semb[((size_t)e0.x << 4) + q];
        float v0 = __int_as_float(e0.y);
        float f0[4];
        dec4(x0, f0);
        a0.x += v0 * f0[0]; a0.y += v0 * f0[1]; a0.z += v0 * f0[2]; a0.w += v0 * f0[3];
    }
    float4 acc;
    acc.x = (a0.x + a1.x) + (a2.x + a3.x);
    acc.y = (a0.y + a1.y) + (a2.y + a3.y);
    acc.z = (a0.z + a1.z) + (a2.z + a3.z);
    acc.w = (a0.w + a1.w) + (a2.w + a3.w);

    acc.x += __shfl_xor(acc.x, 16, 64);
    acc.y += __shfl_xor(acc.y, 16, 64);
    acc.z += __shfl_xor(acc.z, 16, 64);
    acc.w += __shfl_xor(acc.w, 16, 64);
    acc.x += __shfl_xor(acc.x, 32, 64);
    acc.y += __shfl_xor(acc.y, 32, 64);
    acc.z += __shfl_xor(acc.z, 32, 64);
    acc.w += __shfl_xor(acc.w, 32, 64);

    if (sub == 0) {
        size_t ro = ((size_t)row << 4) + q;
        if (MODE < 2) {
            unsigned* dst = isU ? dstU : dstI;
            dst[ro] = enc4(acc.x, acc.y, acc.z, acc.w);
        } else {
            const unsigned* l0 = isU ? l0U : l0I;
            const unsigned* l1 = isU ? l1U : l1I;
            const unsigned* l2 = isU ? l2U : l2I;
            unsigned* g8       = isU ? g8U : g8I;
            float e[4], b[4], c[4];
            dec4(l0[ro], e); dec4(l1[ro], b); dec4(l2[ro], c);
            const float third = 1.f / 3.f;
            float gx = 0.125f * (e[0] + 0.5f * b[0] + third * c[0] + 0.25f * acc.x);
            float gy = 0.125f * (e[1] + 0.5f * b[1] + third * c[1] + 0.25f * acc.y);
            float gz = 0.125f * (e[2] + 0.5f * b[2] + third * c[2] + 0.25f * acc.z);
            float gw = 0.125f * (e[3] + 0.5f * b[3] + third * c[3] + 0.25f * acc.w);
            g8[ro] = enc4(gx, gy, gz, gw);
        }
    }
}

// ---------------- contrastive loss v3: MLP-restructured ----------------------
__device__ __forceinline__ float dotq(const float* a, const float* b) {
    return a[0] * b[0] + a[1] * b[1] + a[2] * b[2] + a[3] * b[3];
}

__global__ void __launch_bounds__(256, 2)
contrastive_both(const unsigned* __restrict__ oldU, const unsigned* __restrict__ gcnU,
                 const int* __restrict__ userU, const int* __restrict__ iiU,
                 const int* __restrict__ ijU, const float* __restrict__ degU,
                 const unsigned* __restrict__ oldI, const unsigned* __restrict__ gcnI,
                 const int* __restrict__ userI, const int* __restrict__ iiI,
                 const int* __restrict__ ijI, const float* __restrict__ degI,
                 float* __restrict__ out)
{
    int lane = threadIdx.x & 63;
    int sub  = lane >> 4;
    int ql   = lane & 15;
    int qg = (blockIdx.x * blockDim.x + threadIdx.x) >> 4;
    int s0 = qg << 2;

    int sel = ql >> 2, so = s0 + (ql & 3);
    const int* pu = (sel == 0) ? (userU + so) : (sel == 1) ? (iiU + so)
                  : (sel == 2) ? (ijU + so)   : ((const int*)degU + so);
    const int* pi = (sel == 0) ? (userI + so) : (sel == 1) ? (iiI + so)
                  : (sel == 2) ? (ijI + so)   : ((const int*)degI + so);
    int idxU = *pu;
    int idxI = *pi;

    int qb = sub << 4;
    unsigned Au[4], Ai[4], Aj[4], Bu[4], Bi[4], Bj[4];
    #pragma unroll
    for (int t = 0; t < 4; t++) {
        int uU = __shfl(idxU, qb + t, 64);
        int iU = __shfl(idxU, qb + 4 + t, 64);
        int jU = __shfl(idxU, qb + 8 + t, 64);
        int uI = __shfl(idxI, qb + t, 64);
        int iI = __shfl(idxI, qb + 4 + t, 64);
        int jI = __shfl(idxI, qb + 8 + t, 64);
        Au[t] = oldU[((size_t)uU << 4) + ql];
        Ai[t] = gcnU[((size_t)iU << 4) + ql];
        Aj[t] = gcnU[((size_t)jU << 4) + ql];
        Bu[t] = oldI[((size_t)uI << 4) + ql];
        Bi[t] = gcnI[((size_t)iI << 4) + ql];
        Bj[t] = gcnI[((size_t)jI << 4) + ql];
    }

    float siU[4], sjU[4], siI[4], sjI[4];
    #pragma unroll
    for (int t = 0; t < 4; t++) {
        float fu[4], fi[4], fj[4];
        dec4(Au[t], fu); dec4(Ai[t], fi); dec4(Aj[t], fj);
        siU[t] = dotq(fu, fi); sjU[t] = dotq(fu, fj);
        dec4(Bu[t], fu); dec4(Bi[t], fi); dec4(Bj[t], fj);
        siI[t] = dotq(fu, fi); sjI[t] = dotq(fu, fj);
    }

    #pragma unroll
    for (int off = 1; off < 16; off <<= 1) {
        #pragma unroll
        for (int t = 0; t < 4; t++) {
            siU[t] += __shfl_xor(siU[t], off, 64);
            sjU[t] += __shfl_xor(sjU[t], off, 64);
            siI[t] += __shfl_xor(siI[t], off, 64);
            sjI[t] += __shfl_xor(sjI[t], off, 64);
        }
    }

    int t3 = ql & 3;
    bool isI = (ql & 4) != 0;
    float si = isI ? siI[t3] : siU[t3];
    float sj = isI ? sjI[t3] : sjU[t3];
    float dg = __int_as_float(__shfl(isI ? idxI : idxU, qb + 12 + t3, 64));
    float inv = isI ? (1.f / I_NUM) : (1.f / U_NUM);

    const float S = 0.0625f;
    si *= S; sj *= S;
    float m = fmaxf(si, sj);
    float lse = m + logf(expf(si - m) + expf(sj - m));
    float acc = (ql < 8) ? -(si - lse) * dg * inv : 0.f;

    #pragma unroll
    for (int off = 32; off > 0; off >>= 1) acc += __shfl_down(acc, off, 64);
    __shared__ float wsum[4];
    if (lane == 0) wsum[threadIdx.x >> 6] = acc;
    __syncthreads();
    if (threadIdx.x == 0)
        atomicAdd(out, wsum[0] + wsum[1] + wsum[2] + wsum[3]);
}

extern "C" void kernel_launch(void* const* d_in, const int* in_sizes, int n_in,
                              void* d_out, int out_size, void* d_ws, size_t ws_size,
                              hipStream_t stream)
{
    const float* embed_user = (const float*)d_in[0];
    const float* embed_item = (const float*)d_in[1];
    const float* old_U      = (const float*)d_in[2];
    const float* old_I      = (const float*)d_in[3];
    const int*   erow       = (const int*)d_in[4];
    const int*   ecol       = (const int*)d_in[5];
    const float* ui_vals    = (const float*)d_in[6];
    const float* iu_vals    = (const float*)d_in[7];
    const int*   user       = (const int*)d_in[8];
    const int*   item_i     = (const int*)d_in[9];
    const int*   item_j     = (const int*)d_in[10];
    const float* degU       = (const float*)d_in[11];
    const int*   user_      = (const int*)d_in[13];
    const int*   item_i_    = (const int*)d_in[14];
    const int*   item_j_    = (const int*)d_in[15];
    const float* degI       = (const float*)d_in[16];

    const size_t UF = (size_t)U_NUM * F_DIM;
    const size_t IF = (size_t)I_NUM * F_DIM;
    const size_t CREC = (size_t)P_U * CAPP_U + (size_t)P_I * CAPP_I;

    int2*  cbufU  = (int2*)d_ws;
    int2*  cbufI  = cbufU + (size_t)P_U * CAPP_U;
    int2*  edgesU = (int2*)d_ws;
    int2*  edgesI = edgesU + N_EDGES;
    int2*  fbufU  = (int2*)d_ws + CREC;
    int2*  fbufI  = fbufU + (size_t)FP_U * CAPF_U;
    char* cur = (char*)d_ws + 2 * CREC * sizeof(int2);
    unsigned* e8U = (unsigned*)cur; cur += UF;
    unsigned* e8I = (unsigned*)cur; cur += IF;
    unsigned* o8U = (unsigned*)cur; cur += UF;
    unsigned* o8I = (unsigned*)cur; cur += IF;
    unsigned* u1_8 = (unsigned*)cur; cur += UF;
    unsigned* u2_8 = (unsigned*)cur; cur += UF;
    unsigned* i1_8 = (unsigned*)cur; cur += IF;
    unsigned* i2_8 = (unsigned*)cur; cur += IF;
    unsigned* g8U  = (unsigned*)cur; cur += UF;
    unsigned* g8I  = (unsigned*)cur; cur += IF;
    int* pcurU = (int*)cur;
    int* pcurI = pcurU + 32;
    int* fcurU = pcurI + 32;
    int* fcurI = fcurU + 256;
    int* ptrU  = fcurI + 256;
    int* cntUa = ptrU + U_NUM;
    int* ptrI  = cntUa + U_NUM;
    int* cntIa = ptrI + I_NUM;

    dim3 blk(256);
    const int cv_blocks  = (N_EU + N_EI + N_OU + N_OI + 255) / 256;
    const int p1_blocks  = P1B + cv_blocks;
    const int rf_blocks  = P_U * BRU + P_I * BRI;
    const int st_blocks  = FP_U + FP_I;
    const int spmm_blocks = (U_NUM + I_NUM) / 4;

    hipMemsetAsync(pcurU, 0, 576 * sizeof(int), stream);
    hipMemsetAsync(d_out, 0, sizeof(float), stream);

    pass1_cvt<<<p1_blocks, blk, 0, stream>>>(erow, ecol, ui_vals, iu_vals,
                                             pcurU, pcurI, cbufU, cbufI,
                                             embed_user, embed_item, old_U, old_I,
                                             e8U, e8I, o8U, o8I);
    refine<<<rf_blocks, blk, 0, stream>>>(pcurU, cbufU, fcurU, fbufU,
                                          pcurI, cbufI, fcurI, fbufI);
    sort_csr<<<st_blocks, blk, 0, stream>>>(fcurU, fbufU, ptrU, cntUa, edgesU,
                                            fcurI, fbufI, ptrI, cntIa, edgesI);

    // L1: u1_8 = enc(128*u1) ; i1_8 = enc(128*i1)
    spmm_level<0><<<spmm_blocks, blk, 0, stream>>>(
        ptrU, cntUa, edgesU, e8I, u1_8, nullptr, nullptr, nullptr, nullptr,
        ptrI, cntIa, edgesI, e8U, i1_8, nullptr, nullptr, nullptr, nullptr);
    // L2: u2_8 = enc(128*u2) ; i2_8 = enc(128*i2)
    spmm_level<1><<<spmm_blocks, blk, 0, stream>>>(
        ptrU, cntUa, edgesU, i1_8, u2_8, nullptr, nullptr, nullptr, nullptr,
        ptrI, cntIa, edgesI, u1_8, i2_8, nullptr, nullptr, nullptr, nullptr);
    // L3: g8 = enc(0.125*(l0 + 0.5*l1 + (1/3)*l2 + 0.25*acc)) = enc(16*gcn)
    spmm_level<2><<<spmm_blocks, blk, 0, stream>>>(
        ptrU, cntUa, edgesU, i2_8, nullptr, e8U, u1_8, u2_8, g8U,
        ptrI, cntIa, edgesI, u2_8, nullptr, e8I, i1_8, i2_8, g8I);

    contrastive_both<<<2048, blk, 0, stream>>>(o8U, g8U, user, item_i, item_j, degU,
                                               o8I, g8I, user_, item_i_, item_j_, degI,
                                               (float*)d_out);
}

// Round 13
// 307.141 us; speedup vs baseline: 3.5428x; 1.0377x over previous
//
#include <hip/hip_runtime.h>

#define U_NUM 50000
#define I_NUM 20000
#define F_DIM 64
#define N_EDGES 1000000
#define BATCH 131072

#define P_U 25
#define P_I 20
#define CAPP_U 45056
#define CAPP_I 55296
#define FP_U 200
#define FP_I 160
#define CAPF_U 5632
#define CAPF_I 6912
#define BRU 40
#define BRI 50
#define P1B 977            // (N_EDGES+1023)/1024

// fp8 e4m3 (OCP) helpers; HW converts on gfx950, software fallback otherwise.
#if defined(__has_builtin)
#if __has_builtin(__builtin_amdgcn_cvt_pk_f32_fp8) && __has_builtin(__builtin_amdgcn_cvt_pk_fp8_f32)
#define HW_FP8 1
#endif
#endif

typedef float v2f __attribute__((ext_vector_type(2)));

__device__ __forceinline__ void dec4(unsigned u, float* f) {
#ifdef HW_FP8
    v2f lo = __builtin_amdgcn_cvt_pk_f32_fp8((int)u, false);
    v2f hi = __builtin_amdgcn_cvt_pk_f32_fp8((int)u, true);
    f[0] = lo.x; f[1] = lo.y; f[2] = hi.x; f[3] = hi.y;
#else
    #pragma unroll
    for (int i = 0; i < 4; i++) {
        unsigned v = (u >> (8 * i)) & 0xFFu;
        unsigned s = v >> 7, e = (v >> 3) & 15u, m = v & 7u;
        float mag = (e == 0) ? (float)m * 0.001953125f
                             : __uint_as_float(((e + 120u) << 23) | (m << 20));
        f[i] = s ? -mag : mag;
    }
#endif
}

#ifndef HW_FP8
__device__ __forceinline__ unsigned char enc1(float x) {
    unsigned s = (__float_as_uint(x) >> 31) << 7;
    float a = fabsf(x);
    if (a >= 448.f) return (unsigned char)(s | 0x7E);
    if (a < 0.015625f) {
        int m = __float2int_rn(a * 512.f);
        if (m >= 8) return (unsigned char)(s | 0x08);
        return (unsigned char)(s | m);
    }
    unsigned au = __float_as_uint(a);
    au += 0x7FFFFu + ((au >> 20) & 1u);
    int e = (int)(au >> 23) - 127;
    if (e > 8) return (unsigned char)(s | 0x7E);
    return (unsigned char)(s | ((unsigned)(e + 7) << 3) | ((au >> 20) & 7u));
}
#endif

__device__ __forceinline__ unsigned enc4(float a, float b, float c, float d) {
#ifdef HW_FP8
    int v = __builtin_amdgcn_cvt_pk_fp8_f32(a, b, 0, false);
    v = __builtin_amdgcn_cvt_pk_fp8_f32(c, d, v, true);
    return (unsigned)v;
#else
    return (unsigned)enc1(a) | ((unsigned)enc1(b) << 8)
         | ((unsigned)enc1(c) << 16) | ((unsigned)enc1(d) << 24);
#endif
}

// bf16 round-to-nearest-even (for 4B edge records).
__device__ __forceinline__ unsigned short f2b(float f) {
    unsigned b = __float_as_uint(f);
    b += 0x7FFFu + ((b >> 16) & 1u);
    return (unsigned short)(b >> 16);
}

// ---------------- pass 1 (+ merged fp32->fp8 table cvt) ----------------------
#define N_EU 800000
#define N_EI 320000
#define N_OU 800000
#define N_OI 320000
__global__ void pass1_cvt(const int* __restrict__ rows, const int* __restrict__ cols,
                          const float* __restrict__ uiv, const float* __restrict__ iuv,
                          int* __restrict__ pcurU, int* __restrict__ pcurI,
                          int2* __restrict__ cbufU, int2* __restrict__ cbufI,
                          const float* __restrict__ eU, const float* __restrict__ eI,
                          const float* __restrict__ oU, const float* __restrict__ oI,
                          unsigned* __restrict__ e8U, unsigned* __restrict__ e8I,
                          unsigned* __restrict__ o8U, unsigned* __restrict__ o8I)
{
    if (blockIdx.x >= P1B) {
        int idx = (blockIdx.x - P1B) * 256 + threadIdx.x;
        const float* s; unsigned* d; int off; float sc;
        if (idx < N_EU)                        { s = eU; d = e8U; off = idx; sc = 128.f; }
        else if (idx < N_EU + N_EI)            { s = eI; d = e8I; off = idx - N_EU; sc = 128.f; }
        else if (idx < N_EU + N_EI + N_OU)     { s = oU; d = o8U; off = idx - N_EU - N_EI; sc = 1.f; }
        else if (idx < N_EU + N_EI + N_OU + N_OI) { s = oI; d = o8I; off = idx - N_EU - N_EI - N_OU; sc = 1.f; }
        else return;
        float4 v = ((const float4*)s)[off];
        d[off] = enc4(v.x * sc, v.y * sc, v.z * sc, v.w * sc);
        return;
    }

    __shared__ int histU[32], histI[32];
    __shared__ int lbaseU[32], lbaseI[32];
    __shared__ int deltaU[32], deltaI[32];
    __shared__ int totU, totI;
    __shared__ int2 recU[1024], recI[1024];
    __shared__ unsigned char pidU[1024], pidI[1024];

    if (threadIdx.x < 32) { histU[threadIdx.x] = 0; histI[threadIdx.x] = 0; }
    __syncthreads();

    int base = blockIdx.x * 1024;
    int r[4], c[4], lpU[4], lpI[4];
    float vu[4], vi[4];
    #pragma unroll
    for (int i = 0; i < 4; i++) {
        int e = base + threadIdx.x + i * 256;
        if (e < N_EDGES) {
            r[i] = rows[e]; c[i] = cols[e];
            vu[i] = uiv[e]; vi[i] = iuv[e];
            lpU[i] = atomicAdd(&histU[r[i] >> 11], 1);
            lpI[i] = atomicAdd(&histI[c[i] >> 10], 1);
        } else {
            lpU[i] = -1; lpI[i] = -1; r[i] = 0; c[i] = 0; vu[i] = 0.f; vi[i] = 0.f;
        }
    }
    __syncthreads();

    int lane = threadIdx.x & 63;
    int w    = threadIdx.x >> 6;
    if (w == 0) {
        int h = (lane < 32) ? histU[lane] : 0;
        int res = (lane < 32 && h) ? atomicAdd(&pcurU[lane], h) : 0;
        int inc = h;
        #pragma unroll
        for (int off = 1; off < 32; off <<= 1) {
            int t = __shfl_up(inc, off, 64);
            if (lane >= off) inc += t;
        }
        if (lane < 32) {
            int lb = inc - h;
            lbaseU[lane] = lb;
            deltaU[lane] = lane * CAPP_U + res - lb;
            if (lane == 31) totU = inc;
        }
    } else if (w == 1) {
        int h = (lane < 32) ? histI[lane] : 0;
        int res = (lane < 32 && h) ? atomicAdd(&pcurI[lane], h) : 0;
        int inc = h;
        #pragma unroll
        for (int off = 1; off < 32; off <<= 1) {
            int t = __shfl_up(inc, off, 64);
            if (lane >= off) inc += t;
        }
        if (lane < 32) {
            int lb = inc - h;
            lbaseI[lane] = lb;
            deltaI[lane] = lane * CAPP_I + res - lb;
            if (lane == 31) totI = inc;
        }
    }
    __syncthreads();

    #pragma unroll
    for (int i = 0; i < 4; i++) {
        if (lpU[i] >= 0) {
            int p = r[i] >> 11;
            int slot = lbaseU[p] + lpU[i];
            int2 rec;
            rec.x = (int)(((unsigned)c[i] << 16) | (unsigned)r[i]);
            rec.y = __float_as_int(vu[i]);
            recU[slot] = rec;
            pidU[slot] = (unsigned char)p;

            p = c[i] >> 10;
            slot = lbaseI[p] + lpI[i];
            rec.x = (int)(((unsigned)r[i] << 16) | (unsigned)c[i]);
            rec.y = __float_as_int(vi[i]);
            recI[slot] = rec;
            pidI[slot] = (unsigned char)p;
        }
    }
    __syncthreads();

    for (int t = threadIdx.x; t < totU; t += 256) {
        int p = pidU[t];
        int a = deltaU[p] + t;
        if (a < (p + 1) * CAPP_U) cbufU[a] = recU[t];
    }
    for (int t = threadIdx.x; t < totI; t += 256) {
        int p = pidI[t];
        int a = deltaI[p] + t;
        if (a < (p + 1) * CAPP_I) cbufI[a] = recI[t];
    }
}

// ---------------- refine: coarse -> 8 fine partitions ------------------------
__global__ void refine(const int* __restrict__ pcurU, const int2* __restrict__ cbufU,
                       int* __restrict__ fcurU, int2* __restrict__ fbufU,
                       const int* __restrict__ pcurI, const int2* __restrict__ cbufI,
                       int* __restrict__ fcurI, int2* __restrict__ fbufI)
{
    const int* pcur; const int2* cbuf; int* fcur; int2* fbuf;
    int p, b, br, capp, capf, shift;
    if (blockIdx.x < P_U * BRU) {
        pcur = pcurU; cbuf = cbufU; fcur = fcurU; fbuf = fbufU;
        p = blockIdx.x / BRU; b = blockIdx.x % BRU; br = BRU;
        capp = CAPP_U; capf = CAPF_U; shift = 8;
    } else {
        int q = blockIdx.x - P_U * BRU;
        pcur = pcurI; cbuf = cbufI; fcur = fcurI; fbuf = fbufI;
        p = q / BRI; b = q % BRI; br = BRI;
        capp = CAPP_I; capf = CAPF_I; shift = 7;
    }
    int n = min(pcur[p], capp);
    const int2* src = cbuf + (size_t)p * capp;

    __shared__ int hist[8], lbase[8], delta[8];
    __shared__ int tot;
    __shared__ int2 rec[1024];
    __shared__ unsigned char pid[1024];

    for (int base = b * 1024; base < n; base += br * 1024) {
        __syncthreads();
        if (threadIdx.x < 8) hist[threadIdx.x] = 0;
        __syncthreads();
        int2 rr[4]; int ff[4], lp[4];
        #pragma unroll
        for (int i = 0; i < 4; i++) {
            int t = base + i * 256 + threadIdx.x;
            if (t < n) {
                rr[i] = src[t];
                ff[i] = (int)((((unsigned)rr[i].x & 0xFFFFu) >> shift) & 7u);
                lp[i] = atomicAdd(&hist[ff[i]], 1);
            } else lp[i] = -1;
        }
        __syncthreads();
        if ((threadIdx.x >> 6) == 0) {
            int lane = threadIdx.x & 63;
            int h = (lane < 8) ? hist[lane] : 0;
            int res = (lane < 8 && h) ? atomicAdd(&fcur[p * 8 + lane], h) : 0;
            int inc = h;
            #pragma unroll
            for (int off = 1; off < 8; off <<= 1) {
                int t = __shfl_up(inc, off, 64);
                if (lane >= off) inc += t;
            }
            if (lane < 8) {
                int lb = inc - h;
                lbase[lane] = lb;
                delta[lane] = (p * 8 + lane) * capf + res - lb;
                if (lane == 7) tot = inc;
            }
        }
        __syncthreads();
        #pragma unroll
        for (int i = 0; i < 4; i++) {
            if (lp[i] >= 0) {
                int slot = lbase[ff[i]] + lp[i];
                rec[slot] = rr[i];
                pid[slot] = (unsigned char)ff[i];
            }
        }
        __syncthreads();
        for (int t = threadIdx.x; t < tot; t += 256) {
            int f2 = pid[t];
            int a = delta[f2] + t;
            if (a < (p * 8 + f2 + 1) * capf) fbuf[a] = rec[t];
        }
    }
}

// ---------------- sort_csr: fine partition -> exact CSR (4B recs) + ptr/cnt --
// CSR record: (bf16(val)<<16) | src  — 4 bytes. src < 50000 fits 16b both
// sides; bf16 on uniform [0,1) vals = 0.2% err (vs 3% fp8 rows). Halves the
// edge stream the 3 spmm levels read (r12: 16 MB of the 35.6 MB FETCH/level).
__global__ void sort_csr(const int* __restrict__ fcurU, const int2* __restrict__ fbufU,
                         int* __restrict__ ptrU, int* __restrict__ cntU, unsigned* __restrict__ edgesU,
                         const int* __restrict__ fcurI, const int2* __restrict__ fbufI,
                         int* __restrict__ ptrI, int* __restrict__ cntI, unsigned* __restrict__ edgesI)
{
    __shared__ int hist[256], scan[256], curs[256];
    __shared__ int gbase_s;

    const int* fcur; const int2* fbuf; int* ptr; int* cnt; unsigned* edges;
    int fp, bins, capf, nrow;
    if (blockIdx.x < FP_U) {
        fcur = fcurU; fbuf = fbufU; ptr = ptrU; cnt = cntU; edges = edgesU;
        fp = blockIdx.x; bins = 256; capf = CAPF_U; nrow = U_NUM;
    } else {
        fcur = fcurI; fbuf = fbufI; ptr = ptrI; cnt = cntI; edges = edgesI;
        fp = blockIdx.x - FP_U; bins = 128; capf = CAPF_I; nrow = I_NUM;
    }

    if (threadIdx.x == 0) gbase_s = 0;
    for (int i = threadIdx.x; i < bins; i += 256) hist[i] = 0;
    __syncthreads();

    int contrib = ((int)threadIdx.x < fp) ? min(fcur[threadIdx.x], capf) : 0;
    #pragma unroll
    for (int off = 32; off > 0; off >>= 1) contrib += __shfl_down(contrib, off, 64);
    if ((threadIdx.x & 63) == 0 && contrib) atomicAdd(&gbase_s, contrib);

    int n = min(fcur[fp], capf);
    const int2* src = fbuf + (size_t)fp * capf;
    int mask = bins - 1;

    for (int t = threadIdx.x; t < n; t += 256) {
        int dst = src[t].x & 0xFFFF;
        atomicAdd(&hist[dst & mask], 1);
    }
    __syncthreads();

    int v = ((int)threadIdx.x < bins) ? hist[threadIdx.x] : 0;
    scan[threadIdx.x] = v;
    __syncthreads();
    for (int off = 1; off < 256; off <<= 1) {
        int t = ((int)threadIdx.x >= off) ? scan[threadIdx.x - off] : 0;
        __syncthreads();
        scan[threadIdx.x] += t;
        __syncthreads();
    }
    int ex = scan[threadIdx.x] - v;
    curs[threadIdx.x] = ex;
    __syncthreads();
    int gbase = gbase_s;

    if ((int)threadIdx.x < bins) {
        int row = fp * bins + threadIdx.x;
        if (row < nrow) {
            ptr[row] = gbase + ex;
            cnt[row] = v;
        }
    }

    for (int t = threadIdx.x; t < n; t += 256) {
        int2 r = src[t];
        int dst = r.x & 0xFFFF;
        int pos = atomicAdd(&curs[dst & mask], 1);
        unsigned rec = ((unsigned)f2b(__int_as_float(r.y)) << 16)
                     | ((unsigned)r.x >> 16);
        edges[gbase + pos] = rec;
    }
}

// ---------------- fused-level gather SpMM (fp8 in, fp8 out) ------------------
// 4B edge records: v = asfloat(rec & 0xFFFF0000) (bf16 bits ARE the f32 high
// half), src = rec & 0xFFFF. begin/len readfirstlane'd to SGPRs (wave-uniform:
// wave = row) so edge loads use scalar-base addressing — r12 showed the loop
// is VALU-issue bound (~17 wave-insts/edge vs ~5 ideal).
template <int MODE>
__global__ void spmm_level(const int* __restrict__ ptrU, const int* __restrict__ cntU,
                           const unsigned* __restrict__ edgesU, const unsigned* __restrict__ srcU,
                           unsigned* __restrict__ dstU,
                           const unsigned* __restrict__ l0U, const unsigned* __restrict__ l1U,
                           const unsigned* __restrict__ l2U, unsigned* __restrict__ g8U,
                           const int* __restrict__ ptrI, const int* __restrict__ cntI,
                           const unsigned* __restrict__ edgesI, const unsigned* __restrict__ srcI,
                           unsigned* __restrict__ dstI,
                           const unsigned* __restrict__ l0I, const unsigned* __restrict__ l1I,
                           const unsigned* __restrict__ l2I, unsigned* __restrict__ g8I)
{
    int wave = (blockIdx.x * blockDim.x + threadIdx.x) >> 6;
    bool isU = wave < U_NUM;
    int row = isU ? wave : wave - U_NUM;
    if (!isU && row >= I_NUM) return;

    const int*  ptr   = isU ? ptrU   : ptrI;
    const int*  cnt   = isU ? cntU   : cntI;
    const unsigned* edges = isU ? edgesU : edgesI;
    const unsigned* semb  = isU ? srcU   : srcI;

    int lane = threadIdx.x & 63;
    int sub  = lane >> 4;
    int q    = lane & 15;
    // wave-uniform scalars -> SGPRs (enables scalar-base edge addressing)
    int begin = __builtin_amdgcn_readfirstlane(ptr[row]);
    int len   = __builtin_amdgcn_readfirstlane(cnt[row]);
    const unsigned* erow = edges + begin;

    float4 a0 = make_float4(0.f, 0.f, 0.f, 0.f);
    float4 a1 = make_float4(0.f, 0.f, 0.f, 0.f);
    float4 a2 = make_float4(0.f, 0.f, 0.f, 0.f);
    float4 a3 = make_float4(0.f, 0.f, 0.f, 0.f);
    int k = sub;
    for (; k + 12 < len; k += 16) {
        unsigned r0 = erow[k];
        unsigned r1 = erow[k + 4];
        unsigned r2 = erow[k + 8];
        unsigned r3 = erow[k + 12];
        unsigned x0 = semb[((size_t)(r0 & 0xFFFFu) << 4) + q];
        unsigned x1 = semb[((size_t)(r1 & 0xFFFFu) << 4) + q];
        unsigned x2 = semb[((size_t)(r2 & 0xFFFFu) << 4) + q];
        unsigned x3 = semb[((size_t)(r3 & 0xFFFFu) << 4) + q];
        float v0 = __uint_as_float(r0 & 0xFFFF0000u);
        float v1 = __uint_as_float(r1 & 0xFFFF0000u);
        float v2 = __uint_as_float(r2 & 0xFFFF0000u);
        float v3 = __uint_as_float(r3 & 0xFFFF0000u);
        float f0[4], f1[4], f2[4], f3[4];
        dec4(x0, f0); dec4(x1, f1); dec4(x2, f2); dec4(x3, f3);
        a0.x += v0 * f0[0]; a0.y += v0 * f0[1]; a0.z += v0 * f0[2]; a0.w += v0 * f0[3];
        a1.x += v1 * f1[0]; a1.y += v1 * f1[1]; a1.z += v1 * f1[2]; a1.w += v1 * f1[3];
        a2.x += v2 * f2[0]; a2.y += v2 * f2[1]; a2.z += v2 * f2[2]; a2.w += v2 * f2[3];
        a3.x += v3 * f3[0]; a3.y += v3 * f3[1]; a3.z += v3 * f3[2]; a3.w += v3 * f3[3];
    }
    for (; k < len; k += 4) {
        unsigned r0 = erow[k];
        unsigned x0 = semb[((size_t)(r0 & 0xFFFFu) << 4) + q];
        float v0 = __uint_as_float(r0 & 0xFFFF0000u);
        float f0[4];
        dec4(x0, f0);
        a0.x += v0 * f0[0]; a0.y += v0 * f0[1]; a0.z += v0 * f0[2]; a0.w += v0 * f0[3];
    }
    float4 acc;
    acc.x = (a0.x + a1.x) + (a2.x + a3.x);
    acc.y = (a0.y + a1.y) + (a2.y + a3.y);
    acc.z = (a0.z + a1.z) + (a2.z + a3.z);
    acc.w = (a0.w + a1.w) + (a2.w + a3.w);

    acc.x += __shfl_xor(acc.x, 16, 64);
    acc.y += __shfl_xor(acc.y, 16, 64);
    acc.z += __shfl_xor(acc.z, 16, 64);
    acc.w += __shfl_xor(acc.w, 16, 64);
    acc.x += __shfl_xor(acc.x, 32, 64);
    acc.y += __shfl_xor(acc.y, 32, 64);
    acc.z += __shfl_xor(acc.z, 32, 64);
    acc.w += __shfl_xor(acc.w, 32, 64);

    if (sub == 0) {
        size_t ro = ((size_t)row << 4) + q;
        if (MODE < 2) {
            unsigned* dst = isU ? dstU : dstI;
            dst[ro] = enc4(acc.x, acc.y, acc.z, acc.w);
        } else {
            const unsigned* l0 = isU ? l0U : l0I;
            const unsigned* l1 = isU ? l1U : l1I;
            const unsigned* l2 = isU ? l2U : l2I;
            unsigned* g8       = isU ? g8U : g8I;
            float e[4], b[4], c[4];
            dec4(l0[ro], e); dec4(l1[ro], b); dec4(l2[ro], c);
            const float third = 1.f / 3.f;
            float gx = 0.125f * (e[0] + 0.5f * b[0] + third * c[0] + 0.25f * acc.x);
            float gy = 0.125f * (e[1] + 0.5f * b[1] + third * c[1] + 0.25f * acc.y);
            float gz = 0.125f * (e[2] + 0.5f * b[2] + third * c[2] + 0.25f * acc.z);
            float gw = 0.125f * (e[3] + 0.5f * b[3] + third * c[3] + 0.25f * acc.w);
            g8[ro] = enc4(gx, gy, gz, gw);
        }
    }
}

// ---------------- contrastive loss v3: MLP-restructured ----------------------
__device__ __forceinline__ float dotq(const float* a, const float* b) {
    return a[0] * b[0] + a[1] * b[1] + a[2] * b[2] + a[3] * b[3];
}

__global__ void __launch_bounds__(256, 2)
contrastive_both(const unsigned* __restrict__ oldU, const unsigned* __restrict__ gcnU,
                 const int* __restrict__ userU, const int* __restrict__ iiU,
                 const int* __restrict__ ijU, const float* __restrict__ degU,
                 const unsigned* __restrict__ oldI, const unsigned* __restrict__ gcnI,
                 const int* __restrict__ userI, const int* __restrict__ iiI,
                 const int* __restrict__ ijI, const float* __restrict__ degI,
                 float* __restrict__ out)
{
    int lane = threadIdx.x & 63;
    int sub  = lane >> 4;
    int ql   = lane & 15;
    int qg = (blockIdx.x * blockDim.x + threadIdx.x) >> 4;
    int s0 = qg << 2;

    int sel = ql >> 2, so = s0 + (ql & 3);
    const int* pu = (sel == 0) ? (userU + so) : (sel == 1) ? (iiU + so)
                  : (sel == 2) ? (ijU + so)   : ((const int*)degU + so);
    const int* pi = (sel == 0) ? (userI + so) : (sel == 1) ? (iiI + so)
                  : (sel == 2) ? (ijI + so)   : ((const int*)degI + so);
    int idxU = *pu;
    int idxI = *pi;

    int qb = sub << 4;
    unsigned Au[4], Ai[4], Aj[4], Bu[4], Bi[4], Bj[4];
    #pragma unroll
    for (int t = 0; t < 4; t++) {
        int uU = __shfl(idxU, qb + t, 64);
        int iU = __shfl(idxU, qb + 4 + t, 64);
        int jU = __shfl(idxU, qb + 8 + t, 64);
        int uI = __shfl(idxI, qb + t, 64);
        int iI = __shfl(idxI, qb + 4 + t, 64);
        int jI = __shfl(idxI, qb + 8 + t, 64);
        Au[t] = oldU[((size_t)uU << 4) + ql];
        Ai[t] = gcnU[((size_t)iU << 4) + ql];
        Aj[t] = gcnU[((size_t)jU << 4) + ql];
        Bu[t] = oldI[((size_t)uI << 4) + ql];
        Bi[t] = gcnI[((size_t)iI << 4) + ql];
        Bj[t] = gcnI[((size_t)jI << 4) + ql];
    }

    float siU[4], sjU[4], siI[4], sjI[4];
    #pragma unroll
    for (int t = 0; t < 4; t++) {
        float fu[4], fi[4], fj[4];
        dec4(Au[t], fu); dec4(Ai[t], fi); dec4(Aj[t], fj);
        siU[t] = dotq(fu, fi); sjU[t] = dotq(fu, fj);
        dec4(Bu[t], fu); dec4(Bi[t], fi); dec4(Bj[t], fj);
        siI[t] = dotq(fu, fi); sjI[t] = dotq(fu, fj);
    }

    #pragma unroll
    for (int off = 1; off < 16; off <<= 1) {
        #pragma unroll
        for (int t = 0; t < 4; t++) {
            siU[t] += __shfl_xor(siU[t], off, 64);
            sjU[t] += __shfl_xor(sjU[t], off, 64);
            siI[t] += __shfl_xor(siI[t], off, 64);
            sjI[t] += __shfl_xor(sjI[t], off, 64);
        }
    }

    int t3 = ql & 3;
    bool isI = (ql & 4) != 0;
    float si = isI ? siI[t3] : siU[t3];
    float sj = isI ? sjI[t3] : sjU[t3];
    float dg = __int_as_float(__shfl(isI ? idxI : idxU, qb + 12 + t3, 64));
    float inv = isI ? (1.f / I_NUM) : (1.f / U_NUM);

    const float S = 0.0625f;
    si *= S; sj *= S;
    float m = fmaxf(si, sj);
    float lse = m + logf(expf(si - m) + expf(sj - m));
    float acc = (ql < 8) ? -(si - lse) * dg * inv : 0.f;

    #pragma unroll
    for (int off = 32; off > 0; off >>= 1) acc += __shfl_down(acc, off, 64);
    __shared__ float wsum[4];
    if (lane == 0) wsum[threadIdx.x >> 6] = acc;
    __syncthreads();
    if (threadIdx.x == 0)
        atomicAdd(out, wsum[0] + wsum[1] + wsum[2] + wsum[3]);
}

extern "C" void kernel_launch(void* const* d_in, const int* in_sizes, int n_in,
                              void* d_out, int out_size, void* d_ws, size_t ws_size,
                              hipStream_t stream)
{
    const float* embed_user = (const float*)d_in[0];
    const float* embed_item = (const float*)d_in[1];
    const float* old_U      = (const float*)d_in[2];
    const float* old_I      = (const float*)d_in[3];
    const int*   erow       = (const int*)d_in[4];
    const int*   ecol       = (const int*)d_in[5];
    const float* ui_vals    = (const float*)d_in[6];
    const float* iu_vals    = (const float*)d_in[7];
    const int*   user       = (const int*)d_in[8];
    const int*   item_i     = (const int*)d_in[9];
    const int*   item_j     = (const int*)d_in[10];
    const float* degU       = (const float*)d_in[11];
    const int*   user_      = (const int*)d_in[13];
    const int*   item_i_    = (const int*)d_in[14];
    const int*   item_j_    = (const int*)d_in[15];
    const float* degI       = (const float*)d_in[16];

    const size_t UF = (size_t)U_NUM * F_DIM;
    const size_t IF = (size_t)I_NUM * F_DIM;
    const size_t CREC = (size_t)P_U * CAPP_U + (size_t)P_I * CAPP_I;

    int2*  cbufU  = (int2*)d_ws;
    int2*  cbufI  = cbufU + (size_t)P_U * CAPP_U;
    unsigned* edgesU = (unsigned*)d_ws;          // overlay (4B recs, 8 MB total)
    unsigned* edgesI = edgesU + N_EDGES;
    int2*  fbufU  = (int2*)d_ws + CREC;
    int2*  fbufI  = fbufU + (size_t)FP_U * CAPF_U;
    char* cur = (char*)d_ws + 2 * CREC * sizeof(int2);
    unsigned* e8U = (unsigned*)cur; cur += UF;
    unsigned* e8I = (unsigned*)cur; cur += IF;
    unsigned* o8U = (unsigned*)cur; cur += UF;
    unsigned* o8I = (unsigned*)cur; cur += IF;
    unsigned* u1_8 = (unsigned*)cur; cur += UF;
    unsigned* u2_8 = (unsigned*)cur; cur += UF;
    unsigned* i1_8 = (unsigned*)cur; cur += IF;
    unsigned* i2_8 = (unsigned*)cur; cur += IF;
    unsigned* g8U  = (unsigned*)cur; cur += UF;
    unsigned* g8I  = (unsigned*)cur; cur += IF;
    int* pcurU = (int*)cur;
    int* pcurI = pcurU + 32;
    int* fcurU = pcurI + 32;
    int* fcurI = fcurU + 256;
    int* ptrU  = fcurI + 256;
    int* cntUa = ptrU + U_NUM;
    int* ptrI  = cntUa + U_NUM;
    int* cntIa = ptrI + I_NUM;

    dim3 blk(256);
    const int cv_blocks  = (N_EU + N_EI + N_OU + N_OI + 255) / 256;
    const int p1_blocks  = P1B + cv_blocks;
    const int rf_blocks  = P_U * BRU + P_I * BRI;
    const int st_blocks  = FP_U + FP_I;
    const int spmm_blocks = (U_NUM + I_NUM) / 4;

    hipMemsetAsync(pcurU, 0, 576 * sizeof(int), stream);
    hipMemsetAsync(d_out, 0, sizeof(float), stream);

    pass1_cvt<<<p1_blocks, blk, 0, stream>>>(erow, ecol, ui_vals, iu_vals,
                                             pcurU, pcurI, cbufU, cbufI,
                                             embed_user, embed_item, old_U, old_I,
                                             e8U, e8I, o8U, o8I);
    refine<<<rf_blocks, blk, 0, stream>>>(pcurU, cbufU, fcurU, fbufU,
                                          pcurI, cbufI, fcurI, fbufI);
    sort_csr<<<st_blocks, blk, 0, stream>>>(fcurU, fbufU, ptrU, cntUa, edgesU,
                                            fcurI, fbufI, ptrI, cntIa, edgesI);

    // L1: u1_8 = enc(128*u1) ; i1_8 = enc(128*i1)
    spmm_level<0><<<spmm_blocks, blk, 0, stream>>>(
        ptrU, cntUa, edgesU, e8I, u1_8, nullptr, nullptr, nullptr, nullptr,
        ptrI, cntIa, edgesI, e8U, i1_8, nullptr, nullptr, nullptr, nullptr);
    // L2: u2_8 = enc(128*u2) ; i2_8 = enc(128*i2)
    spmm_level<1><<<spmm_blocks, blk, 0, stream>>>(
        ptrU, cntUa, edgesU, i1_8, u2_8, nullptr, nullptr, nullptr, nullptr,
        ptrI, cntIa, edgesI, u1_8, i2_8, nullptr, nullptr, nullptr, nullptr);
    // L3: g8 = enc(0.125*(l0 + 0.5*l1 + (1/3)*l2 + 0.25*acc)) = enc(16*gcn)
    spmm_level<2><<<spmm_blocks, blk, 0, stream>>>(
        ptrU, cntUa, edgesU, i2_8, nullptr, e8U, u1_8, u2_8, g8U,
        ptrI, cntIa, edgesI, u2_8, nullptr, e8I, i1_8, i2_8, g8I);

    contrastive_both<<<2048, blk, 0, stream>>>(o8U, g8U, user, item_i, item_j, degU,
                                               o8I, g8I, user_, item_i_, item_j_, degI,
                                               (float*)d_out);
}

// Round 14
// 304.830 us; speedup vs baseline: 3.5697x; 1.0076x over previous
//
#include <hip/hip_runtime.h>

#define U_NUM 50000
#define I_NUM 20000
#define F_DIM 64
#define N_EDGES 1000000
#define BATCH 131072

#define FP_U 200           // fine partitions: 256 rows each
#define FP_I 160           // fine partitions: 128 cols each
#define CAPF_U 5632        // mean 5120, +7 sigma
#define CAPF_I 6912        // mean 6400, +6.4 sigma
#define TILE 8192
#define NBU 123            // ceil(1M / 8192)
#define NBI 123
#define CVB 512            // grid-strided cvt blocks

// fp8 e4m3 (OCP) helpers; HW converts on gfx950, software fallback otherwise.
#if defined(__has_builtin)
#if __has_builtin(__builtin_amdgcn_cvt_pk_f32_fp8) && __has_builtin(__builtin_amdgcn_cvt_pk_fp8_f32)
#define HW_FP8 1
#endif
#endif

typedef float v2f __attribute__((ext_vector_type(2)));

__device__ __forceinline__ void dec4(unsigned u, float* f) {
#ifdef HW_FP8
    v2f lo = __builtin_amdgcn_cvt_pk_f32_fp8((int)u, false);
    v2f hi = __builtin_amdgcn_cvt_pk_f32_fp8((int)u, true);
    f[0] = lo.x; f[1] = lo.y; f[2] = hi.x; f[3] = hi.y;
#else
    #pragma unroll
    for (int i = 0; i < 4; i++) {
        unsigned v = (u >> (8 * i)) & 0xFFu;
        unsigned s = v >> 7, e = (v >> 3) & 15u, m = v & 7u;
        float mag = (e == 0) ? (float)m * 0.001953125f
                             : __uint_as_float(((e + 120u) << 23) | (m << 20));
        f[i] = s ? -mag : mag;
    }
#endif
}

#ifndef HW_FP8
__device__ __forceinline__ unsigned char enc1(float x) {
    unsigned s = (__float_as_uint(x) >> 31) << 7;
    float a = fabsf(x);
    if (a >= 448.f) return (unsigned char)(s | 0x7E);
    if (a < 0.015625f) {
        int m = __float2int_rn(a * 512.f);
        if (m >= 8) return (unsigned char)(s | 0x08);
        return (unsigned char)(s | m);
    }
    unsigned au = __float_as_uint(a);
    au += 0x7FFFFu + ((au >> 20) & 1u);
    int e = (int)(au >> 23) - 127;
    if (e > 8) return (unsigned char)(s | 0x7E);
    return (unsigned char)(s | ((unsigned)(e + 7) << 3) | ((au >> 20) & 7u));
}
#endif

__device__ __forceinline__ unsigned enc4(float a, float b, float c, float d) {
#ifdef HW_FP8
    int v = __builtin_amdgcn_cvt_pk_fp8_f32(a, b, 0, false);
    v = __builtin_amdgcn_cvt_pk_fp8_f32(c, d, v, true);
    return (unsigned)v;
#else
    return (unsigned)enc1(a) | ((unsigned)enc1(b) << 8)
         | ((unsigned)enc1(c) << 16) | ((unsigned)enc1(d) << 24);
#endif
}

__device__ __forceinline__ unsigned short f2b(float f) {
    unsigned b = __float_as_uint(f);
    b += 0x7FFFu + ((b >> 16) & 1u);
    return (unsigned short)(b >> 16);
}

// ---------------- single-pass fine-partition build (+ merged cvt) ------------
// One block per 8192-edge tile, per side. Bins directly into the 360 fine
// partitions: mean 41 recs/bin/tile -> 328B coalesced runs (full lines), which
// is what the old coarse+refine two-pass existed to guarantee. Record:
// x = (src<<16)|dst, y = val bits (sort_csr format unchanged).
#define N_EU 800000
#define N_EI 320000
#define N_OU 800000
#define N_OI 320000
#define CVT_TOT (N_EU + N_EI + N_OU + N_OI)
__global__ void build_fine(const int* __restrict__ rows, const int* __restrict__ cols,
                           const float* __restrict__ uiv, const float* __restrict__ iuv,
                           int* __restrict__ fcurU, int2* __restrict__ fbufU,
                           int* __restrict__ fcurI, int2* __restrict__ fbufI,
                           const float* __restrict__ eU, const float* __restrict__ eI,
                           const float* __restrict__ oU, const float* __restrict__ oI,
                           unsigned* __restrict__ e8U, unsigned* __restrict__ e8I,
                           unsigned* __restrict__ o8U, unsigned* __restrict__ o8I)
{
    if (blockIdx.x >= NBU + NBI) {
        // grid-strided fp32->fp8 table conversion (independent work)
        for (int idx = (blockIdx.x - NBU - NBI) * 256 + threadIdx.x;
             idx < CVT_TOT; idx += CVB * 256) {
            const float* s; unsigned* d; int off; float sc;
            if (idx < N_EU)                      { s = eU; d = e8U; off = idx; sc = 128.f; }
            else if (idx < N_EU + N_EI)          { s = eI; d = e8I; off = idx - N_EU; sc = 128.f; }
            else if (idx < N_EU + N_EI + N_OU)   { s = oU; d = o8U; off = idx - N_EU - N_EI; sc = 1.f; }
            else                                 { s = oI; d = o8I; off = idx - N_EU - N_EI - N_OU; sc = 1.f; }
            float4 v = ((const float4*)s)[off];
            d[off] = enc4(v.x * sc, v.y * sc, v.z * sc, v.w * sc);
        }
        return;
    }

    __shared__ int2 rec[TILE];                  // 64 KB
    __shared__ unsigned char pid[TILE];         // 8 KB
    __shared__ int hist[256], scan[256], curs[256], delta[256];

    bool isU = blockIdx.x < NBU;
    int tb = isU ? blockIdx.x : blockIdx.x - NBU;
    int n0 = tb * TILE;
    int n  = min(TILE, N_EDGES - n0);
    int bins  = isU ? FP_U : FP_I;
    int capf  = isU ? CAPF_U : CAPF_I;
    int shift = isU ? 8 : 7;
    int* fcur = isU ? fcurU : fcurI;
    int2* fbuf = isU ? fbufU : fbufI;
    const int* keys = isU ? rows : cols;
    const int* srcs = isU ? cols : rows;
    const float* vals = isU ? uiv : iuv;

    hist[threadIdx.x] = 0;
    __syncthreads();

    // phase A: histogram by fine partition
    for (int t = threadIdx.x; t < n; t += 256)
        atomicAdd(&hist[keys[n0 + t] >> shift], 1);
    __syncthreads();

    // phase B: 256-wide LDS scan -> lbase; reserve global cursors
    int v = hist[threadIdx.x];
    scan[threadIdx.x] = v;
    __syncthreads();
    for (int off = 1; off < 256; off <<= 1) {
        int t = ((int)threadIdx.x >= off) ? scan[threadIdx.x - off] : 0;
        __syncthreads();
        scan[threadIdx.x] += t;
        __syncthreads();
    }
    int lbase = scan[threadIdx.x] - v;
    curs[threadIdx.x] = lbase;
    if ((int)threadIdx.x < bins) {
        int res = v ? atomicAdd(&fcur[threadIdx.x], v) : 0;
        delta[threadIdx.x] = threadIdx.x * capf + res - lbase;
    }
    __syncthreads();

    // phase C: re-read (L2-warm) and place partition-sorted in LDS
    for (int t = threadIdx.x; t < n; t += 256) {
        int key = keys[n0 + t];
        int src = srcs[n0 + t];
        float vv = vals[n0 + t];
        int b = key >> shift;
        int slot = atomicAdd(&curs[b], 1);
        int2 r;
        r.x = (int)(((unsigned)src << 16) | (unsigned)key);
        r.y = __float_as_int(vv);
        rec[slot] = r;
        pid[slot] = (unsigned char)b;
    }
    __syncthreads();

    // flush: consecutive slots -> consecutive global addresses per bin run
    for (int t = threadIdx.x; t < n; t += 256) {
        int b = pid[t];
        int a = delta[b] + t;
        if (a < (b + 1) * capf) fbuf[a] = rec[t];
    }
}

// ---------------- sort_csr: fine partition -> exact CSR (4B recs) + ptr/cnt --
__global__ void sort_csr(const int* __restrict__ fcurU, const int2* __restrict__ fbufU,
                         int* __restrict__ ptrU, int* __restrict__ cntU, unsigned* __restrict__ edgesU,
                         const int* __restrict__ fcurI, const int2* __restrict__ fbufI,
                         int* __restrict__ ptrI, int* __restrict__ cntI, unsigned* __restrict__ edgesI)
{
    __shared__ int hist[256], scan[256], curs[256];
    __shared__ int gbase_s;

    const int* fcur; const int2* fbuf; int* ptr; int* cnt; unsigned* edges;
    int fp, bins, capf, nrow;
    if (blockIdx.x < FP_U) {
        fcur = fcurU; fbuf = fbufU; ptr = ptrU; cnt = cntU; edges = edgesU;
        fp = blockIdx.x; bins = 256; capf = CAPF_U; nrow = U_NUM;
    } else {
        fcur = fcurI; fbuf = fbufI; ptr = ptrI; cnt = cntI; edges = edgesI;
        fp = blockIdx.x - FP_U; bins = 128; capf = CAPF_I; nrow = I_NUM;
    }

    if (threadIdx.x == 0) gbase_s = 0;
    for (int i = threadIdx.x; i < bins; i += 256) hist[i] = 0;
    __syncthreads();

    int contrib = ((int)threadIdx.x < fp) ? min(fcur[threadIdx.x], capf) : 0;
    #pragma unroll
    for (int off = 32; off > 0; off >>= 1) contrib += __shfl_down(contrib, off, 64);
    if ((threadIdx.x & 63) == 0 && contrib) atomicAdd(&gbase_s, contrib);

    int n = min(fcur[fp], capf);
    const int2* src = fbuf + (size_t)fp * capf;
    int mask = bins - 1;

    for (int t = threadIdx.x; t < n; t += 256) {
        int dst = src[t].x & 0xFFFF;
        atomicAdd(&hist[dst & mask], 1);
    }
    __syncthreads();

    int v = ((int)threadIdx.x < bins) ? hist[threadIdx.x] : 0;
    scan[threadIdx.x] = v;
    __syncthreads();
    for (int off = 1; off < 256; off <<= 1) {
        int t = ((int)threadIdx.x >= off) ? scan[threadIdx.x - off] : 0;
        __syncthreads();
        scan[threadIdx.x] += t;
        __syncthreads();
    }
    int ex = scan[threadIdx.x] - v;
    curs[threadIdx.x] = ex;
    __syncthreads();
    int gbase = gbase_s;

    if ((int)threadIdx.x < bins) {
        int row = fp * bins + threadIdx.x;
        if (row < nrow) {
            ptr[row] = gbase + ex;
            cnt[row] = v;
        }
    }

    for (int t = threadIdx.x; t < n; t += 256) {
        int2 r = src[t];
        int dst = r.x & 0xFFFF;
        int pos = atomicAdd(&curs[dst & mask], 1);
        unsigned rec = ((unsigned)f2b(__int_as_float(r.y)) << 16)
                     | ((unsigned)r.x >> 16);
        edges[gbase + pos] = rec;
    }
}

// ---------------- fused-level gather SpMM (fp8 in, fp8 out) ------------------
template <int MODE>
__global__ void spmm_level(const int* __restrict__ ptrU, const int* __restrict__ cntU,
                           const unsigned* __restrict__ edgesU, const unsigned* __restrict__ srcU,
                           unsigned* __restrict__ dstU,
                           const unsigned* __restrict__ l0U, const unsigned* __restrict__ l1U,
                           const unsigned* __restrict__ l2U, unsigned* __restrict__ g8U,
                           const int* __restrict__ ptrI, const int* __restrict__ cntI,
                           const unsigned* __restrict__ edgesI, const unsigned* __restrict__ srcI,
                           unsigned* __restrict__ dstI,
                           const unsigned* __restrict__ l0I, const unsigned* __restrict__ l1I,
                           const unsigned* __restrict__ l2I, unsigned* __restrict__ g8I)
{
    int wave = (blockIdx.x * blockDim.x + threadIdx.x) >> 6;
    bool isU = wave < U_NUM;
    int row = isU ? wave : wave - U_NUM;
    if (!isU && row >= I_NUM) return;

    const int*  ptr   = isU ? ptrU   : ptrI;
    const int*  cnt   = isU ? cntU   : cntI;
    const unsigned* edges = isU ? edgesU : edgesI;
    const unsigned* semb  = isU ? srcU   : srcI;

    int lane = threadIdx.x & 63;
    int sub  = lane >> 4;
    int q    = lane & 15;
    int begin = __builtin_amdgcn_readfirstlane(ptr[row]);
    int len   = __builtin_amdgcn_readfirstlane(cnt[row]);
    const unsigned* erow = edges + begin;

    float4 a0 = make_float4(0.f, 0.f, 0.f, 0.f);
    float4 a1 = make_float4(0.f, 0.f, 0.f, 0.f);
    float4 a2 = make_float4(0.f, 0.f, 0.f, 0.f);
    float4 a3 = make_float4(0.f, 0.f, 0.f, 0.f);
    int k = sub;
    for (; k + 12 < len; k += 16) {
        unsigned r0 = erow[k];
        unsigned r1 = erow[k + 4];
        unsigned r2 = erow[k + 8];
        unsigned r3 = erow[k + 12];
        unsigned x0 = semb[((size_t)(r0 & 0xFFFFu) << 4) + q];
        unsigned x1 = semb[((size_t)(r1 & 0xFFFFu) << 4) + q];
        unsigned x2 = semb[((size_t)(r2 & 0xFFFFu) << 4) + q];
        unsigned x3 = semb[((size_t)(r3 & 0xFFFFu) << 4) + q];
        float v0 = __uint_as_float(r0 & 0xFFFF0000u);
        float v1 = __uint_as_float(r1 & 0xFFFF0000u);
        float v2 = __uint_as_float(r2 & 0xFFFF0000u);
        float v3 = __uint_as_float(r3 & 0xFFFF0000u);
        float f0[4], f1[4], f2[4], f3[4];
        dec4(x0, f0); dec4(x1, f1); dec4(x2, f2); dec4(x3, f3);
        a0.x += v0 * f0[0]; a0.y += v0 * f0[1]; a0.z += v0 * f0[2]; a0.w += v0 * f0[3];
        a1.x += v1 * f1[0]; a1.y += v1 * f1[1]; a1.z += v1 * f1[2]; a1.w += v1 * f1[3];
        a2.x += v2 * f2[0]; a2.y += v2 * f2[1]; a2.z += v2 * f2[2]; a2.w += v2 * f2[3];
        a3.x += v3 * f3[0]; a3.y += v3 * f3[1]; a3.z += v3 * f3[2]; a3.w += v3 * f3[3];
    }
    for (; k < len; k += 4) {
        unsigned r0 = erow[k];
        unsigned x0 = semb[((size_t)(r0 & 0xFFFFu) << 4) + q];
        float v0 = __uint_as_float(r0 & 0xFFFF0000u);
        float f0[4];
        dec4(x0, f0);
        a0.x += v0 * f0[0]; a0.y += v0 * f0[1]; a0.z += v0 * f0[2]; a0.w += v0 * f0[3];
    }
    float4 acc;
    acc.x = (a0.x + a1.x) + (a2.x + a3.x);
    acc.y = (a0.y + a1.y) + (a2.y + a3.y);
    acc.z = (a0.z + a1.z) + (a2.z + a3.z);
    acc.w = (a0.w + a1.w) + (a2.w + a3.w);

    acc.x += __shfl_xor(acc.x, 16, 64);
    acc.y += __shfl_xor(acc.y, 16, 64);
    acc.z += __shfl_xor(acc.z, 16, 64);
    acc.w += __shfl_xor(acc.w, 16, 64);
    acc.x += __shfl_xor(acc.x, 32, 64);
    acc.y += __shfl_xor(acc.y, 32, 64);
    acc.z += __shfl_xor(acc.z, 32, 64);
    acc.w += __shfl_xor(acc.w, 32, 64);

    if (sub == 0) {
        size_t ro = ((size_t)row << 4) + q;
        if (MODE < 2) {
            unsigned* dst = isU ? dstU : dstI;
            dst[ro] = enc4(acc.x, acc.y, acc.z, acc.w);
        } else {
            const unsigned* l0 = isU ? l0U : l0I;
            const unsigned* l1 = isU ? l1U : l1I;
            const unsigned* l2 = isU ? l2U : l2I;
            unsigned* g8       = isU ? g8U : g8I;
            float e[4], b[4], c[4];
            dec4(l0[ro], e); dec4(l1[ro], b); dec4(l2[ro], c);
            const float third = 1.f / 3.f;
            float gx = 0.125f * (e[0] + 0.5f * b[0] + third * c[0] + 0.25f * acc.x);
            float gy = 0.125f * (e[1] + 0.5f * b[1] + third * c[1] + 0.25f * acc.y);
            float gz = 0.125f * (e[2] + 0.5f * b[2] + third * c[2] + 0.25f * acc.z);
            float gw = 0.125f * (e[3] + 0.5f * b[3] + third * c[3] + 0.25f * acc.w);
            g8[ro] = enc4(gx, gy, gz, gw);
        }
    }
}

// ---------------- contrastive loss v3: MLP-restructured ----------------------
__device__ __forceinline__ float dotq(const float* a, const float* b) {
    return a[0] * b[0] + a[1] * b[1] + a[2] * b[2] + a[3] * b[3];
}

__global__ void __launch_bounds__(256, 2)
contrastive_both(const unsigned* __restrict__ oldU, const unsigned* __restrict__ gcnU,
                 const int* __restrict__ userU, const int* __restrict__ iiU,
                 const int* __restrict__ ijU, const float* __restrict__ degU,
                 const unsigned* __restrict__ oldI, const unsigned* __restrict__ gcnI,
                 const int* __restrict__ userI, const int* __restrict__ iiI,
                 const int* __restrict__ ijI, const float* __restrict__ degI,
                 float* __restrict__ out)
{
    int lane = threadIdx.x & 63;
    int sub  = lane >> 4;
    int ql   = lane & 15;
    int qg = (blockIdx.x * blockDim.x + threadIdx.x) >> 4;
    int s0 = qg << 2;

    int sel = ql >> 2, so = s0 + (ql & 3);
    const int* pu = (sel == 0) ? (userU + so) : (sel == 1) ? (iiU + so)
                  : (sel == 2) ? (ijU + so)   : ((const int*)degU + so);
    const int* pi = (sel == 0) ? (userI + so) : (sel == 1) ? (iiI + so)
                  : (sel == 2) ? (ijI + so)   : ((const int*)degI + so);
    int idxU = *pu;
    int idxI = *pi;

    int qb = sub << 4;
    unsigned Au[4], Ai[4], Aj[4], Bu[4], Bi[4], Bj[4];
    #pragma unroll
    for (int t = 0; t < 4; t++) {
        int uU = __shfl(idxU, qb + t, 64);
        int iU = __shfl(idxU, qb + 4 + t, 64);
        int jU = __shfl(idxU, qb + 8 + t, 64);
        int uI = __shfl(idxI, qb + t, 64);
        int iI = __shfl(idxI, qb + 4 + t, 64);
        int jI = __shfl(idxI, qb + 8 + t, 64);
        Au[t] = oldU[((size_t)uU << 4) + ql];
        Ai[t] = gcnU[((size_t)iU << 4) + ql];
        Aj[t] = gcnU[((size_t)jU << 4) + ql];
        Bu[t] = oldI[((size_t)uI << 4) + ql];
        Bi[t] = gcnI[((size_t)iI << 4) + ql];
        Bj[t] = gcnI[((size_t)jI << 4) + ql];
    }

    float siU[4], sjU[4], siI[4], sjI[4];
    #pragma unroll
    for (int t = 0; t < 4; t++) {
        float fu[4], fi[4], fj[4];
        dec4(Au[t], fu); dec4(Ai[t], fi); dec4(Aj[t], fj);
        siU[t] = dotq(fu, fi); sjU[t] = dotq(fu, fj);
        dec4(Bu[t], fu); dec4(Bi[t], fi); dec4(Bj[t], fj);
        siI[t] = dotq(fu, fi); sjI[t] = dotq(fu, fj);
    }

    #pragma unroll
    for (int off = 1; off < 16; off <<= 1) {
        #pragma unroll
        for (int t = 0; t < 4; t++) {
            siU[t] += __shfl_xor(siU[t], off, 64);
            sjU[t] += __shfl_xor(sjU[t], off, 64);
            siI[t] += __shfl_xor(siI[t], off, 64);
            sjI[t] += __shfl_xor(sjI[t], off, 64);
        }
    }

    int t3 = ql & 3;
    bool isI = (ql & 4) != 0;
    float si = isI ? siI[t3] : siU[t3];
    float sj = isI ? sjI[t3] : sjU[t3];
    float dg = __int_as_float(__shfl(isI ? idxI : idxU, qb + 12 + t3, 64));
    float inv = isI ? (1.f / I_NUM) : (1.f / U_NUM);

    const float S = 0.0625f;
    si *= S; sj *= S;
    float m = fmaxf(si, sj);
    float lse = m + logf(expf(si - m) + expf(sj - m));
    float acc = (ql < 8) ? -(si - lse) * dg * inv : 0.f;

    #pragma unroll
    for (int off = 32; off > 0; off >>= 1) acc += __shfl_down(acc, off, 64);
    __shared__ float wsum[4];
    if (lane == 0) wsum[threadIdx.x >> 6] = acc;
    __syncthreads();
    if (threadIdx.x == 0)
        atomicAdd(out, wsum[0] + wsum[1] + wsum[2] + wsum[3]);
}

extern "C" void kernel_launch(void* const* d_in, const int* in_sizes, int n_in,
                              void* d_out, int out_size, void* d_ws, size_t ws_size,
                              hipStream_t stream)
{
    const float* embed_user = (const float*)d_in[0];
    const float* embed_item = (const float*)d_in[1];
    const float* old_U      = (const float*)d_in[2];
    const float* old_I      = (const float*)d_in[3];
    const int*   erow       = (const int*)d_in[4];
    const int*   ecol       = (const int*)d_in[5];
    const float* ui_vals    = (const float*)d_in[6];
    const float* iu_vals    = (const float*)d_in[7];
    const int*   user       = (const int*)d_in[8];
    const int*   item_i     = (const int*)d_in[9];
    const int*   item_j     = (const int*)d_in[10];
    const float* degU       = (const float*)d_in[11];
    const int*   user_      = (const int*)d_in[13];
    const int*   item_i_    = (const int*)d_in[14];
    const int*   item_j_    = (const int*)d_in[15];
    const float* degI       = (const float*)d_in[16];

    const size_t UF = (size_t)U_NUM * F_DIM;
    const size_t IF = (size_t)I_NUM * F_DIM;
    const size_t FRECU = (size_t)FP_U * CAPF_U;   // 1,126,400
    const size_t FRECI = (size_t)FP_I * CAPF_I;   // 1,105,920

    // Layout: fine buffers first; 4B CSR edges overlay the fbuf region after
    // sort_csr consumes it? NO — sort reads fbuf while writing edges, so they
    // must not alias. Keep separate regions (plenty of ws).
    int2*  fbufU  = (int2*)d_ws;                       // 9.0 MB
    int2*  fbufI  = fbufU + FRECU;                     // 8.8 MB
    unsigned* edgesU = (unsigned*)(fbufI + FRECI);     // 4 MB
    unsigned* edgesI = edgesU + N_EDGES;               // 4 MB
    char* cur = (char*)(edgesI + N_EDGES);
    unsigned* e8U = (unsigned*)cur; cur += UF;
    unsigned* e8I = (unsigned*)cur; cur += IF;
    unsigned* o8U = (unsigned*)cur; cur += UF;
    unsigned* o8I = (unsigned*)cur; cur += IF;
    unsigned* u1_8 = (unsigned*)cur; cur += UF;
    unsigned* u2_8 = (unsigned*)cur; cur += UF;
    unsigned* i1_8 = (unsigned*)cur; cur += IF;
    unsigned* i2_8 = (unsigned*)cur; cur += IF;
    unsigned* g8U  = (unsigned*)cur; cur += UF;
    unsigned* g8I  = (unsigned*)cur; cur += IF;
    int* fcurU = (int*)cur;            // 256 slots (200 used)
    int* fcurI = fcurU + 256;          // 256 slots (160 used)
    int* ptrU  = fcurI + 256;
    int* cntUa = ptrU + U_NUM;
    int* ptrI  = cntUa + U_NUM;
    int* cntIa = ptrI + I_NUM;
    // total ~48 MB

    dim3 blk(256);
    const int bf_blocks  = NBU + NBI + CVB;            // 758
    const int st_blocks  = FP_U + FP_I;                // 360
    const int spmm_blocks = (U_NUM + I_NUM) / 4;       // 17500

    hipMemsetAsync(fcurU, 0, 512 * sizeof(int), stream);
    hipMemsetAsync(d_out, 0, sizeof(float), stream);

    build_fine<<<bf_blocks, blk, 0, stream>>>(erow, ecol, ui_vals, iu_vals,
                                              fcurU, fbufU, fcurI, fbufI,
                                              embed_user, embed_item, old_U, old_I,
                                              e8U, e8I, o8U, o8I);
    sort_csr<<<st_blocks, blk, 0, stream>>>(fcurU, fbufU, ptrU, cntUa, edgesU,
                                            fcurI, fbufI, ptrI, cntIa, edgesI);

    // L1: u1_8 = enc(128*u1) ; i1_8 = enc(128*i1)
    spmm_level<0><<<spmm_blocks, blk, 0, stream>>>(
        ptrU, cntUa, edgesU, e8I, u1_8, nullptr, nullptr, nullptr, nullptr,
        ptrI, cntIa, edgesI, e8U, i1_8, nullptr, nullptr, nullptr, nullptr);
    // L2: u2_8 = enc(128*u2) ; i2_8 = enc(128*i2)
    spmm_level<1><<<spmm_blocks, blk, 0, stream>>>(
        ptrU, cntUa, edgesU, i1_8, u2_8, nullptr, nullptr, nullptr, nullptr,
        ptrI, cntIa, edgesI, u1_8, i2_8, nullptr, nullptr, nullptr, nullptr);
    // L3: g8 = enc(0.125*(l0 + 0.5*l1 + (1/3)*l2 + 0.25*acc)) = enc(16*gcn)
    spmm_level<2><<<spmm_blocks, blk, 0, stream>>>(
        ptrU, cntUa, edgesU, i2_8, nullptr, e8U, u1_8, u2_8, g8U,
        ptrI, cntIa, edgesI, u2_8, nullptr, e8I, i1_8, i2_8, g8I);

    contrastive_both<<<2048, blk, 0, stream>>>(o8U, g8U, user, item_i, item_j, degU,
                                               o8I, g8I, user_, item_i_, item_j_, degI,
                                               (float*)d_out);
}